// Round 2
// baseline (3543.531 us; speedup 1.0000x reference)
//
#include <hip/hip_runtime.h>

constexpr int TN = 100000;   // nodes
constexpr int TE = 200000;   // edges
constexpr int TG = 4000;     // graphs
constexpr int TH = 128;      // hidden

constexpr int CN = 20000;    // gin-MLP row chunk   (N/CN = 5)
constexpr int CG = 10000;    // GRU row chunk       (N/CG = 10)
constexpr int CE = 20000;    // edge-pipe chunk     (E/CE = 10)

#define DEVINL __device__ __forceinline__

DEVINL float sigm(float x) { return 1.f / (1.f + expf(-x)); }

DEVINL void atomicMaxFloat(float* addr, float val) {
    if (val >= 0.f) atomicMax((int*)addr, __float_as_int(val));
    else            atomicMin((unsigned int*)addr, __float_as_uint(val));
}

// ---------- projection: out[m,h] = sum_k X[m,k]*W[k,h] + b[h]  (H=128) ----------
__global__ void proj_kernel(const float* __restrict__ X, const float* __restrict__ W,
                            const float* __restrict__ b, float* __restrict__ out,
                            int M, int K) {
    int idx = blockIdx.x * 256 + threadIdx.x;
    if (idx >= M * TH) return;
    int m = idx >> 7, h = idx & 127;
    float acc = b[h];
    const float* xr = X + (size_t)m * K;
    for (int k = 0; k < K; ++k) acc = fmaf(xr[k], W[k * TH + h], acc);
    out[idx] = acc;
}

// ---------- z = (1+eps[l]) * node ----------
__global__ void zinit_kernel(const float* __restrict__ node, float* __restrict__ z,
                             const float* __restrict__ eps, int l, int n4) {
    int i = blockIdx.x * 256 + threadIdx.x;
    if (i >= n4) return;
    float s = 1.f + eps[l];
    float4 v = ((const float4*)node)[i];
    v.x *= s; v.y *= s; v.z *= s; v.w *= s;
    ((float4*)z)[i] = v;
}

// ---------- layer-0 scatter: z[dst] += relu(node[src] + proj(edge_attr[e])) ----------
__global__ void scatter_fused0(const float* __restrict__ node,
                               const float* __restrict__ edge_attr,
                               const float* __restrict__ edge_w,
                               const float* __restrict__ edge_b,
                               const int* __restrict__ ei,
                               float* __restrict__ z, int En) {
    int t = blockIdx.x * 256 + threadIdx.x;
    int e = t >> 5;
    if (e >= En) return;
    int c = (t & 31) * 4;
    int src = ei[e], dst = ei[En + e];
    float ea0 = edge_attr[e * 4 + 0], ea1 = edge_attr[e * 4 + 1];
    float ea2 = edge_attr[e * 4 + 2], ea3 = edge_attr[e * 4 + 3];
    float4 nv = *(const float4*)(node + (size_t)src * TH + c);
    float* zp = z + (size_t)dst * TH + c;
#pragma unroll
    for (int j = 0; j < 4; ++j) {
        float ev = edge_b[c + j];
        ev = fmaf(ea0, edge_w[0 * TH + c + j], ev);
        ev = fmaf(ea1, edge_w[1 * TH + c + j], ev);
        ev = fmaf(ea2, edge_w[2 * TH + c + j], ev);
        ev = fmaf(ea3, edge_w[3 * TH + c + j], ev);
        float nvj = (j == 0) ? nv.x : (j == 1) ? nv.y : (j == 2) ? nv.z : nv.w;
        atomicAdd(zp + j, fmaxf(nvj + ev, 0.f));
    }
}

// ---------- generic scatter from a chunk edge buffer ----------
__global__ void scatter_msg(const float* __restrict__ node, const float* __restrict__ edge,
                            const int* __restrict__ ei_src, const int* __restrict__ ei_dst,
                            float* __restrict__ z, int En) {
    int t = blockIdx.x * 256 + threadIdx.x;
    int e = t >> 5;
    if (e >= En) return;
    int c = (t & 31) * 4;
    int src = ei_src[e], dst = ei_dst[e];
    float4 nv = *(const float4*)(node + (size_t)src * TH + c);
    float4 ev = *(const float4*)(edge + (size_t)e * TH + c);
    float* zp = z + (size_t)dst * TH + c;
    atomicAdd(zp + 0, fmaxf(nv.x + ev.x, 0.f));
    atomicAdd(zp + 1, fmaxf(nv.y + ev.y, 0.f));
    atomicAdd(zp + 2, fmaxf(nv.z + ev.z, 0.f));
    atomicAdd(zp + 3, fmaxf(nv.w + ev.w, 0.f));
}

// ---------- tiled fp32 GEMM: C = [relu]( A[M,K] @ B (+bias) [+C] ) ----------
template<bool TRANSB, bool RELU, bool ACC>
__global__ __launch_bounds__(256) void sgemm_k(
    const float* __restrict__ A, const float* __restrict__ B,
    const float* __restrict__ bias, float* __restrict__ C,
    int M, int K, int Nc)
{
    constexpr int BM = 64, BN = 64, BK = 32, PAD = 4;
    __shared__ float As[BK][BM + PAD];
    __shared__ float Bs[BK][BN + PAD];
    const int tid = threadIdx.x;
    const int bm = blockIdx.x * BM;
    const int bn = blockIdx.y * BN;
    const int tx = tid & 15, ty = tid >> 4;
    float acc[4][4] = {};
    for (int k0 = 0; k0 < K; k0 += BK) {
#pragma unroll
        for (int i = 0; i < 2; ++i) {
            int idx = tid + i * 256;
            int r = idx >> 3, kq = (idx & 7) * 4;
            int row = bm + r;
            float4 v = make_float4(0.f, 0.f, 0.f, 0.f);
            if (row < M) v = *(const float4*)(A + (size_t)row * K + k0 + kq);
            As[kq + 0][r] = v.x; As[kq + 1][r] = v.y;
            As[kq + 2][r] = v.z; As[kq + 3][r] = v.w;
        }
        if (TRANSB) {
#pragma unroll
            for (int i = 0; i < 2; ++i) {
                int idx = tid + i * 256;
                int n = idx >> 3, kq = (idx & 7) * 4;
                float4 v = *(const float4*)(B + (size_t)(bn + n) * K + k0 + kq);
                Bs[kq + 0][n] = v.x; Bs[kq + 1][n] = v.y;
                Bs[kq + 2][n] = v.z; Bs[kq + 3][n] = v.w;
            }
        } else {
#pragma unroll
            for (int i = 0; i < 2; ++i) {
                int idx = tid + i * 256;
                int kk = idx >> 4, nq = (idx & 15) * 4;
                float4 v = *(const float4*)(B + (size_t)(k0 + kk) * Nc + bn + nq);
                Bs[kk][nq + 0] = v.x; Bs[kk][nq + 1] = v.y;
                Bs[kk][nq + 2] = v.z; Bs[kk][nq + 3] = v.w;
            }
        }
        __syncthreads();
#pragma unroll
        for (int k = 0; k < BK; ++k) {
            float4 av = *(const float4*)&As[k][ty * 4];
            float4 bv = *(const float4*)&Bs[k][tx * 4];
            float a4[4] = {av.x, av.y, av.z, av.w};
            float b4[4] = {bv.x, bv.y, bv.z, bv.w};
#pragma unroll
            for (int i = 0; i < 4; ++i)
#pragma unroll
                for (int j = 0; j < 4; ++j)
                    acc[i][j] = fmaf(a4[i], b4[j], acc[i][j]);
        }
        __syncthreads();
    }
#pragma unroll
    for (int i = 0; i < 4; ++i) {
        int row = bm + ty * 4 + i;
        if (row >= M) continue;
#pragma unroll
        for (int j = 0; j < 4; ++j) {
            int col = bn + tx * 4 + j;
            float v = acc[i][j] + bias[col];
            if (ACC) v += C[(size_t)row * Nc + col];
            if (RELU) v = fmaxf(v, 0.f);
            C[(size_t)row * Nc + col] = v;
        }
    }
}

// ---------- GRU gates (chunk), node chunk updated in place ----------
__global__ void gru_gates(const float* __restrict__ gi, const float* __restrict__ gh,
                          float* __restrict__ node, int NH) {
    int i = blockIdx.x * 256 + threadIdx.x;
    if (i >= NH) return;
    size_t n = (size_t)(i >> 7);
    int h = i & 127;
    const float* gir = gi + n * 384;
    const float* ghr = gh + n * 384;
    float r  = sigm(gir[h] + ghr[h]);
    float zt = sigm(gir[128 + h] + ghr[128 + h]);
    float nn = tanhf(gir[256 + h] + r * ghr[256 + h]);
    float ho = node[i];
    node[i] = (1.f - zt) * nn + zt * ho;
}

// ---------- LSTM gates + write q into qs, zero r-part, init emax/denom ----------
__global__ void lstm_gates(const float* __restrict__ g4, float* __restrict__ cl,
                           float* __restrict__ hl, float* __restrict__ qs,
                           float* __restrict__ emax, float* __restrict__ denom, int Gn) {
    int i = blockIdx.x * 256 + threadIdx.x;
    if (i >= Gn * TH) return;
    int g = i >> 7, h = i & 127;
    const float* row = g4 + (size_t)g * 512;
    float ig = sigm(row[h]);
    float fg = sigm(row[128 + h]);
    float gg = tanhf(row[256 + h]);
    float og = sigm(row[384 + h]);
    float c = fg * cl[i] + ig * gg;
    cl[i] = c;
    float hv = og * tanhf(c);
    hl[i] = hv;
    qs[(size_t)g * 256 + h] = hv;
    qs[(size_t)g * 256 + 128 + h] = 0.f;
    if (h == 0) { emax[g] = -__builtin_inff(); denom[g] = 0.f; }
}

// ---------- attention dot: e[n] = <node[n], hl[batch[n]]>, segment max ----------
__global__ void att_dot(const float* __restrict__ node, const float* __restrict__ hl,
                        const int* __restrict__ batch, float* __restrict__ e,
                        float* __restrict__ emax, int Nn) {
    int t = blockIdx.x * 256 + threadIdx.x;
    int n = t >> 6;
    if (n >= Nn) return;
    int lane = t & 63;
    int g = batch[n];
    const float* nr = node + (size_t)n * TH;
    const float* qr = hl + (size_t)g * TH;
    float p = nr[lane] * qr[lane] + nr[lane + 64] * qr[lane + 64];
    for (int off = 32; off; off >>= 1) p += __shfl_down(p, off);
    if (lane == 0) { e[n] = p; atomicMaxFloat(&emax[g], p); }
}

// ---------- exp + denom ----------
__global__ void att_exp(float* __restrict__ e, const float* __restrict__ emax,
                        float* __restrict__ denom, const int* __restrict__ batch, int Nn) {
    int n = blockIdx.x * 256 + threadIdx.x;
    if (n >= Nn) return;
    int g = batch[n];
    float ex = expf(e[n] - emax[g]);
    e[n] = ex;
    atomicAdd(&denom[g], ex);
}

// ---------- weighted scatter: qs[g, H:2H] += a[n] * node[n] ----------
__global__ void att_scatter(const float* __restrict__ node, const float* __restrict__ e,
                            const float* __restrict__ denom, const int* __restrict__ batch,
                            float* __restrict__ qs, int Nn) {
    int t = blockIdx.x * 256 + threadIdx.x;
    int n = t >> 5;
    if (n >= Nn) return;
    int c = (t & 31) * 4;
    int g = batch[n];
    float a = e[n] / fmaxf(denom[g], 1e-9f);
    float4 nv = *(const float4*)(node + (size_t)n * TH + c);
    float* qp = qs + (size_t)g * 256 + 128 + c;
    atomicAdd(qp + 0, a * nv.x); atomicAdd(qp + 1, a * nv.y);
    atomicAdd(qp + 2, a * nv.z); atomicAdd(qp + 3, a * nv.w);
}

// ---------- final FC ----------
__global__ __launch_bounds__(128) void final_fc(const float* __restrict__ qs,
                                                const float* __restrict__ w1,
                                                const float* __restrict__ b1,
                                                const float* __restrict__ w2,
                                                const float* __restrict__ b2,
                                                float* __restrict__ out) {
    __shared__ float q[256];
    __shared__ float red[2];
    int g = blockIdx.x, t = threadIdx.x;
    q[t] = qs[(size_t)g * 256 + t];
    q[t + 128] = qs[(size_t)g * 256 + 128 + t];
    __syncthreads();
    float acc = b1[t];
    for (int k = 0; k < 256; ++k) acc = fmaf(q[k], w1[k * TH + t], acc);
    acc = fmaxf(acc, 0.f);
    float p = acc * w2[t];
    for (int off = 32; off; off >>= 1) p += __shfl_down(p, off);
    if ((t & 63) == 0) red[t >> 6] = p;
    __syncthreads();
    if (t == 0) out[g] = red[0] + red[1] + b2[0];
}

// ---------------------------------------------------------------------------
template<bool TB, bool RL, bool AC>
static void launch_gemm(const float* A, const float* B, const float* bias, float* C,
                        int M, int K, int Nc, hipStream_t s) {
    dim3 grid((M + 63) / 64, Nc / 64);
    hipLaunchKernelGGL((sgemm_k<TB, RL, AC>), grid, dim3(256), 0, s, A, B, bias, C, M, K, Nc);
}

extern "C" void kernel_launch(void* const* d_in, const int* in_sizes, int n_in,
                              void* d_out, int out_size, void* d_ws, size_t ws_size,
                              hipStream_t stream) {
    const float* x         = (const float*)d_in[0];
    const float* edge_attr = (const float*)d_in[1];
    const int*   edge_index= (const int*)d_in[2];
    const int*   batch     = (const int*)d_in[3];
    const float* node_w    = (const float*)d_in[4];
    const float* node_b    = (const float*)d_in[5];
    const float* edge_w    = (const float*)d_in[6];
    const float* edge_b    = (const float*)d_in[7];
    const float* eps       = (const float*)d_in[8];
    const float* gin_w1    = (const float*)d_in[9];
    const float* gin_b1    = (const float*)d_in[10];
    const float* gin_w2    = (const float*)d_in[11];
    const float* gin_b2    = (const float*)d_in[12];
    const float* em_w1     = (const float*)d_in[13];
    const float* em_b1     = (const float*)d_in[14];
    const float* em_w2     = (const float*)d_in[15];
    const float* em_b2     = (const float*)d_in[16];
    const float* gru_wih   = (const float*)d_in[17];
    const float* gru_whh   = (const float*)d_in[18];
    const float* gru_bih   = (const float*)d_in[19];
    const float* gru_bhh   = (const float*)d_in[20];
    const float* lstm_wih  = (const float*)d_in[21];
    const float* lstm_whh  = (const float*)d_in[22];
    const float* lstm_bih  = (const float*)d_in[23];
    const float* lstm_bhh  = (const float*)d_in[24];
    const float* fc_w1     = (const float*)d_in[25];
    const float* fc_b1     = (const float*)d_in[26];
    const float* fc_w2     = (const float*)d_in[27];
    const float* fc_b2     = (const float*)d_in[28];
    float* out = (float*)d_out;

    // ---- compact workspace layout (floats) ----
    float* ws    = (float*)d_ws;
    float* node  = ws;                                   // N*H        = 12.80M
    float* zbuf  = node + (size_t)TN * TH;               // N*H        = 12.80M
    float* sc    = zbuf + (size_t)TN * TH;               // scratch    =  7.68M (max of GRU 2*CG*384, edge 2*CE*128, MLP CN*128)
    float* qs    = sc   + (size_t)2 * CG * 3 * TH;       // G*2H       =  1.02M
    float* hl    = qs   + (size_t)TG * 2 * TH;           // G*H
    float* cl    = hl   + (size_t)TG * TH;               // G*H
    float* g4    = cl   + (size_t)TG * TH;               // G*4H
    float* ebuf  = g4   + (size_t)TG * 4 * TH;           // N
    float* emax  = ebuf + TN;                            // G
    float* denom = emax + TG;                            // G
    size_t need  = (size_t)(denom + TG - ws) * sizeof(float);
    if (ws_size < need) return;   // graceful fail (diagnostic: absmax == max|ref|)

    // zero LSTM state: qs, hl, cl contiguous = G*4H floats
    hipMemsetAsync(qs, 0, (size_t)TG * 4 * TH * sizeof(float), stream);

    // ---- node projection ----
    proj_kernel<<<(TN * TH + 255) / 256, 256, 0, stream>>>(x, node_w, node_b, node, TN, 14);

    // ---- GIN layers ----
    for (int l = 0; l < 2; ++l) {
        zinit_kernel<<<(TN * TH / 4 + 255) / 256, 256, 0, stream>>>(node, zbuf, eps, l, TN * TH / 4);
        if (l == 0) {
            scatter_fused0<<<(TE * 32 + 255) / 256, 256, 0, stream>>>(
                node, edge_attr, edge_w, edge_b, edge_index, zbuf, TE);
        } else {
            // edge pipeline per chunk: e0 = proj(edge_attr); t = relu(e0@em_w1+b1); e1 = t@em_w2+b2; scatter
            float* e0c = sc;
            float* tc  = sc + (size_t)CE * TH;
            for (int e0 = 0; e0 < TE; e0 += CE) {
                proj_kernel<<<(CE * TH + 255) / 256, 256, 0, stream>>>(
                    edge_attr + (size_t)e0 * 4, edge_w, edge_b, e0c, CE, 4);
                launch_gemm<false, true,  false>(e0c, em_w1, em_b1, tc,  CE, TH, TH, stream);
                launch_gemm<false, false, false>(tc,  em_w2, em_b2, e0c, CE, TH, TH, stream);
                scatter_msg<<<(CE * 32 + 255) / 256, 256, 0, stream>>>(
                    node, e0c, edge_index + e0, edge_index + TE + e0, zbuf, CE);
            }
        }
        // gin MLP (chunked): t1 = relu(z@w1+b1); m = t1@w2+b2 (overwrites zbuf chunk)
        for (int r0 = 0; r0 < TN; r0 += CN) {
            launch_gemm<false, true,  false>(zbuf + (size_t)r0 * TH, gin_w1 + (size_t)l * TH * TH,
                                             gin_b1 + l * TH, sc, CN, TH, TH, stream);
            launch_gemm<false, false, false>(sc, gin_w2 + (size_t)l * TH * TH,
                                             gin_b2 + l * TH, zbuf + (size_t)r0 * TH, CN, TH, TH, stream);
        }
        // GRU (chunked): gi = m@wih^T+bih ; gh = h@whh^T+bhh ; gates
        float* gic = sc;
        float* ghc = sc + (size_t)CG * 3 * TH;
        for (int r0 = 0; r0 < TN; r0 += CG) {
            launch_gemm<true, false, false>(zbuf + (size_t)r0 * TH, gru_wih, gru_bih, gic, CG, TH, 3 * TH, stream);
            launch_gemm<true, false, false>(node + (size_t)r0 * TH, gru_whh, gru_bhh, ghc, CG, TH, 3 * TH, stream);
            gru_gates<<<(CG * TH + 255) / 256, 256, 0, stream>>>(gic, ghc, node + (size_t)r0 * TH, CG * TH);
        }
    }

    // ---- Set2Set (3 steps) ----
    for (int s = 0; s < 3; ++s) {
        launch_gemm<true, false, false>(qs, lstm_wih, lstm_bih, g4, TG, 2 * TH, 4 * TH, stream);
        launch_gemm<true, false, true >(hl, lstm_whh, lstm_bhh, g4, TG, TH,     4 * TH, stream);
        lstm_gates<<<(TG * TH + 255) / 256, 256, 0, stream>>>(g4, cl, hl, qs, emax, denom, TG);
        att_dot<<<(TN * 64 + 255) / 256, 256, 0, stream>>>(node, hl, batch, ebuf, emax, TN);
        att_exp<<<(TN + 255) / 256, 256, 0, stream>>>(ebuf, emax, denom, batch, TN);
        att_scatter<<<(TN * 32 + 255) / 256, 256, 0, stream>>>(node, ebuf, denom, batch, qs, TN);
    }

    // ---- final FC ----
    final_fc<<<TG, 128, 0, stream>>>(qs, fc_w1, fc_b1, fc_w2, fc_b2, out);
}

// Round 3
// 1356.235 us; speedup vs baseline: 2.6128x; 2.6128x over previous
//
#include <hip/hip_runtime.h>
#include <hip/hip_bf16.h>

constexpr int TN = 100000;   // nodes
constexpr int TE = 200000;   // edges
constexpr int TG = 4000;     // graphs
constexpr int TH = 128;      // hidden

constexpr int CG = 12500;    // GRU row chunk (fp32 gi/gh in 38.4MB arena), 8 chunks
constexpr int CN = 50000;    // GIN-MLP row chunk (t in arena)
constexpr int CE = 50000;    // edge-pipe chunk

using short8 = __attribute__((ext_vector_type(8))) short;
using f32x4  = __attribute__((ext_vector_type(4))) float;
typedef __hip_bfloat16 bf16;

#define DEVINL __device__ __forceinline__
DEVINL float sigm(float x) { return 1.f / (1.f + expf(-x)); }

// ================= weight conversion =================
// dst[n][k] = bf16(src[k][n]) for src [rows=K][cols=N]
__global__ void conv_transpose_bf16(const float* __restrict__ src, bf16* __restrict__ dst,
                                    int K, int N) {
    int i = blockIdx.x * 256 + threadIdx.x;
    if (i >= K * N) return;
    int n = i / K, k = i % K;
    dst[i] = __float2bfloat16(src[k * N + n]);
}
__global__ void conv_bf16(const float* __restrict__ src, bf16* __restrict__ dst, int n) {
    int i = blockIdx.x * 256 + threadIdx.x;
    if (i < n) dst[i] = __float2bfloat16(src[i]);
}

// ================= projection (fp32 in, bf16 out) =================
__global__ void proj_bf16(const float* __restrict__ X, const float* __restrict__ W,
                          const float* __restrict__ b, bf16* __restrict__ out,
                          int M, int K) {
    int idx = blockIdx.x * 256 + threadIdx.x;
    if (idx >= M * TH) return;
    int m = idx >> 7, h = idx & 127;
    float acc = b[h];
    const float* xr = X + (size_t)m * K;
    for (int k = 0; k < K; ++k) acc = fmaf(xr[k], W[k * TH + h], acc);
    out[idx] = __float2bfloat16(acc);
}

// ================= CSR build =================
__global__ void count_deg(const int* __restrict__ ei_dst, int* __restrict__ deg, int En) {
    int e = blockIdx.x * 256 + threadIdx.x;
    if (e < En) atomicAdd(&deg[ei_dst[e]], 1);
}
__global__ void scan_block(const int* __restrict__ deg, int* __restrict__ rowptr,
                           int* __restrict__ bsum, int Nn) {
    __shared__ int sm[256];
    int tid = threadIdx.x;
    int gid = blockIdx.x * 256 + tid;
    int v = (gid < Nn) ? deg[gid] : 0;
    int x = v;
    sm[tid] = x; __syncthreads();
    for (int off = 1; off < 256; off <<= 1) {
        int t = (tid >= off) ? sm[tid - off] : 0;
        __syncthreads();
        x += t; sm[tid] = x;
        __syncthreads();
    }
    if (gid < Nn) rowptr[gid] = x - v;     // exclusive within block
    if (tid == 255) bsum[blockIdx.x] = x;  // block total
}
__global__ void scan_bsum(const int* __restrict__ bsum, int* __restrict__ bsumx, int nb) {
    __shared__ int sm[512];
    int tid = threadIdx.x;
    int v = (tid < nb) ? bsum[tid] : 0;
    int x = v;
    sm[tid] = x; __syncthreads();
    for (int off = 1; off < 512; off <<= 1) {
        int t = (tid >= off) ? sm[tid - off] : 0;
        __syncthreads();
        x += t; sm[tid] = x;
        __syncthreads();
    }
    if (tid < nb) bsumx[tid] = x - v;
}
__global__ void add_off(int* __restrict__ rowptr, const int* __restrict__ bsumx,
                        int Nn, int Etot) {
    int gid = blockIdx.x * 256 + threadIdx.x;
    if (gid < Nn) rowptr[gid] += bsumx[gid >> 8];
    if (gid == 0) rowptr[Nn] = Etot;
}
__global__ void fill_csr(const int* __restrict__ ei_dst, const int* __restrict__ rowptr,
                         int* __restrict__ cur, int* __restrict__ eidx, int En) {
    int e = blockIdx.x * 256 + threadIdx.x;
    if (e >= En) return;
    int d = ei_dst[e];
    int p = atomicAdd(&cur[d], 1);
    eidx[rowptr[d] + p] = e;
}
// gptr[g] = first node index of graph g (batch sorted)
__global__ void build_gptr(const int* __restrict__ batch, int* __restrict__ gptr,
                           int Nn, int Gn) {
    int n = blockIdx.x * 256 + threadIdx.x;
    if (n >= Nn) return;
    int bc = batch[n];
    int bp = (n == 0) ? -1 : batch[n - 1];
    for (int g = bp + 1; g <= bc; ++g) gptr[g] = n;
    if (n == Nn - 1) for (int g = bc + 1; g <= Gn; ++g) gptr[g] = Nn;
}

// ================= aggregation: zb[n] = (1+eps)*node[n] + sum relu(node[src]+edge) ====
template<bool LAYER0>
__global__ void aggregate_k(const bf16* __restrict__ node, const bf16* __restrict__ e1,
                            const float* __restrict__ edge_attr,
                            const float* __restrict__ edge_w, const float* __restrict__ edge_b,
                            const int* __restrict__ ei_src, const int* __restrict__ rowptr,
                            const int* __restrict__ eidx, const float* __restrict__ eps,
                            int l, bf16* __restrict__ zb, int Nn) {
    int n = blockIdx.x * 2 + (threadIdx.x >> 7);
    int c = threadIdx.x & 127;
    if (n >= Nn) return;
    float acc = (1.f + eps[l]) * __bfloat162float(node[(size_t)n * TH + c]);
    int s0 = rowptr[n], s1 = rowptr[n + 1];
    for (int i = s0; i < s1; ++i) {
        int e = eidx[i];
        int src = ei_src[e];
        float nv = __bfloat162float(node[(size_t)src * TH + c]);
        float ev;
        if (LAYER0) {
            const float* ea = edge_attr + (size_t)e * 4;
            ev = edge_b[c];
            ev = fmaf(ea[0], edge_w[c], ev);
            ev = fmaf(ea[1], edge_w[TH + c], ev);
            ev = fmaf(ea[2], edge_w[2 * TH + c], ev);
            ev = fmaf(ea[3], edge_w[3 * TH + c], ev);
        } else {
            ev = __bfloat162float(e1[(size_t)e * TH + c]);
        }
        acc += fmaxf(nv + ev, 0.f);
    }
    zb[(size_t)n * TH + c] = __float2bfloat16(acc);
}

// ================= bf16 MFMA GEMM, K=128 fixed =================
// A [M][128] bf16 row-major; Bt [Nc][128] bf16 (i.e. B transposed); C [M][Nc]
template<bool RELU, bool OUT_BF16>
__global__ __launch_bounds__(256) void mfma_gemm_k128(
    const ushort* __restrict__ A, const ushort* __restrict__ Bt,
    const float* __restrict__ bias, void* __restrict__ C, int M, int Nc)
{
    constexpr int KP = 136;  // padded row (bf16): stride 272B -> 4-bank shift/row
    __shared__ ushort As[128 * KP];
    __shared__ ushort Bs[128 * KP];
    const int tid = threadIdx.x;
    const int bm = blockIdx.x * 128;
    const int bn = blockIdx.y * 128;
#pragma unroll
    for (int p = 0; p < 8; ++p) {
        int ch = p * 256 + tid;          // 2048 16B-chunks per tile
        int r  = ch >> 4;
        int kc = (ch & 15) * 8;
        uint4 va = make_uint4(0u, 0u, 0u, 0u);
        int ra = bm + r;
        if (ra < M) va = *(const uint4*)(A + (size_t)ra * 128 + kc);
        *(uint4*)(&As[r * KP + kc]) = va;
        uint4 vb = *(const uint4*)(Bt + (size_t)(bn + r) * 128 + kc);
        *(uint4*)(&Bs[r * KP + kc]) = vb;
    }
    __syncthreads();
    const int lane = tid & 63;
    const int wid  = tid >> 6;
    const int wm = (wid & 1) * 64, wn = (wid >> 1) * 64;
    const int lr = lane & 15;
    const int lq = lane >> 4;
    f32x4 acc[4][4] = {};
#pragma unroll
    for (int ks = 0; ks < 4; ++ks) {
        int kb = ks * 32 + lq * 8;
        short8 af[4], bfr[4];
#pragma unroll
        for (int i = 0; i < 4; ++i) {
            af[i]  = *(const short8*)(&As[(wm + i * 16 + lr) * KP + kb]);
            bfr[i] = *(const short8*)(&Bs[(wn + i * 16 + lr) * KP + kb]);
        }
#pragma unroll
        for (int mi = 0; mi < 4; ++mi)
#pragma unroll
            for (int ni = 0; ni < 4; ++ni)
                acc[mi][ni] = __builtin_amdgcn_mfma_f32_16x16x32_bf16(af[mi], bfr[ni], acc[mi][ni], 0, 0, 0);
    }
#pragma unroll
    for (int mi = 0; mi < 4; ++mi) {
#pragma unroll
        for (int reg = 0; reg < 4; ++reg) {
            int row = bm + wm + mi * 16 + lq * 4 + reg;
            if (row >= M) continue;
#pragma unroll
            for (int ni = 0; ni < 4; ++ni) {
                int col = bn + wn + ni * 16 + lr;
                float v = acc[mi][ni][reg] + bias[col];
                if (RELU) v = fmaxf(v, 0.f);
                if (OUT_BF16) ((bf16*)C)[(size_t)row * Nc + col] = __float2bfloat16(v);
                else          ((float*)C)[(size_t)row * Nc + col] = v;
            }
        }
    }
}

// ================= GRU gates (chunk), node bf16 updated in place ==========
__global__ void gru_gates(const float* __restrict__ gi, const float* __restrict__ gh,
                          bf16* __restrict__ node, int NH) {
    int i = blockIdx.x * 256 + threadIdx.x;
    if (i >= NH) return;
    size_t n = (size_t)(i >> 7);
    int h = i & 127;
    const float* gir = gi + n * 384;
    const float* ghr = gh + n * 384;
    float r  = sigm(gir[h] + ghr[h]);
    float zt = sigm(gir[128 + h] + ghr[128 + h]);
    float nn = tanhf(gir[256 + h] + r * ghr[256 + h]);
    float ho = __bfloat162float(node[i]);
    node[i] = __float2bfloat16((1.f - zt) * nn + zt * ho);
}

// ================= fp32 SGEMM (set2set only, small) =================
template<bool TRANSB, bool ACC>
__global__ __launch_bounds__(256) void sgemm_k(
    const float* __restrict__ A, const float* __restrict__ B,
    const float* __restrict__ bias, float* __restrict__ C,
    int M, int K, int Nc)
{
    constexpr int BM = 64, BN = 64, BK = 32, PAD = 4;
    __shared__ float As[BK][BM + PAD];
    __shared__ float Bs[BK][BN + PAD];
    const int tid = threadIdx.x;
    const int bm = blockIdx.x * BM;
    const int bn = blockIdx.y * BN;
    const int tx = tid & 15, ty = tid >> 4;
    float acc[4][4] = {};
    for (int k0 = 0; k0 < K; k0 += BK) {
#pragma unroll
        for (int i = 0; i < 2; ++i) {
            int idx = tid + i * 256;
            int r = idx >> 3, kq = (idx & 7) * 4;
            int row = bm + r;
            float4 v = make_float4(0.f, 0.f, 0.f, 0.f);
            if (row < M) v = *(const float4*)(A + (size_t)row * K + k0 + kq);
            As[kq + 0][r] = v.x; As[kq + 1][r] = v.y;
            As[kq + 2][r] = v.z; As[kq + 3][r] = v.w;
        }
        if (TRANSB) {
#pragma unroll
            for (int i = 0; i < 2; ++i) {
                int idx = tid + i * 256;
                int n = idx >> 3, kq = (idx & 7) * 4;
                float4 v = *(const float4*)(B + (size_t)(bn + n) * K + k0 + kq);
                Bs[kq + 0][n] = v.x; Bs[kq + 1][n] = v.y;
                Bs[kq + 2][n] = v.z; Bs[kq + 3][n] = v.w;
            }
        } else {
#pragma unroll
            for (int i = 0; i < 2; ++i) {
                int idx = tid + i * 256;
                int kk = idx >> 4, nq = (idx & 15) * 4;
                float4 v = *(const float4*)(B + (size_t)(k0 + kk) * Nc + bn + nq);
                Bs[kk][nq + 0] = v.x; Bs[kk][nq + 1] = v.y;
                Bs[kk][nq + 2] = v.z; Bs[kk][nq + 3] = v.w;
            }
        }
        __syncthreads();
#pragma unroll
        for (int k = 0; k < BK; ++k) {
            float4 av = *(const float4*)&As[k][ty * 4];
            float4 bv = *(const float4*)&Bs[k][tx * 4];
            float a4[4] = {av.x, av.y, av.z, av.w};
            float b4[4] = {bv.x, bv.y, bv.z, bv.w};
#pragma unroll
            for (int i = 0; i < 4; ++i)
#pragma unroll
                for (int j = 0; j < 4; ++j)
                    acc[i][j] = fmaf(a4[i], b4[j], acc[i][j]);
        }
        __syncthreads();
    }
#pragma unroll
    for (int i = 0; i < 4; ++i) {
        int row = bm + ty * 4 + i;
        if (row >= M) continue;
#pragma unroll
        for (int j = 0; j < 4; ++j) {
            int col = bn + tx * 4 + j;
            float v = acc[i][j] + bias[col];
            if (ACC) v += C[(size_t)row * Nc + col];
            C[(size_t)row * Nc + col] = v;
        }
    }
}

// ================= LSTM gates =================
__global__ void lstm_gates(const float* __restrict__ g4, float* __restrict__ cl,
                           float* __restrict__ hl, float* __restrict__ qs, int Gn) {
    int i = blockIdx.x * 256 + threadIdx.x;
    if (i >= Gn * TH) return;
    int g = i >> 7, h = i & 127;
    const float* row = g4 + (size_t)g * 512;
    float ig = sigm(row[h]);
    float fg = sigm(row[128 + h]);
    float gg = tanhf(row[256 + h]);
    float og = sigm(row[384 + h]);
    float c = fg * cl[i] + ig * gg;
    cl[i] = c;
    float hv = og * tanhf(c);
    hl[i] = hv;
    qs[(size_t)g * 256 + h] = hv;
}

// ================= fused per-graph attention (batch sorted) ==============
__global__ __launch_bounds__(256) void att_fused(
    const bf16* __restrict__ node, const float* __restrict__ hl,
    const int* __restrict__ gptr, float* __restrict__ qs)
{
    __shared__ float q[128];
    __shared__ float es[512];
    __shared__ float red[8];
    int g = blockIdx.x;
    int tid = threadIdx.x, lane = tid & 63, wid = tid >> 6;
    int n0 = gptr[g], n1 = gptr[g + 1];
    int cnt = n1 - n0; if (cnt > 512) cnt = 512;
    if (tid < 128) q[tid] = hl[(size_t)g * TH + tid];
    __syncthreads();
    // dots (one wave per node)
    for (int i = wid; i < cnt; i += 4) {
        const bf16* nr = node + (size_t)(n0 + i) * TH;
        float p = __bfloat162float(nr[lane]) * q[lane]
                + __bfloat162float(nr[lane + 64]) * q[lane + 64];
        for (int off = 32; off; off >>= 1) p += __shfl_down(p, off);
        if (lane == 0) es[i] = p;
    }
    __syncthreads();
    // segment max
    float m = -1e30f;
    for (int i = tid; i < cnt; i += 256) m = fmaxf(m, es[i]);
    for (int off = 32; off; off >>= 1) m = fmaxf(m, __shfl_down(m, off));
    if (lane == 0) red[wid] = m;
    __syncthreads();
    m = fmaxf(fmaxf(red[0], red[1]), fmaxf(red[2], red[3]));
    // exp + sum
    float s = 0.f;
    for (int i = tid; i < cnt; i += 256) { float ex = expf(es[i] - m); es[i] = ex; s += ex; }
    for (int off = 32; off; off >>= 1) s += __shfl_down(s, off);
    if (lane == 0) red[4 + wid] = s;
    __syncthreads();
    s = red[4] + red[5] + red[6] + red[7];
    float inv = 1.f / fmaxf(s, 1e-9f);
    // r[c] = sum_i a_i * node[i][c]   (two halves of the block)
    int c = tid & 127, half = tid >> 7;
    float r = 0.f;
    for (int i = half; i < cnt; i += 2)
        r += es[i] * __bfloat162float(node[(size_t)(n0 + i) * TH + c]);
    __syncthreads();
    if (half == 1) es[c] = r;
    __syncthreads();
    if (half == 0) qs[(size_t)g * 256 + 128 + c] = (r + es[c]) * inv;
}

// ================= final FC =================
__global__ __launch_bounds__(128) void final_fc(const float* __restrict__ qs,
                                                const float* __restrict__ w1,
                                                const float* __restrict__ b1,
                                                const float* __restrict__ w2,
                                                const float* __restrict__ b2,
                                                float* __restrict__ out) {
    __shared__ float q[256];
    __shared__ float red[2];
    int g = blockIdx.x, t = threadIdx.x;
    q[t] = qs[(size_t)g * 256 + t];
    q[t + 128] = qs[(size_t)g * 256 + 128 + t];
    __syncthreads();
    float acc = b1[t];
    for (int k = 0; k < 256; ++k) acc = fmaf(q[k], w1[k * TH + t], acc);
    acc = fmaxf(acc, 0.f);
    float p = acc * w2[t];
    for (int off = 32; off; off >>= 1) p += __shfl_down(p, off);
    if ((t & 63) == 0) red[t >> 6] = p;
    __syncthreads();
    if (t == 0) out[g] = red[0] + red[1] + b2[0];
}

// ---------------------------------------------------------------------------
template<bool RELU, bool OBF>
static void launch_mfma(const bf16* A, const bf16* Bt, const float* bias, void* C,
                        int M, int Nc, hipStream_t s) {
    dim3 grid((M + 127) / 128, Nc / 128);
    hipLaunchKernelGGL((mfma_gemm_k128<RELU, OBF>), grid, dim3(256), 0, s,
                       (const ushort*)A, (const ushort*)Bt, bias, C, M, Nc);
}
template<bool TB, bool AC>
static void launch_sgemm(const float* A, const float* B, const float* bias, float* C,
                         int M, int K, int Nc, hipStream_t s) {
    dim3 grid((M + 63) / 64, Nc / 64);
    hipLaunchKernelGGL((sgemm_k<TB, AC>), grid, dim3(256), 0, s, A, B, bias, C, M, K, Nc);
}

extern "C" void kernel_launch(void* const* d_in, const int* in_sizes, int n_in,
                              void* d_out, int out_size, void* d_ws, size_t ws_size,
                              hipStream_t stream) {
    const float* x         = (const float*)d_in[0];
    const float* edge_attr = (const float*)d_in[1];
    const int*   edge_index= (const int*)d_in[2];
    const int*   batch     = (const int*)d_in[3];
    const float* node_w    = (const float*)d_in[4];
    const float* node_b    = (const float*)d_in[5];
    const float* edge_w    = (const float*)d_in[6];
    const float* edge_b    = (const float*)d_in[7];
    const float* eps       = (const float*)d_in[8];
    const float* gin_w1    = (const float*)d_in[9];
    const float* gin_b1    = (const float*)d_in[10];
    const float* gin_w2    = (const float*)d_in[11];
    const float* gin_b2    = (const float*)d_in[12];
    const float* em_w1     = (const float*)d_in[13];
    const float* em_b1     = (const float*)d_in[14];
    const float* em_w2     = (const float*)d_in[15];
    const float* em_b2     = (const float*)d_in[16];
    const float* gru_wih   = (const float*)d_in[17];
    const float* gru_whh   = (const float*)d_in[18];
    const float* gru_bih   = (const float*)d_in[19];
    const float* gru_bhh   = (const float*)d_in[20];
    const float* lstm_wih  = (const float*)d_in[21];
    const float* lstm_whh  = (const float*)d_in[22];
    const float* lstm_bih  = (const float*)d_in[23];
    const float* lstm_bhh  = (const float*)d_in[24];
    const float* fc_w1     = (const float*)d_in[25];
    const float* fc_b1     = (const float*)d_in[26];
    const float* fc_w2     = (const float*)d_in[27];
    const float* fc_b2     = (const float*)d_in[28];
    float* out = (float*)d_out;
    const int* ei_src = edge_index;
    const int* ei_dst = edge_index + TE;

    // ---- workspace layout (bytes) ----
    char* base = (char*)d_ws;
    size_t off = 0;
    auto alloc = [&](size_t bytes) { void* p = base + off; off += (bytes + 15) & ~size_t(15); return p; };
    bf16*  nodeb = (bf16*)alloc((size_t)TN * TH * 2);          // 25.6 MB (h state, bf16)
    bf16*  zb    = (bf16*)alloc((size_t)TN * TH * 2);          // 25.6 MB (agg out, then m)
    float* gruA  = (float*)alloc((size_t)CG * 384 * 4);        // 19.2 MB
    float* gruB  = (float*)alloc((size_t)CG * 384 * 4);        // 19.2 MB (arena = gruA..gruB)
    bf16*  e1b   = (bf16*)alloc((size_t)TE * TH * 2);          // 51.2 MB (layer-1 edge feats)
    int*   deg   = (int*)alloc((size_t)TN * 4);
    int*   rowptr= (int*)alloc((size_t)(TN + 1) * 4);
    int*   cur   = (int*)alloc((size_t)TN * 4);
    int*   eidx  = (int*)alloc((size_t)TE * 4);
    int*   bsum  = (int*)alloc(512 * 4);
    int*   bsumx = (int*)alloc(512 * 4);
    int*   gptr  = (int*)alloc((size_t)(TG + 1) * 4);
    bf16*  w_gin1t = (bf16*)alloc(2 * TH * TH * 2);
    bf16*  w_gin2t = (bf16*)alloc(2 * TH * TH * 2);
    bf16*  w_em1t  = (bf16*)alloc(TH * TH * 2);
    bf16*  w_em2t  = (bf16*)alloc(TH * TH * 2);
    bf16*  w_wih   = (bf16*)alloc(384 * TH * 2);
    bf16*  w_whh   = (bf16*)alloc(384 * TH * 2);
    if (ws_size < off) return;  // graceful fail -> absmax == max|ref| signature

    // set2set state overlays e1b (e1b dead after layer-1 aggregation)
    float* qs = (float*)e1b;                 // G*256
    float* hl = qs + (size_t)TG * 256;       // G*128
    float* cl = hl + (size_t)TG * TH;        // G*128
    float* g4 = cl + (size_t)TG * TH;        // G*512
    // edge/MLP chunk scratch overlays the GRU arena
    bf16* arena = (bf16*)gruA;               // 38.4 MB

    // ---- CSR + gptr build ----
    hipMemsetAsync(deg, 0, (size_t)TN * 4, stream);
    hipMemsetAsync(cur, 0, (size_t)TN * 4, stream);
    count_deg<<<(TE + 255) / 256, 256, 0, stream>>>(ei_dst, deg, TE);
    int nb = (TN + 255) / 256;  // 391
    scan_block<<<nb, 256, 0, stream>>>(deg, rowptr, bsum, TN);
    scan_bsum<<<1, 512, 0, stream>>>(bsum, bsumx, nb);
    add_off<<<nb, 256, 0, stream>>>(rowptr, bsumx, TN, TE);
    fill_csr<<<(TE + 255) / 256, 256, 0, stream>>>(ei_dst, rowptr, cur, eidx, TE);
    build_gptr<<<(TN + 255) / 256, 256, 0, stream>>>(batch, gptr, TN, TG);

    // ---- weight conversion ----
    int wgrid = (TH * TH + 255) / 256;
    for (int l = 0; l < 2; ++l) {
        conv_transpose_bf16<<<wgrid, 256, 0, stream>>>(gin_w1 + (size_t)l * TH * TH, w_gin1t + (size_t)l * TH * TH, TH, TH);
        conv_transpose_bf16<<<wgrid, 256, 0, stream>>>(gin_w2 + (size_t)l * TH * TH, w_gin2t + (size_t)l * TH * TH, TH, TH);
    }
    conv_transpose_bf16<<<wgrid, 256, 0, stream>>>(em_w1, w_em1t, TH, TH);
    conv_transpose_bf16<<<wgrid, 256, 0, stream>>>(em_w2, w_em2t, TH, TH);
    conv_bf16<<<(384 * TH + 255) / 256, 256, 0, stream>>>(gru_wih, w_wih, 384 * TH);
    conv_bf16<<<(384 * TH + 255) / 256, 256, 0, stream>>>(gru_whh, w_whh, 384 * TH);

    // ---- node projection (bf16 h state) ----
    proj_bf16<<<(TN * TH + 255) / 256, 256, 0, stream>>>(x, node_w, node_b, nodeb, TN, 14);

    // ---- edge pipeline: e1 = MLP(proj(edge_attr)) for layer-1 aggregation ----
    {
        bf16* e0c = arena;
        bf16* tc  = arena + (size_t)CE * TH;
        for (int e0 = 0; e0 < TE; e0 += CE) {
            proj_bf16<<<(CE * TH + 255) / 256, 256, 0, stream>>>(
                edge_attr + (size_t)e0 * 4, edge_w, edge_b, e0c, CE, 4);
            launch_mfma<true,  true>(e0c, w_em1t, em_b1, tc, CE, TH, stream);
            launch_mfma<false, true>(tc, w_em2t, em_b2, e1b + (size_t)e0 * TH, CE, TH, stream);
        }
    }

    // ---- GIN layers ----
    for (int l = 0; l < 2; ++l) {
        if (l == 0)
            aggregate_k<true><<<(TN + 1) / 2, 256, 0, stream>>>(
                nodeb, nullptr, edge_attr, edge_w, edge_b, ei_src, rowptr, eidx, eps, l, zb, TN);
        else
            aggregate_k<false><<<(TN + 1) / 2, 256, 0, stream>>>(
                nodeb, e1b, nullptr, nullptr, nullptr, ei_src, rowptr, eidx, eps, l, zb, TN);
        // GIN MLP: t = relu(z@w1+b1); m = t@w2+b2 (in-place over zb; Nc=128 so safe)
        for (int r0 = 0; r0 < TN; r0 += CN) {
            launch_mfma<true,  true>(zb + (size_t)r0 * TH, w_gin1t + (size_t)l * TH * TH,
                                     gin_b1 + l * TH, arena, CN, TH, stream);
            launch_mfma<false, true>(arena, w_gin2t + (size_t)l * TH * TH,
                                     gin_b2 + l * TH, zb + (size_t)r0 * TH, CN, TH, stream);
        }
        // GRU (fp32 pre-activations, chunked)
        for (int r0 = 0; r0 < TN; r0 += CG) {
            launch_mfma<false, false>(zb + (size_t)r0 * TH, w_wih, gru_bih, gruA, CG, 384, stream);
            launch_mfma<false, false>(nodeb + (size_t)r0 * TH, w_whh, gru_bhh, gruB, CG, 384, stream);
            gru_gates<<<(CG * TH + 255) / 256, 256, 0, stream>>>(gruA, gruB, nodeb + (size_t)r0 * TH, CG * TH);
        }
    }

    // ---- Set2Set (3 steps) ----
    hipMemsetAsync(qs, 0, (size_t)TG * 512 * 4, stream);  // qs + hl + cl
    for (int s = 0; s < 3; ++s) {
        launch_sgemm<true, false>(qs, lstm_wih, lstm_bih, g4, TG, 2 * TH, 4 * TH, stream);
        launch_sgemm<true, true >(hl, lstm_whh, lstm_bhh, g4, TG, TH,     4 * TH, stream);
        lstm_gates<<<(TG * TH + 255) / 256, 256, 0, stream>>>(g4, cl, hl, qs, TG);
        att_fused<<<TG, 256, 0, stream>>>(nodeb, hl, gptr, qs);
    }

    // ---- final FC ----
    final_fc<<<TG, 128, 0, stream>>>(qs, fc_w1, fc_b1, fc_w2, fc_b2, out);
}

// Round 4
// 933.076 us; speedup vs baseline: 3.7977x; 1.4535x over previous
//
#include <hip/hip_runtime.h>
#include <hip/hip_bf16.h>

constexpr int TN = 100000;   // nodes
constexpr int TE = 200000;   // edges
constexpr int TG = 4000;     // graphs
constexpr int TH = 128;      // hidden

using short8 = __attribute__((ext_vector_type(8))) short;
using f32x4  = __attribute__((ext_vector_type(4))) float;
typedef __hip_bfloat16 bf16;

#define DEVINL __device__ __forceinline__
DEVINL float sigm(float x) { return 1.f / (1.f + expf(-x)); }

// ================= weight conversion =================
// 6 transposed 128x128 mats -> w6 (dst[n][k] = src[k][n])
__global__ void conv6(const float* __restrict__ s0, const float* __restrict__ s1,
                      const float* __restrict__ s2, const float* __restrict__ s3,
                      const float* __restrict__ s4, const float* __restrict__ s5,
                      bf16* __restrict__ dst) {
    int i = blockIdx.x * 256 + threadIdx.x;
    if (i >= 6 * TH * TH) return;
    int m = i >> 14, r = i & 16383;
    int n = r >> 7, k = r & 127;
    const float* s = (m == 0) ? s0 : (m == 1) ? s1 : (m == 2) ? s2
                   : (m == 3) ? s3 : (m == 4) ? s4 : s5;
    dst[i] = __float2bfloat16(s[k * TH + n]);
}
// straight copy of gru weights (already B^T layout [384][128])
__global__ void conv2(const float* __restrict__ a, const float* __restrict__ b,
                      bf16* __restrict__ dst) {
    int i = blockIdx.x * 256 + threadIdx.x;
    if (i >= 2 * 384 * TH) return;
    const float* s = (i < 384 * TH) ? a : b;
    int r = (i < 384 * TH) ? i : i - 384 * TH;
    dst[i] = __float2bfloat16(s[r]);
}

// ================= fast projection: 16 rows/block, 8 ch/thread =================
template<int K>
__global__ __launch_bounds__(256) void proj16(const float* __restrict__ X,
                                              const float* __restrict__ W,
                                              const float* __restrict__ b,
                                              ushort* __restrict__ out, int M) {
    __shared__ float xs[16][K];
    int tid = threadIdx.x;
    int bm = blockIdx.x * 16;
    if (tid < 16 * K) {
        int r = tid / K, k = tid % K;
        xs[r][k] = (bm + r < M) ? X[(size_t)(bm + r) * K + k] : 0.f;
    }
    __syncthreads();
    int r = tid >> 4, h0 = (tid & 15) * 8;
    if (bm + r >= M) return;
    float acc[8];
#pragma unroll
    for (int j = 0; j < 8; ++j) acc[j] = b[h0 + j];
#pragma unroll
    for (int k = 0; k < K; ++k) {
        float xv = xs[r][k];
        float4 w0 = *(const float4*)(W + k * TH + h0);
        float4 w1 = *(const float4*)(W + k * TH + h0 + 4);
        acc[0] = fmaf(xv, w0.x, acc[0]); acc[1] = fmaf(xv, w0.y, acc[1]);
        acc[2] = fmaf(xv, w0.z, acc[2]); acc[3] = fmaf(xv, w0.w, acc[3]);
        acc[4] = fmaf(xv, w1.x, acc[4]); acc[5] = fmaf(xv, w1.y, acc[5]);
        acc[6] = fmaf(xv, w1.z, acc[6]); acc[7] = fmaf(xv, w1.w, acc[7]);
    }
    ushort o[8];
#pragma unroll
    for (int j = 0; j < 8; ++j) {
        bf16 v = __float2bfloat16(acc[j]);
        o[j] = *(ushort*)&v;
    }
    *(uint4*)(out + (size_t)(bm + r) * TH + h0) = *(uint4*)o;
}

// ================= CSR build =================
__global__ void count_deg(const int* __restrict__ ei_dst, int* __restrict__ deg, int En) {
    int e = blockIdx.x * 256 + threadIdx.x;
    if (e < En) atomicAdd(&deg[ei_dst[e]], 1);
}
__global__ void scan_block(const int* __restrict__ deg, int* __restrict__ rowptr,
                           int* __restrict__ bsum, int Nn) {
    __shared__ int sm[256];
    int tid = threadIdx.x;
    int gid = blockIdx.x * 256 + tid;
    int v = (gid < Nn) ? deg[gid] : 0;
    int x = v;
    sm[tid] = x; __syncthreads();
    for (int off = 1; off < 256; off <<= 1) {
        int t = (tid >= off) ? sm[tid - off] : 0;
        __syncthreads();
        x += t; sm[tid] = x;
        __syncthreads();
    }
    if (gid < Nn) rowptr[gid] = x - v;
    if (tid == 255) bsum[blockIdx.x] = x;
}
__global__ void scan_bsum(const int* __restrict__ bsum, int* __restrict__ bsumx, int nb) {
    __shared__ int sm[512];
    int tid = threadIdx.x;
    int v = (tid < nb) ? bsum[tid] : 0;
    int x = v;
    sm[tid] = x; __syncthreads();
    for (int off = 1; off < 512; off <<= 1) {
        int t = (tid >= off) ? sm[tid - off] : 0;
        __syncthreads();
        x += t; sm[tid] = x;
        __syncthreads();
    }
    if (tid < nb) bsumx[tid] = x - v;
}
__global__ void add_off(int* __restrict__ rowptr, const int* __restrict__ bsumx,
                        int Nn, int Etot) {
    int gid = blockIdx.x * 256 + threadIdx.x;
    if (gid < Nn) rowptr[gid] += bsumx[gid >> 8];
    if (gid == 0) rowptr[Nn] = Etot;
}
__global__ void fill_csr(const int* __restrict__ ei_dst, const int* __restrict__ rowptr,
                         int* __restrict__ cur, int* __restrict__ eidx, int En) {
    int e = blockIdx.x * 256 + threadIdx.x;
    if (e >= En) return;
    int d = ei_dst[e];
    int p = atomicAdd(&cur[d], 1);
    eidx[rowptr[d] + p] = e;
}
__global__ void build_gptr(const int* __restrict__ batch, int* __restrict__ gptr,
                           int Nn, int Gn) {
    int n = blockIdx.x * 256 + threadIdx.x;
    if (n >= Nn) return;
    int bc = batch[n];
    int bp = (n == 0) ? -1 : batch[n - 1];
    for (int g = bp + 1; g <= bc; ++g) gptr[g] = n;
    if (n == Nn - 1) for (int g = bc + 1; g <= Gn; ++g) gptr[g] = Nn;
}

// ========== aggregation: zb[n] = (1+eps)*node[n] + sum relu(node[src]+ef[e]) ==========
__global__ void aggregate_k(const bf16* __restrict__ node, const bf16* __restrict__ ef,
                            const int* __restrict__ ei_src, const int* __restrict__ rowptr,
                            const int* __restrict__ eidx, const float* __restrict__ eps,
                            int l, bf16* __restrict__ zb, int Nn) {
    int n = blockIdx.x * 2 + (threadIdx.x >> 7);
    int c = threadIdx.x & 127;
    if (n >= Nn) return;
    float acc = (1.f + eps[l]) * __bfloat162float(node[(size_t)n * TH + c]);
    int s0 = rowptr[n], s1 = rowptr[n + 1];
    for (int i = s0; i < s1; ++i) {
        int e = eidx[i];
        int src = ei_src[e];
        float nv = __bfloat162float(node[(size_t)src * TH + c]);
        float ev = __bfloat162float(ef[(size_t)e * TH + c]);
        acc += fmaxf(nv + ev, 0.f);
    }
    zb[(size_t)n * TH + c] = __float2bfloat16(acc);
}

// ================= bf16 MFMA GEMM, K=128, Nc=128 (in-place-safe) =================
template<bool RELU>
__global__ __launch_bounds__(256) void mfma_gemm_k128(
    const ushort* __restrict__ A, const ushort* __restrict__ Bt,
    const float* __restrict__ bias, ushort* __restrict__ C, int M)
{
    constexpr int KP = 136;
    __shared__ ushort As[128 * KP];
    __shared__ ushort Bs[128 * KP];
    const int tid = threadIdx.x;
    const int bm = blockIdx.x * 128;
#pragma unroll
    for (int p = 0; p < 8; ++p) {
        int ch = p * 256 + tid;
        int r  = ch >> 4;
        int kc = (ch & 15) * 8;
        uint4 va = make_uint4(0u, 0u, 0u, 0u);
        int ra = bm + r;
        if (ra < M) va = *(const uint4*)(A + (size_t)ra * 128 + kc);
        *(uint4*)(&As[r * KP + kc]) = va;
        uint4 vb = *(const uint4*)(Bt + (size_t)r * 128 + kc);
        *(uint4*)(&Bs[r * KP + kc]) = vb;
    }
    __syncthreads();
    const int lane = tid & 63;
    const int wid  = tid >> 6;
    const int wm = (wid & 1) * 64, wn = (wid >> 1) * 64;
    const int lr = lane & 15;
    const int lq = lane >> 4;
    f32x4 acc[4][4] = {};
#pragma unroll
    for (int ks = 0; ks < 4; ++ks) {
        int kb = ks * 32 + lq * 8;
        short8 af[4], bfr[4];
#pragma unroll
        for (int i = 0; i < 4; ++i) {
            af[i]  = *(const short8*)(&As[(wm + i * 16 + lr) * KP + kb]);
            bfr[i] = *(const short8*)(&Bs[(wn + i * 16 + lr) * KP + kb]);
        }
#pragma unroll
        for (int mi = 0; mi < 4; ++mi)
#pragma unroll
            for (int ni = 0; ni < 4; ++ni)
                acc[mi][ni] = __builtin_amdgcn_mfma_f32_16x16x32_bf16(af[mi], bfr[ni], acc[mi][ni], 0, 0, 0);
    }
#pragma unroll
    for (int mi = 0; mi < 4; ++mi) {
#pragma unroll
        for (int reg = 0; reg < 4; ++reg) {
            int row = bm + wm + mi * 16 + lq * 4 + reg;
            if (row >= M) continue;
#pragma unroll
            for (int ni = 0; ni < 4; ++ni) {
                int col = wn + ni * 16 + lr;
                float v = acc[mi][ni][reg] + bias[col];
                if (RELU) v = fmaxf(v, 0.f);
                bf16 bv = __float2bfloat16(v);
                C[(size_t)row * 128 + col] = *(ushort*)&bv;
            }
        }
    }
}

// ================= fused GRU: both GEMMs + gates, one launch =================
// block = 64 rows, 4 waves; wave w covers h-sub [w*32, w*32+32) in each gate group
__global__ __launch_bounds__(256) void gru_fused(
    const ushort* __restrict__ mfeat,   // [N][128] bf16 (GIN MLP output)
    const ushort* __restrict__ wih,     // [384][128] bf16 (B^T)
    const ushort* __restrict__ whh,     // [384][128] bf16
    const float* __restrict__ bih, const float* __restrict__ bhh,
    ushort* __restrict__ node, int Nn)  // [N][128] bf16, in/out
{
    constexpr int KP = 136;
    __shared__ ushort Ms[64 * KP];
    __shared__ ushort Hs[64 * KP];
    const int tid = threadIdx.x;
    const int bm = blockIdx.x * 64;
#pragma unroll
    for (int p = 0; p < 4; ++p) {
        int ch = p * 256 + tid;
        int r = ch >> 4, kc = (ch & 15) * 8;
        int row = bm + r;
        uint4 vm = make_uint4(0u,0u,0u,0u), vh = make_uint4(0u,0u,0u,0u);
        if (row < Nn) {
            vm = *(const uint4*)(mfeat + (size_t)row * 128 + kc);
            vh = *(const uint4*)(node + (size_t)row * 128 + kc);
        }
        *(uint4*)(&Ms[r * KP + kc]) = vm;
        *(uint4*)(&Hs[r * KP + kc]) = vh;
    }
    __syncthreads();
    const int lane = tid & 63, w = tid >> 6;
    const int lr = lane & 15, lq = lane >> 4;
    f32x4 gi[4][3][2] = {}, gh[4][3][2] = {};
#pragma unroll
    for (int ks = 0; ks < 4; ++ks) {
        int kb = ks * 32 + lq * 8;
        short8 am[4], ah[4];
#pragma unroll
        for (int rt = 0; rt < 4; ++rt) {
            am[rt] = *(const short8*)(&Ms[(rt * 16 + lr) * KP + kb]);
            ah[rt] = *(const short8*)(&Hs[(rt * 16 + lr) * KP + kb]);
        }
#pragma unroll
        for (int g = 0; g < 3; ++g) {
#pragma unroll
            for (int c2 = 0; c2 < 2; ++c2) {
                int col = g * 128 + w * 32 + c2 * 16 + lr;
                short8 bi = *(const short8*)(wih + (size_t)col * 128 + kb);
                short8 bh = *(const short8*)(whh + (size_t)col * 128 + kb);
#pragma unroll
                for (int rt = 0; rt < 4; ++rt) {
                    gi[rt][g][c2] = __builtin_amdgcn_mfma_f32_16x16x32_bf16(am[rt], bi, gi[rt][g][c2], 0, 0, 0);
                    gh[rt][g][c2] = __builtin_amdgcn_mfma_f32_16x16x32_bf16(ah[rt], bh, gh[rt][g][c2], 0, 0, 0);
                }
            }
        }
    }
    // gate epilogue (all operands aligned at same (row,h) across groups)
#pragma unroll
    for (int c2 = 0; c2 < 2; ++c2) {
        int h = w * 32 + c2 * 16 + lr;
        float bir = bih[h], biz = bih[128 + h], bin = bih[256 + h];
        float bhr = bhh[h], bhz = bhh[128 + h], bhn = bhh[256 + h];
#pragma unroll
        for (int rt = 0; rt < 4; ++rt) {
#pragma unroll
            for (int reg = 0; reg < 4; ++reg) {
                int lrow = rt * 16 + lq * 4 + reg;
                int row = bm + lrow;
                if (row >= Nn) continue;
                float r = sigm((gi[rt][0][c2][reg] + bir) + (gh[rt][0][c2][reg] + bhr));
                float z = sigm((gi[rt][1][c2][reg] + biz) + (gh[rt][1][c2][reg] + bhz));
                float n = tanhf((gi[rt][2][c2][reg] + bin) + r * (gh[rt][2][c2][reg] + bhn));
                float hold = __bfloat162float(*(const bf16*)&Hs[lrow * KP + h]);
                bf16 hv = __float2bfloat16((1.f - z) * n + z * hold);
                node[(size_t)row * 128 + h] = *(ushort*)&hv;
            }
        }
    }
}

// ================= fp32 SGEMM (set2set only) =================
template<bool TRANSB, bool ACC>
__global__ __launch_bounds__(256) void sgemm_k(
    const float* __restrict__ A, const float* __restrict__ B,
    const float* __restrict__ bias, float* __restrict__ C,
    int M, int K, int Nc)
{
    constexpr int BM = 64, BN = 64, BK = 32, PAD = 4;
    __shared__ float As[BK][BM + PAD];
    __shared__ float Bs[BK][BN + PAD];
    const int tid = threadIdx.x;
    const int bm = blockIdx.x * BM;
    const int bn = blockIdx.y * BN;
    const int tx = tid & 15, ty = tid >> 4;
    float acc[4][4] = {};
    for (int k0 = 0; k0 < K; k0 += BK) {
#pragma unroll
        for (int i = 0; i < 2; ++i) {
            int idx = tid + i * 256;
            int r = idx >> 3, kq = (idx & 7) * 4;
            int row = bm + r;
            float4 v = make_float4(0.f, 0.f, 0.f, 0.f);
            if (row < M) v = *(const float4*)(A + (size_t)row * K + k0 + kq);
            As[kq + 0][r] = v.x; As[kq + 1][r] = v.y;
            As[kq + 2][r] = v.z; As[kq + 3][r] = v.w;
        }
        if (TRANSB) {
#pragma unroll
            for (int i = 0; i < 2; ++i) {
                int idx = tid + i * 256;
                int n = idx >> 3, kq = (idx & 7) * 4;
                float4 v = *(const float4*)(B + (size_t)(bn + n) * K + k0 + kq);
                Bs[kq + 0][n] = v.x; Bs[kq + 1][n] = v.y;
                Bs[kq + 2][n] = v.z; Bs[kq + 3][n] = v.w;
            }
        } else {
#pragma unroll
            for (int i = 0; i < 2; ++i) {
                int idx = tid + i * 256;
                int kk = idx >> 4, nq = (idx & 15) * 4;
                float4 v = *(const float4*)(B + (size_t)(k0 + kk) * Nc + bn + nq);
                Bs[kk][nq + 0] = v.x; Bs[kk][nq + 1] = v.y;
                Bs[kk][nq + 2] = v.z; Bs[kk][nq + 3] = v.w;
            }
        }
        __syncthreads();
#pragma unroll
        for (int k = 0; k < BK; ++k) {
            float4 av = *(const float4*)&As[k][ty * 4];
            float4 bv = *(const float4*)&Bs[k][tx * 4];
            float a4[4] = {av.x, av.y, av.z, av.w};
            float b4[4] = {bv.x, bv.y, bv.z, bv.w};
#pragma unroll
            for (int i = 0; i < 4; ++i)
#pragma unroll
                for (int j = 0; j < 4; ++j)
                    acc[i][j] = fmaf(a4[i], b4[j], acc[i][j]);
        }
        __syncthreads();
    }
#pragma unroll
    for (int i = 0; i < 4; ++i) {
        int row = bm + ty * 4 + i;
        if (row >= M) continue;
#pragma unroll
        for (int j = 0; j < 4; ++j) {
            int col = bn + tx * 4 + j;
            float v = acc[i][j] + bias[col];
            if (ACC) v += C[(size_t)row * Nc + col];
            C[(size_t)row * Nc + col] = v;
        }
    }
}

// ================= LSTM gates =================
__global__ void lstm_gates(const float* __restrict__ g4, float* __restrict__ cl,
                           float* __restrict__ hl, float* __restrict__ qs, int Gn) {
    int i = blockIdx.x * 256 + threadIdx.x;
    if (i >= Gn * TH) return;
    int g = i >> 7, h = i & 127;
    const float* row = g4 + (size_t)g * 512;
    float ig = sigm(row[h]);
    float fg = sigm(row[128 + h]);
    float gg = tanhf(row[256 + h]);
    float og = sigm(row[384 + h]);
    float c = fg * cl[i] + ig * gg;
    cl[i] = c;
    float hv = og * tanhf(c);
    hl[i] = hv;
    qs[(size_t)g * 256 + h] = hv;
}

// ================= fused per-graph attention =================
__global__ __launch_bounds__(256) void att_fused(
    const bf16* __restrict__ node, const float* __restrict__ hl,
    const int* __restrict__ gptr, float* __restrict__ qs)
{
    __shared__ float q[128];
    __shared__ float es[512];
    __shared__ float red[8];
    int g = blockIdx.x;
    int tid = threadIdx.x, lane = tid & 63, wid = tid >> 6;
    int n0 = gptr[g], n1 = gptr[g + 1];
    int cnt = n1 - n0; if (cnt > 512) cnt = 512;
    if (tid < 128) q[tid] = hl[(size_t)g * TH + tid];
    __syncthreads();
    for (int i = wid; i < cnt; i += 4) {
        const bf16* nr = node + (size_t)(n0 + i) * TH;
        float p = __bfloat162float(nr[lane]) * q[lane]
                + __bfloat162float(nr[lane + 64]) * q[lane + 64];
        for (int off = 32; off; off >>= 1) p += __shfl_down(p, off);
        if (lane == 0) es[i] = p;
    }
    __syncthreads();
    float m = -1e30f;
    for (int i = tid; i < cnt; i += 256) m = fmaxf(m, es[i]);
    for (int off = 32; off; off >>= 1) m = fmaxf(m, __shfl_down(m, off));
    if (lane == 0) red[wid] = m;
    __syncthreads();
    m = fmaxf(fmaxf(red[0], red[1]), fmaxf(red[2], red[3]));
    float s = 0.f;
    for (int i = tid; i < cnt; i += 256) { float ex = expf(es[i] - m); es[i] = ex; s += ex; }
    for (int off = 32; off; off >>= 1) s += __shfl_down(s, off);
    if (lane == 0) red[4 + wid] = s;
    __syncthreads();
    s = red[4] + red[5] + red[6] + red[7];
    float inv = 1.f / fmaxf(s, 1e-9f);
    int c = tid & 127, half = tid >> 7;
    float r = 0.f;
    for (int i = half; i < cnt; i += 2)
        r += es[i] * __bfloat162float(node[(size_t)(n0 + i) * TH + c]);
    __syncthreads();
    if (half == 1) es[c] = r;
    __syncthreads();
    if (half == 0) qs[(size_t)g * 256 + 128 + c] = (r + es[c]) * inv;
}

// ================= final FC =================
__global__ __launch_bounds__(128) void final_fc(const float* __restrict__ qs,
                                                const float* __restrict__ w1,
                                                const float* __restrict__ b1,
                                                const float* __restrict__ w2,
                                                const float* __restrict__ b2,
                                                float* __restrict__ out) {
    __shared__ float q[256];
    __shared__ float red[2];
    int g = blockIdx.x, t = threadIdx.x;
    q[t] = qs[(size_t)g * 256 + t];
    q[t + 128] = qs[(size_t)g * 256 + 128 + t];
    __syncthreads();
    float acc = b1[t];
    for (int k = 0; k < 256; ++k) acc = fmaf(q[k], w1[k * TH + t], acc);
    acc = fmaxf(acc, 0.f);
    float p = acc * w2[t];
    for (int off = 32; off; off >>= 1) p += __shfl_down(p, off);
    if ((t & 63) == 0) red[t >> 6] = p;
    __syncthreads();
    if (t == 0) out[g] = red[0] + red[1] + b2[0];
}

// ---------------------------------------------------------------------------
template<bool RELU>
static void launch_mfma(const void* A, const bf16* Bt, const float* bias, void* C,
                        int M, hipStream_t s) {
    dim3 grid((M + 127) / 128, 1);
    hipLaunchKernelGGL((mfma_gemm_k128<RELU>), grid, dim3(256), 0, s,
                       (const ushort*)A, (const ushort*)Bt, bias, (ushort*)C, M);
}
template<bool TB, bool AC>
static void launch_sgemm(const float* A, const float* B, const float* bias, float* C,
                         int M, int K, int Nc, hipStream_t s) {
    dim3 grid((M + 63) / 64, Nc / 64);
    hipLaunchKernelGGL((sgemm_k<TB, AC>), grid, dim3(256), 0, s, A, B, bias, C, M, K, Nc);
}

extern "C" void kernel_launch(void* const* d_in, const int* in_sizes, int n_in,
                              void* d_out, int out_size, void* d_ws, size_t ws_size,
                              hipStream_t stream) {
    const float* x         = (const float*)d_in[0];
    const float* edge_attr = (const float*)d_in[1];
    const int*   edge_index= (const int*)d_in[2];
    const int*   batch     = (const int*)d_in[3];
    const float* node_w    = (const float*)d_in[4];
    const float* node_b    = (const float*)d_in[5];
    const float* edge_w    = (const float*)d_in[6];
    const float* edge_b    = (const float*)d_in[7];
    const float* eps       = (const float*)d_in[8];
    const float* gin_w1    = (const float*)d_in[9];
    const float* gin_b1    = (const float*)d_in[10];
    const float* gin_w2    = (const float*)d_in[11];
    const float* gin_b2    = (const float*)d_in[12];
    const float* em_w1     = (const float*)d_in[13];
    const float* em_b1     = (const float*)d_in[14];
    const float* em_w2     = (const float*)d_in[15];
    const float* em_b2     = (const float*)d_in[16];
    const float* gru_wih   = (const float*)d_in[17];
    const float* gru_whh   = (const float*)d_in[18];
    const float* gru_bih   = (const float*)d_in[19];
    const float* gru_bhh   = (const float*)d_in[20];
    const float* lstm_wih  = (const float*)d_in[21];
    const float* lstm_whh  = (const float*)d_in[22];
    const float* lstm_bih  = (const float*)d_in[23];
    const float* lstm_bhh  = (const float*)d_in[24];
    const float* fc_w1     = (const float*)d_in[25];
    const float* fc_b1     = (const float*)d_in[26];
    const float* fc_w2     = (const float*)d_in[27];
    const float* fc_b2     = (const float*)d_in[28];
    float* out = (float*)d_out;
    const int* ei_src = edge_index;
    const int* ei_dst = edge_index + TE;

    // ---- workspace layout ----
    char* base = (char*)d_ws;
    size_t off = 0;
    auto alloc = [&](size_t bytes) { void* p = base + off; off += (bytes + 15) & ~size_t(15); return p; };
    bf16*  nodeb = (bf16*)alloc((size_t)TN * TH * 2);   // 25.6 MB
    bf16*  zb    = (bf16*)alloc((size_t)TN * TH * 2);   // 25.6 MB
    bf16*  e1b   = (bf16*)alloc((size_t)TE * TH * 2);   // 51.2 MB (edge feats; set2set overlay later)
    int*   deg   = (int*)alloc((size_t)TN * 4);
    int*   rowptr= (int*)alloc((size_t)(TN + 1) * 4);
    int*   cur   = (int*)alloc((size_t)TN * 4);
    int*   eidx  = (int*)alloc((size_t)TE * 4);
    int*   bsum  = (int*)alloc(512 * 4);
    int*   bsumx = (int*)alloc(512 * 4);
    int*   gptr  = (int*)alloc((size_t)(TG + 1) * 4);
    bf16*  w6    = (bf16*)alloc(6 * TH * TH * 2);       // gin1_l0,gin1_l1,gin2_l0,gin2_l1,em1,em2
    bf16*  wgru  = (bf16*)alloc(2 * 384 * TH * 2);      // wih, whh
    if (ws_size < off) return;  // graceful fail signature

    bf16* w_gin1_0 = w6;
    bf16* w_gin1_1 = w6 + 1 * TH * TH;
    bf16* w_gin2_0 = w6 + 2 * TH * TH;
    bf16* w_gin2_1 = w6 + 3 * TH * TH;
    bf16* w_em1    = w6 + 4 * TH * TH;
    bf16* w_em2    = w6 + 5 * TH * TH;
    bf16* w_wih    = wgru;
    bf16* w_whh    = wgru + 384 * TH;

    // set2set state overlays e1b (dead after layer-1 aggregation)
    float* qs = (float*)e1b;
    float* hl = qs + (size_t)TG * 256;
    float* cl = hl + (size_t)TG * TH;
    float* g4 = cl + (size_t)TG * TH;

    // ---- CSR + gptr ----
    hipMemsetAsync(deg, 0, (size_t)TN * 4, stream);
    hipMemsetAsync(cur, 0, (size_t)TN * 4, stream);
    count_deg<<<(TE + 255) / 256, 256, 0, stream>>>(ei_dst, deg, TE);
    int nb = (TN + 255) / 256;
    scan_block<<<nb, 256, 0, stream>>>(deg, rowptr, bsum, TN);
    scan_bsum<<<1, 512, 0, stream>>>(bsum, bsumx, nb);
    add_off<<<nb, 256, 0, stream>>>(rowptr, bsumx, TN, TE);
    fill_csr<<<(TE + 255) / 256, 256, 0, stream>>>(ei_dst, rowptr, cur, eidx, TE);
    build_gptr<<<(TN + 255) / 256, 256, 0, stream>>>(batch, gptr, TN, TG);

    // ---- weights ----
    conv6<<<(6 * TH * TH + 255) / 256, 256, 0, stream>>>(
        gin_w1, gin_w1 + TH * TH, gin_w2, gin_w2 + TH * TH, em_w1, em_w2, w6);
    conv2<<<(2 * 384 * TH + 255) / 256, 256, 0, stream>>>(gru_wih, gru_whh, wgru);

    // ---- projections ----
    proj16<14><<<(TN + 15) / 16, 256, 0, stream>>>(x, node_w, node_b, (ushort*)nodeb, TN);
    proj16<4><<<(TE + 15) / 16, 256, 0, stream>>>(edge_attr, edge_w, edge_b, (ushort*)e1b, TE);

    // ---- layer 0 ----
    aggregate_k<<<(TN + 1) / 2, 256, 0, stream>>>(nodeb, e1b, ei_src, rowptr, eidx, eps, 0, zb, TN);
    launch_mfma<true >(zb, w_gin1_0, gin_b1, zb, TN, stream);          // in-place
    launch_mfma<false>(zb, w_gin2_0, gin_b2, zb, TN, stream);
    gru_fused<<<(TN + 63) / 64, 256, 0, stream>>>(
        (const ushort*)zb, (const ushort*)w_wih, (const ushort*)w_whh,
        gru_bih, gru_bhh, (ushort*)nodeb, TN);

    // ---- edge MLP (in-place on e1b), then layer 1 ----
    launch_mfma<true >(e1b, w_em1, em_b1, e1b, TE, stream);
    launch_mfma<false>(e1b, w_em2, em_b2, e1b, TE, stream);
    aggregate_k<<<(TN + 1) / 2, 256, 0, stream>>>(nodeb, e1b, ei_src, rowptr, eidx, eps, 1, zb, TN);
    launch_mfma<true >(zb, w_gin1_1, gin_b1 + TH, zb, TN, stream);
    launch_mfma<false>(zb, w_gin2_1, gin_b2 + TH, zb, TN, stream);
    gru_fused<<<(TN + 63) / 64, 256, 0, stream>>>(
        (const ushort*)zb, (const ushort*)w_wih, (const ushort*)w_whh,
        gru_bih, gru_bhh, (ushort*)nodeb, TN);

    // ---- Set2Set (3 steps) ----
    hipMemsetAsync(qs, 0, (size_t)TG * 512 * 4, stream);  // qs + hl + cl
    for (int s = 0; s < 3; ++s) {
        launch_sgemm<true, false>(qs, lstm_wih, lstm_bih, g4, TG, 2 * TH, 4 * TH, stream);
        launch_sgemm<true, true >(hl, lstm_whh, lstm_bhh, g4, TG, TH,     4 * TH, stream);
        lstm_gates<<<(TG * TH + 255) / 256, 256, 0, stream>>>(g4, cl, hl, qs, TG);
        att_fused<<<TG, 256, 0, stream>>>(nodeb, hl, gptr, qs);
    }

    // ---- final FC ----
    final_fc<<<TG, 128, 0, stream>>>(qs, fc_w1, fc_b1, fc_w2, fc_b2, out);
}

// Round 5
// 851.753 us; speedup vs baseline: 4.1603x; 1.0955x over previous
//
#include <hip/hip_runtime.h>
#include <hip/hip_bf16.h>

constexpr int TN = 100000;   // nodes
constexpr int TE = 200000;   // edges
constexpr int TG = 4000;     // graphs
constexpr int TH = 128;      // hidden

using short8 = __attribute__((ext_vector_type(8))) short;
using f32x4  = __attribute__((ext_vector_type(4))) float;
typedef __hip_bfloat16 bf16;

#define DEVINL __device__ __forceinline__
DEVINL float sigm(float x) { return 1.f / (1.f + expf(-x)); }

// ================= weight conversion =================
__global__ void conv6(const float* __restrict__ s0, const float* __restrict__ s1,
                      const float* __restrict__ s2, const float* __restrict__ s3,
                      const float* __restrict__ s4, const float* __restrict__ s5,
                      bf16* __restrict__ dst) {
    int i = blockIdx.x * 256 + threadIdx.x;
    if (i >= 6 * TH * TH) return;
    int m = i >> 14, r = i & 16383;
    int n = r >> 7, k = r & 127;
    const float* s = (m == 0) ? s0 : (m == 1) ? s1 : (m == 2) ? s2
                   : (m == 3) ? s3 : (m == 4) ? s4 : s5;
    dst[i] = __float2bfloat16(s[k * TH + n]);
}
__global__ void conv2(const float* __restrict__ a, const float* __restrict__ b,
                      bf16* __restrict__ dst) {
    int i = blockIdx.x * 256 + threadIdx.x;
    if (i >= 2 * 384 * TH) return;
    const float* s = (i < 384 * TH) ? a : b;
    int r = (i < 384 * TH) ? i : i - 384 * TH;
    dst[i] = __float2bfloat16(s[r]);
}

// ================= fast projection =================
template<int K>
__global__ __launch_bounds__(256) void proj16(const float* __restrict__ X,
                                              const float* __restrict__ W,
                                              const float* __restrict__ b,
                                              ushort* __restrict__ out, int M) {
    __shared__ float xs[16][K];
    int tid = threadIdx.x;
    int bm = blockIdx.x * 16;
    if (tid < 16 * K) {
        int r = tid / K, k = tid % K;
        xs[r][k] = (bm + r < M) ? X[(size_t)(bm + r) * K + k] : 0.f;
    }
    __syncthreads();
    int r = tid >> 4, h0 = (tid & 15) * 8;
    if (bm + r >= M) return;
    float acc[8];
#pragma unroll
    for (int j = 0; j < 8; ++j) acc[j] = b[h0 + j];
#pragma unroll
    for (int k = 0; k < K; ++k) {
        float xv = xs[r][k];
        float4 w0 = *(const float4*)(W + k * TH + h0);
        float4 w1 = *(const float4*)(W + k * TH + h0 + 4);
        acc[0] = fmaf(xv, w0.x, acc[0]); acc[1] = fmaf(xv, w0.y, acc[1]);
        acc[2] = fmaf(xv, w0.z, acc[2]); acc[3] = fmaf(xv, w0.w, acc[3]);
        acc[4] = fmaf(xv, w1.x, acc[4]); acc[5] = fmaf(xv, w1.y, acc[5]);
        acc[6] = fmaf(xv, w1.z, acc[6]); acc[7] = fmaf(xv, w1.w, acc[7]);
    }
    ushort o[8];
#pragma unroll
    for (int j = 0; j < 8; ++j) {
        bf16 v = __float2bfloat16(acc[j]);
        o[j] = *(ushort*)&v;
    }
    *(uint4*)(out + (size_t)(bm + r) * TH + h0) = *(uint4*)o;
}

// ================= CSR build =================
__global__ void count_deg(const int* __restrict__ ei_dst, int* __restrict__ deg, int En) {
    int e = blockIdx.x * 256 + threadIdx.x;
    if (e < En) atomicAdd(&deg[ei_dst[e]], 1);
}
__global__ void scan_block(const int* __restrict__ deg, int* __restrict__ rowptr,
                           int* __restrict__ bsum, int Nn) {
    __shared__ int sm[256];
    int tid = threadIdx.x;
    int gid = blockIdx.x * 256 + tid;
    int v = (gid < Nn) ? deg[gid] : 0;
    int x = v;
    sm[tid] = x; __syncthreads();
    for (int off = 1; off < 256; off <<= 1) {
        int t = (tid >= off) ? sm[tid - off] : 0;
        __syncthreads();
        x += t; sm[tid] = x;
        __syncthreads();
    }
    if (gid < Nn) rowptr[gid] = x - v;
    if (tid == 255) bsum[blockIdx.x] = x;
}
__global__ void scan_bsum(const int* __restrict__ bsum, int* __restrict__ bsumx, int nb) {
    __shared__ int sm[512];
    int tid = threadIdx.x;
    int v = (tid < nb) ? bsum[tid] : 0;
    int x = v;
    sm[tid] = x; __syncthreads();
    for (int off = 1; off < 512; off <<= 1) {
        int t = (tid >= off) ? sm[tid - off] : 0;
        __syncthreads();
        x += t; sm[tid] = x;
        __syncthreads();
    }
    if (tid < nb) bsumx[tid] = x - v;
}
__global__ void add_off(int* __restrict__ rowptr, const int* __restrict__ bsumx,
                        int Nn, int Etot) {
    int gid = blockIdx.x * 256 + threadIdx.x;
    if (gid < Nn) rowptr[gid] += bsumx[gid >> 8];
    if (gid == 0) rowptr[Nn] = Etot;
}
__global__ void fill_csr(const int* __restrict__ ei_dst, const int* __restrict__ rowptr,
                         int* __restrict__ cur, int* __restrict__ eidx, int En) {
    int e = blockIdx.x * 256 + threadIdx.x;
    if (e >= En) return;
    int d = ei_dst[e];
    int p = atomicAdd(&cur[d], 1);
    eidx[rowptr[d] + p] = e;
}
__global__ void build_gptr(const int* __restrict__ batch, int* __restrict__ gptr,
                           int Nn, int Gn) {
    int n = blockIdx.x * 256 + threadIdx.x;
    if (n >= Nn) return;
    int bc = batch[n];
    int bp = (n == 0) ? -1 : batch[n - 1];
    for (int g = bp + 1; g <= bc; ++g) gptr[g] = n;
    if (n == Nn - 1) for (int g = bc + 1; g <= Gn; ++g) gptr[g] = Nn;
}

// ========== aggregation ==========
__global__ void aggregate_k(const bf16* __restrict__ node, const bf16* __restrict__ ef,
                            const int* __restrict__ ei_src, const int* __restrict__ rowptr,
                            const int* __restrict__ eidx, const float* __restrict__ eps,
                            int l, bf16* __restrict__ zb, int Nn) {
    int n = blockIdx.x * 2 + (threadIdx.x >> 7);
    int c = threadIdx.x & 127;
    if (n >= Nn) return;
    float acc = (1.f + eps[l]) * __bfloat162float(node[(size_t)n * TH + c]);
    int s0 = rowptr[n], s1 = rowptr[n + 1];
    for (int i = s0; i < s1; ++i) {
        int e = eidx[i];
        int src = ei_src[e];
        float nv = __bfloat162float(node[(size_t)src * TH + c]);
        float ev = __bfloat162float(ef[(size_t)e * TH + c]);
        acc += fmaxf(nv + ev, 0.f);
    }
    zb[(size_t)n * TH + c] = __float2bfloat16(acc);
}

// ================= fused 2-layer MLP: C = relu(A@W1t+b1)@W2t+b2 =================
// A [M][128] bf16; W1t/W2t [128][128] bf16 (B^T); in-place safe (C may == A).
// XOR-swizzled LDS: element chunk c (8 shorts) of row r stored at chunk c^(r&15).
__global__ __launch_bounds__(256) void mlp2_fused(
    const ushort* __restrict__ A, const ushort* __restrict__ W1t,
    const float* __restrict__ b1, const ushort* __restrict__ W2t,
    const float* __restrict__ b2, ushort* __restrict__ C, int M)
{
    __shared__ ushort As[128 * 128];
    __shared__ ushort Ts[128 * 128];
    const int tid = threadIdx.x;
    const int bm = blockIdx.x * 128;
#pragma unroll
    for (int p = 0; p < 8; ++p) {
        int ch = p * 256 + tid;
        int r = ch >> 4, c = ch & 15;
        int row = bm + r;
        uint4 v = make_uint4(0u, 0u, 0u, 0u);
        if (row < M) v = *(const uint4*)(A + (size_t)row * 128 + c * 8);
        *(uint4*)(&As[r * 128 + ((c ^ (r & 15)) * 8)]) = v;
    }
    __syncthreads();
    const int lane = tid & 63, w = tid >> 6;
    const int lr = lane & 15, lq = lane >> 4;
    const int wm = (w & 1) * 64, wn = (w >> 1) * 64;
    // ---- phase 1: t = relu(A@W1t + b1) -> Ts ----
    {
        f32x4 acc[4][4] = {};
#pragma unroll
        for (int ks = 0; ks < 4; ++ks) {
            int cb = ks * 4 + lq;
            short8 af[4], bf[4];
#pragma unroll
            for (int mi = 0; mi < 4; ++mi)
                af[mi] = *(const short8*)(&As[(wm + mi * 16 + lr) * 128 + ((cb ^ lr) * 8)]);
#pragma unroll
            for (int ni = 0; ni < 4; ++ni)
                bf[ni] = *(const short8*)(W1t + (size_t)(wn + ni * 16 + lr) * 128 + ks * 32 + lq * 8);
#pragma unroll
            for (int mi = 0; mi < 4; ++mi)
#pragma unroll
                for (int ni = 0; ni < 4; ++ni)
                    acc[mi][ni] = __builtin_amdgcn_mfma_f32_16x16x32_bf16(af[mi], bf[ni], acc[mi][ni], 0, 0, 0);
        }
#pragma unroll
        for (int mi = 0; mi < 4; ++mi)
#pragma unroll
            for (int reg = 0; reg < 4; ++reg) {
                int row = wm + mi * 16 + lq * 4 + reg;
#pragma unroll
                for (int ni = 0; ni < 4; ++ni) {
                    int col = wn + ni * 16 + lr;
                    float v = fmaxf(acc[mi][ni][reg] + b1[col], 0.f);
                    bf16 bv = __float2bfloat16(v);
                    Ts[row * 128 + (((col >> 3) ^ (row & 15)) * 8) + (col & 7)] = *(ushort*)&bv;
                }
            }
    }
    __syncthreads();
    // ---- phase 2: C = t@W2t + b2 ----
    {
        f32x4 acc[4][4] = {};
#pragma unroll
        for (int ks = 0; ks < 4; ++ks) {
            int cb = ks * 4 + lq;
            short8 af[4], bf[4];
#pragma unroll
            for (int mi = 0; mi < 4; ++mi)
                af[mi] = *(const short8*)(&Ts[(wm + mi * 16 + lr) * 128 + ((cb ^ lr) * 8)]);
#pragma unroll
            for (int ni = 0; ni < 4; ++ni)
                bf[ni] = *(const short8*)(W2t + (size_t)(wn + ni * 16 + lr) * 128 + ks * 32 + lq * 8);
#pragma unroll
            for (int mi = 0; mi < 4; ++mi)
#pragma unroll
                for (int ni = 0; ni < 4; ++ni)
                    acc[mi][ni] = __builtin_amdgcn_mfma_f32_16x16x32_bf16(af[mi], bf[ni], acc[mi][ni], 0, 0, 0);
        }
#pragma unroll
        for (int mi = 0; mi < 4; ++mi)
#pragma unroll
            for (int reg = 0; reg < 4; ++reg) {
                int row = bm + wm + mi * 16 + lq * 4 + reg;
                if (row >= M) continue;
#pragma unroll
                for (int ni = 0; ni < 4; ++ni) {
                    int col = wn + ni * 16 + lr;
                    bf16 bv = __float2bfloat16(acc[mi][ni][reg] + b2[col]);
                    C[(size_t)row * 128 + col] = *(ushort*)&bv;
                }
            }
    }
}

// ================= fused GRU (additive r/z, 32 rows/block) =================
// block = 256 threads (4 waves), 32 rows; wave w covers h-cols [w*32, w*32+32)
__global__ __launch_bounds__(256) void gru_fused(
    const ushort* __restrict__ mfeat, const ushort* __restrict__ wih,
    const ushort* __restrict__ whh, const float* __restrict__ bih,
    const float* __restrict__ bhh, ushort* __restrict__ node, int Nn)
{
    __shared__ ushort Ms[32 * 128];
    __shared__ ushort Hs[32 * 128];
    const int tid = threadIdx.x;
    const int bm = blockIdx.x * 32;
#pragma unroll
    for (int p = 0; p < 4; ++p) {
        int ch = p * 256 + tid;          // 1024 = 2 bufs x 32 rows x 16 chunks
        bool isH = ch >= 512;
        int r = (ch >> 4) & 31, c = ch & 15;
        int row = bm + r;
        uint4 v = make_uint4(0u, 0u, 0u, 0u);
        if (row < Nn) v = *(const uint4*)((isH ? node : mfeat) + (size_t)row * 128 + c * 8);
        ushort* dst = isH ? Hs : Ms;
        *(uint4*)(&dst[r * 128 + ((c ^ (r & 15)) * 8)]) = v;
    }
    __syncthreads();
    const int lane = tid & 63, w = tid >> 6;
    const int lr = lane & 15, lq = lane >> 4;
    f32x4 aR[2][2] = {}, aZ[2][2] = {}, aN[2][2] = {}, aH[2][2] = {};
#pragma unroll
    for (int ks = 0; ks < 4; ++ks) {
        int cb = ks * 4 + lq;
        short8 am[2], ah[2];
#pragma unroll
        for (int rt = 0; rt < 2; ++rt) {
            int off = (rt * 16 + lr) * 128 + ((cb ^ lr) * 8);
            am[rt] = *(const short8*)(&Ms[off]);
            ah[rt] = *(const short8*)(&Hs[off]);
        }
        int koff = ks * 32 + lq * 8;
#pragma unroll
        for (int c2 = 0; c2 < 2; ++c2) {
            int col = w * 32 + c2 * 16 + lr;
            short8 bRi = *(const short8*)(wih + (size_t)col * 128 + koff);
            short8 bZi = *(const short8*)(wih + (size_t)(128 + col) * 128 + koff);
            short8 bNi = *(const short8*)(wih + (size_t)(256 + col) * 128 + koff);
            short8 bRh = *(const short8*)(whh + (size_t)col * 128 + koff);
            short8 bZh = *(const short8*)(whh + (size_t)(128 + col) * 128 + koff);
            short8 bNh = *(const short8*)(whh + (size_t)(256 + col) * 128 + koff);
#pragma unroll
            for (int rt = 0; rt < 2; ++rt) {
                aR[rt][c2] = __builtin_amdgcn_mfma_f32_16x16x32_bf16(am[rt], bRi, aR[rt][c2], 0, 0, 0);
                aR[rt][c2] = __builtin_amdgcn_mfma_f32_16x16x32_bf16(ah[rt], bRh, aR[rt][c2], 0, 0, 0);
                aZ[rt][c2] = __builtin_amdgcn_mfma_f32_16x16x32_bf16(am[rt], bZi, aZ[rt][c2], 0, 0, 0);
                aZ[rt][c2] = __builtin_amdgcn_mfma_f32_16x16x32_bf16(ah[rt], bZh, aZ[rt][c2], 0, 0, 0);
                aN[rt][c2] = __builtin_amdgcn_mfma_f32_16x16x32_bf16(am[rt], bNi, aN[rt][c2], 0, 0, 0);
                aH[rt][c2] = __builtin_amdgcn_mfma_f32_16x16x32_bf16(ah[rt], bNh, aH[rt][c2], 0, 0, 0);
            }
        }
    }
#pragma unroll
    for (int c2 = 0; c2 < 2; ++c2) {
        int h = w * 32 + c2 * 16 + lr;
        float br = bih[h] + bhh[h];
        float bz = bih[128 + h] + bhh[128 + h];
        float bin = bih[256 + h], bhn = bhh[256 + h];
#pragma unroll
        for (int rt = 0; rt < 2; ++rt)
#pragma unroll
            for (int reg = 0; reg < 4; ++reg) {
                int lrow = rt * 16 + lq * 4 + reg;
                int row = bm + lrow;
                if (row >= Nn) continue;
                float r = sigm(aR[rt][c2][reg] + br);
                float z = sigm(aZ[rt][c2][reg] + bz);
                float n = tanhf(aN[rt][c2][reg] + bin + r * (aH[rt][c2][reg] + bhn));
                int hofs = lrow * 128 + (((h >> 3) ^ (lrow & 15)) * 8) + (h & 7);
                float hold = __bfloat162float(*(const bf16*)&Hs[hofs]);
                bf16 hv = __float2bfloat16((1.f - z) * n + z * hold);
                node[(size_t)row * 128 + h] = *(ushort*)&hv;
            }
    }
}

// ================= fp32 SGEMM (set2set only) =================
template<bool TRANSB, bool ACC>
__global__ __launch_bounds__(256) void sgemm_k(
    const float* __restrict__ A, const float* __restrict__ B,
    const float* __restrict__ bias, float* __restrict__ C,
    int M, int K, int Nc)
{
    constexpr int BM = 64, BN = 64, BK = 32, PAD = 4;
    __shared__ float As[BK][BM + PAD];
    __shared__ float Bs[BK][BN + PAD];
    const int tid = threadIdx.x;
    const int bm = blockIdx.x * BM;
    const int bn = blockIdx.y * BN;
    const int tx = tid & 15, ty = tid >> 4;
    float acc[4][4] = {};
    for (int k0 = 0; k0 < K; k0 += BK) {
#pragma unroll
        for (int i = 0; i < 2; ++i) {
            int idx = tid + i * 256;
            int r = idx >> 3, kq = (idx & 7) * 4;
            int row = bm + r;
            float4 v = make_float4(0.f, 0.f, 0.f, 0.f);
            if (row < M) v = *(const float4*)(A + (size_t)row * K + k0 + kq);
            As[kq + 0][r] = v.x; As[kq + 1][r] = v.y;
            As[kq + 2][r] = v.z; As[kq + 3][r] = v.w;
        }
        if (TRANSB) {
#pragma unroll
            for (int i = 0; i < 2; ++i) {
                int idx = tid + i * 256;
                int n = idx >> 3, kq = (idx & 7) * 4;
                float4 v = *(const float4*)(B + (size_t)(bn + n) * K + k0 + kq);
                Bs[kq + 0][n] = v.x; Bs[kq + 1][n] = v.y;
                Bs[kq + 2][n] = v.z; Bs[kq + 3][n] = v.w;
            }
        } else {
#pragma unroll
            for (int i = 0; i < 2; ++i) {
                int idx = tid + i * 256;
                int kk = idx >> 4, nq = (idx & 15) * 4;
                float4 v = *(const float4*)(B + (size_t)(k0 + kk) * Nc + bn + nq);
                Bs[kk][nq + 0] = v.x; Bs[kk][nq + 1] = v.y;
                Bs[kk][nq + 2] = v.z; Bs[kk][nq + 3] = v.w;
            }
        }
        __syncthreads();
#pragma unroll
        for (int k = 0; k < BK; ++k) {
            float4 av = *(const float4*)&As[k][ty * 4];
            float4 bv = *(const float4*)&Bs[k][tx * 4];
            float a4[4] = {av.x, av.y, av.z, av.w};
            float b4[4] = {bv.x, bv.y, bv.z, bv.w};
#pragma unroll
            for (int i = 0; i < 4; ++i)
#pragma unroll
                for (int j = 0; j < 4; ++j)
                    acc[i][j] = fmaf(a4[i], b4[j], acc[i][j]);
        }
        __syncthreads();
    }
#pragma unroll
    for (int i = 0; i < 4; ++i) {
        int row = bm + ty * 4 + i;
        if (row >= M) continue;
#pragma unroll
        for (int j = 0; j < 4; ++j) {
            int col = bn + tx * 4 + j;
            float v = acc[i][j] + bias[col];
            if (ACC) v += C[(size_t)row * Nc + col];
            C[(size_t)row * Nc + col] = v;
        }
    }
}

// ================= LSTM gates =================
__global__ void lstm_gates(const float* __restrict__ g4, float* __restrict__ cl,
                           float* __restrict__ hl, float* __restrict__ qs, int Gn) {
    int i = blockIdx.x * 256 + threadIdx.x;
    if (i >= Gn * TH) return;
    int g = i >> 7, h = i & 127;
    const float* row = g4 + (size_t)g * 512;
    float ig = sigm(row[h]);
    float fg = sigm(row[128 + h]);
    float gg = tanhf(row[256 + h]);
    float og = sigm(row[384 + h]);
    float c = fg * cl[i] + ig * gg;
    cl[i] = c;
    float hv = og * tanhf(c);
    hl[i] = hv;
    qs[(size_t)g * 256 + h] = hv;
}

// ================= fused per-graph attention =================
__global__ __launch_bounds__(256) void att_fused(
    const bf16* __restrict__ node, const float* __restrict__ hl,
    const int* __restrict__ gptr, float* __restrict__ qs)
{
    __shared__ float q[128];
    __shared__ float es[512];
    __shared__ float red[8];
    int g = blockIdx.x;
    int tid = threadIdx.x, lane = tid & 63, wid = tid >> 6;
    int n0 = gptr[g], n1 = gptr[g + 1];
    int cnt = n1 - n0; if (cnt > 512) cnt = 512;
    if (tid < 128) q[tid] = hl[(size_t)g * TH + tid];
    __syncthreads();
    for (int i = wid; i < cnt; i += 4) {
        const bf16* nr = node + (size_t)(n0 + i) * TH;
        float p = __bfloat162float(nr[lane]) * q[lane]
                + __bfloat162float(nr[lane + 64]) * q[lane + 64];
        for (int off = 32; off; off >>= 1) p += __shfl_down(p, off);
        if (lane == 0) es[i] = p;
    }
    __syncthreads();
    float m = -1e30f;
    for (int i = tid; i < cnt; i += 256) m = fmaxf(m, es[i]);
    for (int off = 32; off; off >>= 1) m = fmaxf(m, __shfl_down(m, off));
    if (lane == 0) red[wid] = m;
    __syncthreads();
    m = fmaxf(fmaxf(red[0], red[1]), fmaxf(red[2], red[3]));
    float s = 0.f;
    for (int i = tid; i < cnt; i += 256) { float ex = expf(es[i] - m); es[i] = ex; s += ex; }
    for (int off = 32; off; off >>= 1) s += __shfl_down(s, off);
    if (lane == 0) red[4 + wid] = s;
    __syncthreads();
    s = red[4] + red[5] + red[6] + red[7];
    float inv = 1.f / fmaxf(s, 1e-9f);
    int c = tid & 127, half = tid >> 7;
    float r = 0.f;
    for (int i = half; i < cnt; i += 2)
        r += es[i] * __bfloat162float(node[(size_t)(n0 + i) * TH + c]);
    __syncthreads();
    if (half == 1) es[c] = r;
    __syncthreads();
    if (half == 0) qs[(size_t)g * 256 + 128 + c] = (r + es[c]) * inv;
}

// ================= final FC =================
__global__ __launch_bounds__(128) void final_fc(const float* __restrict__ qs,
                                                const float* __restrict__ w1,
                                                const float* __restrict__ b1,
                                                const float* __restrict__ w2,
                                                const float* __restrict__ b2,
                                                float* __restrict__ out) {
    __shared__ float q[256];
    __shared__ float red[2];
    int g = blockIdx.x, t = threadIdx.x;
    q[t] = qs[(size_t)g * 256 + t];
    q[t + 128] = qs[(size_t)g * 256 + 128 + t];
    __syncthreads();
    float acc = b1[t];
    for (int k = 0; k < 256; ++k) acc = fmaf(q[k], w1[k * TH + t], acc);
    acc = fmaxf(acc, 0.f);
    float p = acc * w2[t];
    for (int off = 32; off; off >>= 1) p += __shfl_down(p, off);
    if ((t & 63) == 0) red[t >> 6] = p;
    __syncthreads();
    if (t == 0) out[g] = red[0] + red[1] + b2[0];
}

// ---------------------------------------------------------------------------
static void launch_mlp2(const void* A, const bf16* W1t, const float* b1,
                        const bf16* W2t, const float* b2, void* C, int M, hipStream_t s) {
    hipLaunchKernelGGL(mlp2_fused, dim3((M + 127) / 128), dim3(256), 0, s,
                       (const ushort*)A, (const ushort*)W1t, b1, (const ushort*)W2t, b2,
                       (ushort*)C, M);
}
template<bool TB, bool AC>
static void launch_sgemm(const float* A, const float* B, const float* bias, float* C,
                         int M, int K, int Nc, hipStream_t s) {
    dim3 grid((M + 63) / 64, Nc / 64);
    hipLaunchKernelGGL((sgemm_k<TB, AC>), grid, dim3(256), 0, s, A, B, bias, C, M, K, Nc);
}

extern "C" void kernel_launch(void* const* d_in, const int* in_sizes, int n_in,
                              void* d_out, int out_size, void* d_ws, size_t ws_size,
                              hipStream_t stream) {
    const float* x         = (const float*)d_in[0];
    const float* edge_attr = (const float*)d_in[1];
    const int*   edge_index= (const int*)d_in[2];
    const int*   batch     = (const int*)d_in[3];
    const float* node_w    = (const float*)d_in[4];
    const float* node_b    = (const float*)d_in[5];
    const float* edge_w    = (const float*)d_in[6];
    const float* edge_b    = (const float*)d_in[7];
    const float* eps       = (const float*)d_in[8];
    const float* gin_w1    = (const float*)d_in[9];
    const float* gin_b1    = (const float*)d_in[10];
    const float* gin_w2    = (const float*)d_in[11];
    const float* gin_b2    = (const float*)d_in[12];
    const float* em_w1     = (const float*)d_in[13];
    const float* em_b1     = (const float*)d_in[14];
    const float* em_w2     = (const float*)d_in[15];
    const float* em_b2     = (const float*)d_in[16];
    const float* gru_wih   = (const float*)d_in[17];
    const float* gru_whh   = (const float*)d_in[18];
    const float* gru_bih   = (const float*)d_in[19];
    const float* gru_bhh   = (const float*)d_in[20];
    const float* lstm_wih  = (const float*)d_in[21];
    const float* lstm_whh  = (const float*)d_in[22];
    const float* lstm_bih  = (const float*)d_in[23];
    const float* lstm_bhh  = (const float*)d_in[24];
    const float* fc_w1     = (const float*)d_in[25];
    const float* fc_b1     = (const float*)d_in[26];
    const float* fc_w2     = (const float*)d_in[27];
    const float* fc_b2     = (const float*)d_in[28];
    float* out = (float*)d_out;
    const int* ei_src = edge_index;
    const int* ei_dst = edge_index + TE;

    // ---- workspace layout ----
    char* base = (char*)d_ws;
    size_t off = 0;
    auto alloc = [&](size_t bytes) { void* p = base + off; off += (bytes + 15) & ~size_t(15); return p; };
    bf16*  nodeb = (bf16*)alloc((size_t)TN * TH * 2);   // 25.6 MB
    bf16*  zb    = (bf16*)alloc((size_t)TN * TH * 2);   // 25.6 MB
    bf16*  e1b   = (bf16*)alloc((size_t)TE * TH * 2);   // 51.2 MB (set2set overlay later)
    int*   deg   = (int*)alloc((size_t)TN * 4);
    int*   rowptr= (int*)alloc((size_t)(TN + 1) * 4);
    int*   cur   = (int*)alloc((size_t)TN * 4);
    int*   eidx  = (int*)alloc((size_t)TE * 4);
    int*   bsum  = (int*)alloc(512 * 4);
    int*   bsumx = (int*)alloc(512 * 4);
    int*   gptr  = (int*)alloc((size_t)(TG + 1) * 4);
    bf16*  w6    = (bf16*)alloc(6 * TH * TH * 2);
    bf16*  wgru  = (bf16*)alloc(2 * 384 * TH * 2);
    if (ws_size < off) return;

    bf16* w_gin1_0 = w6;
    bf16* w_gin1_1 = w6 + 1 * TH * TH;
    bf16* w_gin2_0 = w6 + 2 * TH * TH;
    bf16* w_gin2_1 = w6 + 3 * TH * TH;
    bf16* w_em1    = w6 + 4 * TH * TH;
    bf16* w_em2    = w6 + 5 * TH * TH;
    bf16* w_wih    = wgru;
    bf16* w_whh    = wgru + 384 * TH;

    float* qs = (float*)e1b;
    float* hl = qs + (size_t)TG * 256;
    float* cl = hl + (size_t)TG * TH;
    float* g4 = cl + (size_t)TG * TH;

    // ---- CSR + gptr ----
    hipMemsetAsync(deg, 0, (size_t)TN * 4, stream);
    hipMemsetAsync(cur, 0, (size_t)TN * 4, stream);
    count_deg<<<(TE + 255) / 256, 256, 0, stream>>>(ei_dst, deg, TE);
    int nb = (TN + 255) / 256;
    scan_block<<<nb, 256, 0, stream>>>(deg, rowptr, bsum, TN);
    scan_bsum<<<1, 512, 0, stream>>>(bsum, bsumx, nb);
    add_off<<<nb, 256, 0, stream>>>(rowptr, bsumx, TN, TE);
    fill_csr<<<(TE + 255) / 256, 256, 0, stream>>>(ei_dst, rowptr, cur, eidx, TE);
    build_gptr<<<(TN + 255) / 256, 256, 0, stream>>>(batch, gptr, TN, TG);

    // ---- weights ----
    conv6<<<(6 * TH * TH + 255) / 256, 256, 0, stream>>>(
        gin_w1, gin_w1 + TH * TH, gin_w2, gin_w2 + TH * TH, em_w1, em_w2, w6);
    conv2<<<(2 * 384 * TH + 255) / 256, 256, 0, stream>>>(gru_wih, gru_whh, wgru);

    // ---- projections ----
    proj16<14><<<(TN + 15) / 16, 256, 0, stream>>>(x, node_w, node_b, (ushort*)nodeb, TN);
    proj16<4><<<(TE + 15) / 16, 256, 0, stream>>>(edge_attr, edge_w, edge_b, (ushort*)e1b, TE);

    // ---- layer 0 ----
    aggregate_k<<<(TN + 1) / 2, 256, 0, stream>>>(nodeb, e1b, ei_src, rowptr, eidx, eps, 0, zb, TN);
    launch_mlp2(zb, w_gin1_0, gin_b1, w_gin2_0, gin_b2, zb, TN, stream);
    gru_fused<<<(TN + 31) / 32, 256, 0, stream>>>(
        (const ushort*)zb, (const ushort*)w_wih, (const ushort*)w_whh,
        gru_bih, gru_bhh, (ushort*)nodeb, TN);

    // ---- edge MLP (in-place), layer 1 ----
    launch_mlp2(e1b, w_em1, em_b1, w_em2, em_b2, e1b, TE, stream);
    aggregate_k<<<(TN + 1) / 2, 256, 0, stream>>>(nodeb, e1b, ei_src, rowptr, eidx, eps, 1, zb, TN);
    launch_mlp2(zb, w_gin1_1, gin_b1 + TH, w_gin2_1, gin_b2 + TH, zb, TN, stream);
    gru_fused<<<(TN + 31) / 32, 256, 0, stream>>>(
        (const ushort*)zb, (const ushort*)w_wih, (const ushort*)w_whh,
        gru_bih, gru_bhh, (ushort*)nodeb, TN);

    // ---- Set2Set (3 steps) ----
    hipMemsetAsync(qs, 0, (size_t)TG * 512 * 4, stream);
    for (int s = 0; s < 3; ++s) {
        launch_sgemm<true, false>(qs, lstm_wih, lstm_bih, g4, TG, 2 * TH, 4 * TH, stream);
        launch_sgemm<true, true >(hl, lstm_whh, lstm_bhh, g4, TG, TH,     4 * TH, stream);
        lstm_gates<<<(TG * TH + 255) / 256, 256, 0, stream>>>(g4, cl, hl, qs, TG);
        att_fused<<<TG, 256, 0, stream>>>(nodeb, hl, gptr, qs);
    }

    // ---- final FC ----
    final_fc<<<TG, 128, 0, stream>>>(qs, fc_w1, fc_b1, fc_w2, fc_b2, out);
}

// Round 6
// 807.275 us; speedup vs baseline: 4.3895x; 1.0551x over previous
//
#include <hip/hip_runtime.h>
#include <hip/hip_bf16.h>

constexpr int TN = 100000;   // nodes
constexpr int TE = 200000;   // edges
constexpr int TG = 4000;     // graphs
constexpr int TH = 128;      // hidden

using short8 = __attribute__((ext_vector_type(8))) short;
using f32x4  = __attribute__((ext_vector_type(4))) float;
typedef __hip_bfloat16 bf16;

#define DEVINL __device__ __forceinline__
DEVINL float sigm(float x)  { return 1.f / (1.f + __expf(-x)); }           // safe: exp->inf -> 0
DEVINL float ftanh(float x) { return 1.f - 2.f / (__expf(2.f * x) + 1.f); } // safe both tails

// ================= weight conversion =================
__global__ void conv6(const float* __restrict__ s0, const float* __restrict__ s1,
                      const float* __restrict__ s2, const float* __restrict__ s3,
                      const float* __restrict__ s4, const float* __restrict__ s5,
                      bf16* __restrict__ dst) {
    int i = blockIdx.x * 256 + threadIdx.x;
    if (i >= 6 * TH * TH) return;
    int m = i >> 14, r = i & 16383;
    int n = r >> 7, k = r & 127;
    const float* s = (m == 0) ? s0 : (m == 1) ? s1 : (m == 2) ? s2
                   : (m == 3) ? s3 : (m == 4) ? s4 : s5;
    dst[i] = __float2bfloat16(s[k * TH + n]);
}
__global__ void conv2(const float* __restrict__ a, const float* __restrict__ b,
                      bf16* __restrict__ dst) {
    int i = blockIdx.x * 256 + threadIdx.x;
    if (i >= 2 * 384 * TH) return;
    const float* s = (i < 384 * TH) ? a : b;
    int r = (i < 384 * TH) ? i : i - 384 * TH;
    dst[i] = __float2bfloat16(s[r]);
}
// fused LSTM weight: Wl[c][k<128] = wih[c][k] + whh[c][k]; Wl[c][128+k] = wih[c][128+k]
__global__ void convL(const float* __restrict__ wih, const float* __restrict__ whh,
                      bf16* __restrict__ dst) {
    int i = blockIdx.x * 256 + threadIdx.x;
    if (i >= 512 * 256) return;
    int c = i >> 8, k = i & 255;
    float v = (k < 128) ? wih[c * 256 + k] + whh[c * 128 + k] : wih[c * 256 + k];
    dst[i] = __float2bfloat16(v);
}

// ================= fast projection (optional row permutation on output) ==========
template<int K, bool PERM>
__global__ __launch_bounds__(256) void proj16(const float* __restrict__ X,
                                              const float* __restrict__ W,
                                              const float* __restrict__ b,
                                              ushort* __restrict__ out,
                                              const int* __restrict__ perm, int M) {
    __shared__ float xs[16][K];
    int tid = threadIdx.x;
    int bm = blockIdx.x * 16;
    if (tid < 16 * K) {
        int r = tid / K, k = tid % K;
        xs[r][k] = (bm + r < M) ? X[(size_t)(bm + r) * K + k] : 0.f;
    }
    __syncthreads();
    int r = tid >> 4, h0 = (tid & 15) * 8;
    if (bm + r >= M) return;
    float acc[8];
#pragma unroll
    for (int j = 0; j < 8; ++j) acc[j] = b[h0 + j];
#pragma unroll
    for (int k = 0; k < K; ++k) {
        float xv = xs[r][k];
        float4 w0 = *(const float4*)(W + k * TH + h0);
        float4 w1 = *(const float4*)(W + k * TH + h0 + 4);
        acc[0] = fmaf(xv, w0.x, acc[0]); acc[1] = fmaf(xv, w0.y, acc[1]);
        acc[2] = fmaf(xv, w0.z, acc[2]); acc[3] = fmaf(xv, w0.w, acc[3]);
        acc[4] = fmaf(xv, w1.x, acc[4]); acc[5] = fmaf(xv, w1.y, acc[5]);
        acc[6] = fmaf(xv, w1.z, acc[6]); acc[7] = fmaf(xv, w1.w, acc[7]);
    }
    ushort o[8];
#pragma unroll
    for (int j = 0; j < 8; ++j) {
        bf16 v = __float2bfloat16(acc[j]);
        o[j] = *(ushort*)&v;
    }
    int orow = PERM ? perm[bm + r] : (bm + r);
    *(uint4*)(out + (size_t)orow * TH + h0) = *(uint4*)o;
}

// ================= CSR build =================
__global__ void count_deg(const int* __restrict__ ei_dst, int* __restrict__ deg, int En) {
    int e = blockIdx.x * 256 + threadIdx.x;
    if (e < En) atomicAdd(&deg[ei_dst[e]], 1);
}
__global__ void scan_block(const int* __restrict__ deg, int* __restrict__ rowptr,
                           int* __restrict__ bsum, int Nn) {
    __shared__ int sm[256];
    int tid = threadIdx.x;
    int gid = blockIdx.x * 256 + tid;
    int v = (gid < Nn) ? deg[gid] : 0;
    int x = v;
    sm[tid] = x; __syncthreads();
    for (int off = 1; off < 256; off <<= 1) {
        int t = (tid >= off) ? sm[tid - off] : 0;
        __syncthreads();
        x += t; sm[tid] = x;
        __syncthreads();
    }
    if (gid < Nn) rowptr[gid] = x - v;
    if (tid == 255) bsum[blockIdx.x] = x;
}
__global__ void scan_bsum(const int* __restrict__ bsum, int* __restrict__ bsumx, int nb) {
    __shared__ int sm[512];
    int tid = threadIdx.x;
    int v = (tid < nb) ? bsum[tid] : 0;
    int x = v;
    sm[tid] = x; __syncthreads();
    for (int off = 1; off < 512; off <<= 1) {
        int t = (tid >= off) ? sm[tid - off] : 0;
        __syncthreads();
        x += t; sm[tid] = x;
        __syncthreads();
    }
    if (tid < nb) bsumx[tid] = x - v;
}
__global__ void add_off(int* __restrict__ rowptr, const int* __restrict__ bsumx,
                        int Nn, int Etot) {
    int gid = blockIdx.x * 256 + threadIdx.x;
    if (gid < Nn) rowptr[gid] += bsumx[gid >> 8];
    if (gid == 0) rowptr[Nn] = Etot;
}
// also emits srcp (source per CSR slot) and epos (edge -> CSR slot)
__global__ void fill_csr(const int* __restrict__ ei_src, const int* __restrict__ ei_dst,
                         const int* __restrict__ rowptr, int* __restrict__ cur,
                         int* __restrict__ srcp, int* __restrict__ epos, int En) {
    int e = blockIdx.x * 256 + threadIdx.x;
    if (e >= En) return;
    int d = ei_dst[e];
    int p = atomicAdd(&cur[d], 1);
    int slot = rowptr[d] + p;
    srcp[slot] = ei_src[e];
    epos[e] = slot;
}
__global__ void build_gptr(const int* __restrict__ batch, int* __restrict__ gptr,
                           int Nn, int Gn) {
    int n = blockIdx.x * 256 + threadIdx.x;
    if (n >= Nn) return;
    int bc = batch[n];
    int bp = (n == 0) ? -1 : batch[n - 1];
    for (int g = bp + 1; g <= bc; ++g) gptr[g] = n;
    if (n == Nn - 1) for (int g = bc + 1; g <= Gn; ++g) gptr[g] = Nn;
}

// ========== aggregation (CSR-ordered: srcp + ef both sequential in slot i) ==========
__global__ void aggregate_k(const bf16* __restrict__ node, const bf16* __restrict__ ef,
                            const int* __restrict__ srcp, const int* __restrict__ rowptr,
                            const float* __restrict__ eps, int l,
                            bf16* __restrict__ zb, int Nn) {
    int n = blockIdx.x * 2 + (threadIdx.x >> 7);
    int c = threadIdx.x & 127;
    if (n >= Nn) return;
    float acc = (1.f + eps[l]) * __bfloat162float(node[(size_t)n * TH + c]);
    int s0 = rowptr[n], s1 = rowptr[n + 1];
    for (int i = s0; i < s1; ++i) {
        int src = srcp[i];
        float nv = __bfloat162float(node[(size_t)src * TH + c]);
        float ev = __bfloat162float(ef[(size_t)i * TH + c]);
        acc += fmaxf(nv + ev, 0.f);
    }
    zb[(size_t)n * TH + c] = __float2bfloat16(acc);
}

// ================= fused 2-layer MLP (weights preloaded to registers) =================
__global__ __launch_bounds__(256) void mlp2_fused(
    const ushort* __restrict__ A, const ushort* __restrict__ W1t,
    const float* __restrict__ b1, const ushort* __restrict__ W2t,
    const float* __restrict__ b2, ushort* __restrict__ C, int M)
{
    __shared__ ushort As[128 * 128];
    __shared__ ushort Ts[128 * 128];
    const int tid = threadIdx.x;
    const int bm = blockIdx.x * 128;
    const int lane = tid & 63, w = tid >> 6;
    const int lr = lane & 15, lq = lane >> 4;
    const int wm = (w & 1) * 64, wn = (w >> 1) * 64;
    // preload phase-1 weight fragments (16 short8 = 64 VGPRs)
    short8 wf[4][4];
#pragma unroll
    for (int ni = 0; ni < 4; ++ni)
#pragma unroll
        for (int ks = 0; ks < 4; ++ks)
            wf[ni][ks] = *(const short8*)(W1t + (size_t)(wn + ni * 16 + lr) * 128 + ks * 32 + lq * 8);
#pragma unroll
    for (int p = 0; p < 8; ++p) {
        int ch = p * 256 + tid;
        int r = ch >> 4, c = ch & 15;
        int row = bm + r;
        uint4 v = make_uint4(0u, 0u, 0u, 0u);
        if (row < M) v = *(const uint4*)(A + (size_t)row * 128 + c * 8);
        *(uint4*)(&As[r * 128 + ((c ^ (r & 15)) * 8)]) = v;
    }
    __syncthreads();
    // ---- phase 1 ----
    {
        f32x4 acc[4][4] = {};
#pragma unroll
        for (int ks = 0; ks < 4; ++ks) {
            int cb = ks * 4 + lq;
            short8 af[4];
#pragma unroll
            for (int mi = 0; mi < 4; ++mi)
                af[mi] = *(const short8*)(&As[(wm + mi * 16 + lr) * 128 + ((cb ^ lr) * 8)]);
#pragma unroll
            for (int mi = 0; mi < 4; ++mi)
#pragma unroll
                for (int ni = 0; ni < 4; ++ni)
                    acc[mi][ni] = __builtin_amdgcn_mfma_f32_16x16x32_bf16(af[mi], wf[ni][ks], acc[mi][ni], 0, 0, 0);
        }
#pragma unroll
        for (int mi = 0; mi < 4; ++mi)
#pragma unroll
            for (int reg = 0; reg < 4; ++reg) {
                int row = wm + mi * 16 + lq * 4 + reg;
#pragma unroll
                for (int ni = 0; ni < 4; ++ni) {
                    int col = wn + ni * 16 + lr;
                    float v = fmaxf(acc[mi][ni][reg] + b1[col], 0.f);
                    bf16 bv = __float2bfloat16(v);
                    Ts[row * 128 + (((col >> 3) ^ (row & 15)) * 8) + (col & 7)] = *(ushort*)&bv;
                }
            }
    }
    // preload phase-2 weight fragments
#pragma unroll
    for (int ni = 0; ni < 4; ++ni)
#pragma unroll
        for (int ks = 0; ks < 4; ++ks)
            wf[ni][ks] = *(const short8*)(W2t + (size_t)(wn + ni * 16 + lr) * 128 + ks * 32 + lq * 8);
    __syncthreads();
    // ---- phase 2 ----
    {
        f32x4 acc[4][4] = {};
#pragma unroll
        for (int ks = 0; ks < 4; ++ks) {
            int cb = ks * 4 + lq;
            short8 af[4];
#pragma unroll
            for (int mi = 0; mi < 4; ++mi)
                af[mi] = *(const short8*)(&Ts[(wm + mi * 16 + lr) * 128 + ((cb ^ lr) * 8)]);
#pragma unroll
            for (int mi = 0; mi < 4; ++mi)
#pragma unroll
                for (int ni = 0; ni < 4; ++ni)
                    acc[mi][ni] = __builtin_amdgcn_mfma_f32_16x16x32_bf16(af[mi], wf[ni][ks], acc[mi][ni], 0, 0, 0);
        }
#pragma unroll
        for (int mi = 0; mi < 4; ++mi)
#pragma unroll
            for (int reg = 0; reg < 4; ++reg) {
                int row = bm + wm + mi * 16 + lq * 4 + reg;
                if (row >= M) continue;
#pragma unroll
                for (int ni = 0; ni < 4; ++ni) {
                    int col = wn + ni * 16 + lr;
                    bf16 bv = __float2bfloat16(acc[mi][ni][reg] + b2[col]);
                    C[(size_t)row * 128 + col] = *(ushort*)&bv;
                }
            }
    }
}

// ================= fused GRU (64 rows/block, additive r/z, fast gates) =================
__global__ __launch_bounds__(256) void gru_fused(
    const ushort* __restrict__ mfeat, const ushort* __restrict__ wih,
    const ushort* __restrict__ whh, const float* __restrict__ bih,
    const float* __restrict__ bhh, ushort* __restrict__ node, int Nn)
{
    __shared__ ushort Ms[64 * 128];
    __shared__ ushort Hs[64 * 128];
    const int tid = threadIdx.x;
    const int bm = blockIdx.x * 64;
#pragma unroll
    for (int p = 0; p < 8; ++p) {
        int ch = p * 256 + tid;          // 2048 = 2 bufs x 64 rows x 16 chunks
        bool isH = ch >= 1024;
        int r = (ch >> 4) & 63, c = ch & 15;
        int row = bm + r;
        uint4 v = make_uint4(0u, 0u, 0u, 0u);
        if (row < Nn) v = *(const uint4*)((isH ? node : mfeat) + (size_t)row * 128 + c * 8);
        ushort* dst = isH ? Hs : Ms;
        *(uint4*)(&dst[r * 128 + ((c ^ (r & 15)) * 8)]) = v;
    }
    __syncthreads();
    const int lane = tid & 63, w = tid >> 6;
    const int lr = lane & 15, lq = lane >> 4;
    f32x4 aR[4][2] = {}, aZ[4][2] = {}, aN[4][2] = {}, aH[4][2] = {};
#pragma unroll
    for (int ks = 0; ks < 4; ++ks) {
        int cb = ks * 4 + lq;
        short8 am[4], ah[4];
#pragma unroll
        for (int rt = 0; rt < 4; ++rt) {
            int off = (rt * 16 + lr) * 128 + ((cb ^ lr) * 8);
            am[rt] = *(const short8*)(&Ms[off]);
            ah[rt] = *(const short8*)(&Hs[off]);
        }
        int koff = ks * 32 + lq * 8;
#pragma unroll
        for (int c2 = 0; c2 < 2; ++c2) {
            int col = w * 32 + c2 * 16 + lr;
            short8 bRi = *(const short8*)(wih + (size_t)col * 128 + koff);
            short8 bZi = *(const short8*)(wih + (size_t)(128 + col) * 128 + koff);
            short8 bNi = *(const short8*)(wih + (size_t)(256 + col) * 128 + koff);
            short8 bRh = *(const short8*)(whh + (size_t)col * 128 + koff);
            short8 bZh = *(const short8*)(whh + (size_t)(128 + col) * 128 + koff);
            short8 bNh = *(const short8*)(whh + (size_t)(256 + col) * 128 + koff);
#pragma unroll
            for (int rt = 0; rt < 4; ++rt) {
                aR[rt][c2] = __builtin_amdgcn_mfma_f32_16x16x32_bf16(am[rt], bRi, aR[rt][c2], 0, 0, 0);
                aR[rt][c2] = __builtin_amdgcn_mfma_f32_16x16x32_bf16(ah[rt], bRh, aR[rt][c2], 0, 0, 0);
                aZ[rt][c2] = __builtin_amdgcn_mfma_f32_16x16x32_bf16(am[rt], bZi, aZ[rt][c2], 0, 0, 0);
                aZ[rt][c2] = __builtin_amdgcn_mfma_f32_16x16x32_bf16(ah[rt], bZh, aZ[rt][c2], 0, 0, 0);
                aN[rt][c2] = __builtin_amdgcn_mfma_f32_16x16x32_bf16(am[rt], bNi, aN[rt][c2], 0, 0, 0);
                aH[rt][c2] = __builtin_amdgcn_mfma_f32_16x16x32_bf16(ah[rt], bNh, aH[rt][c2], 0, 0, 0);
            }
        }
    }
#pragma unroll
    for (int c2 = 0; c2 < 2; ++c2) {
        int h = w * 32 + c2 * 16 + lr;
        float br = bih[h] + bhh[h];
        float bz = bih[128 + h] + bhh[128 + h];
        float bin = bih[256 + h], bhn = bhh[256 + h];
#pragma unroll
        for (int rt = 0; rt < 4; ++rt)
#pragma unroll
            for (int reg = 0; reg < 4; ++reg) {
                int lrow = rt * 16 + lq * 4 + reg;
                int row = bm + lrow;
                if (row >= Nn) continue;
                float r = sigm(aR[rt][c2][reg] + br);
                float z = sigm(aZ[rt][c2][reg] + bz);
                float n = ftanh(aN[rt][c2][reg] + bin + r * (aH[rt][c2][reg] + bhn));
                int hofs = lrow * 128 + (((h >> 3) ^ (lrow & 15)) * 8) + (h & 7);
                float hold = __bfloat162float(*(const bf16*)&Hs[hofs]);
                bf16 hv = __float2bfloat16((1.f - z) * n + z * hold);
                node[(size_t)row * 128 + h] = *(ushort*)&hv;
            }
    }
}

// ================= fused LSTM step: g4 = s@Wl^T + b ; gates ; hl -> s[:,0:128] ==========
// s = [hl | r] bf16 [G][256]; Wl [512][256] bf16 fused; in-place safe (rows staged first)
__global__ __launch_bounds__(256) void lstm_fused(
    ushort* __restrict__ s, const ushort* __restrict__ Wl,
    const float* __restrict__ bih, const float* __restrict__ bhh,
    float* __restrict__ cl, int Gn)
{
    __shared__ ushort Ss[32 * 256];
    const int tid = threadIdx.x;
    const int bm = blockIdx.x * 32;
#pragma unroll
    for (int p = 0; p < 4; ++p) {
        int ch = p * 256 + tid;          // 1024 = 32 rows x 32 chunks
        int r = ch >> 5, c = ch & 31;
        int row = bm + r;
        uint4 v = make_uint4(0u, 0u, 0u, 0u);
        if (row < Gn) v = *(const uint4*)(s + (size_t)row * 256 + c * 8);
        *(uint4*)(&Ss[r * 256 + ((c ^ (r & 15)) * 8)]) = v;
    }
    __syncthreads();
    const int lane = tid & 63, w = tid >> 6;
    const int lr = lane & 15, lq = lane >> 4;
    f32x4 acc[2][4][2] = {};   // [rt][gate][sub]
#pragma unroll
    for (int ks = 0; ks < 8; ++ks) {
        int cb = ks * 4 + lq;
        short8 am[2];
#pragma unroll
        for (int rt = 0; rt < 2; ++rt)
            am[rt] = *(const short8*)(&Ss[(rt * 16 + lr) * 256 + ((cb ^ lr) * 8)]);
        int koff = ks * 32 + lq * 8;
#pragma unroll
        for (int g = 0; g < 4; ++g)
#pragma unroll
            for (int sub = 0; sub < 2; ++sub) {
                int col = g * 128 + w * 32 + sub * 16 + lr;
                short8 bf = *(const short8*)(Wl + (size_t)col * 256 + koff);
#pragma unroll
                for (int rt = 0; rt < 2; ++rt)
                    acc[rt][g][sub] = __builtin_amdgcn_mfma_f32_16x16x32_bf16(am[rt], bf, acc[rt][g][sub], 0, 0, 0);
            }
    }
#pragma unroll
    for (int sub = 0; sub < 2; ++sub) {
        int h = w * 32 + sub * 16 + lr;
        float bi = bih[h] + bhh[h];
        float bff = bih[128 + h] + bhh[128 + h];
        float bg = bih[256 + h] + bhh[256 + h];
        float bo = bih[384 + h] + bhh[384 + h];
#pragma unroll
        for (int rt = 0; rt < 2; ++rt)
#pragma unroll
            for (int reg = 0; reg < 4; ++reg) {
                int row = bm + rt * 16 + lq * 4 + reg;
                if (row >= Gn) continue;
                float iv = sigm(acc[rt][0][sub][reg] + bi);
                float fv = sigm(acc[rt][1][sub][reg] + bff);
                float gv = ftanh(acc[rt][2][sub][reg] + bg);
                float ov = sigm(acc[rt][3][sub][reg] + bo);
                float c = fv * cl[(size_t)row * 128 + h] + iv * gv;
                cl[(size_t)row * 128 + h] = c;
                bf16 hv = __float2bfloat16(ov * ftanh(c));
                s[(size_t)row * 256 + h] = *(ushort*)&hv;
            }
    }
}

// ================= fused per-graph attention (s = [hl | r] bf16) ==============
__global__ __launch_bounds__(256) void att_fused(
    const bf16* __restrict__ node, ushort* __restrict__ s,
    const int* __restrict__ gptr)
{
    __shared__ float q[128];
    __shared__ float es[512];
    __shared__ float red[8];
    int g = blockIdx.x;
    int tid = threadIdx.x, lane = tid & 63, wid = tid >> 6;
    int n0 = gptr[g], n1 = gptr[g + 1];
    int cnt = n1 - n0; if (cnt > 512) cnt = 512;
    if (tid < 128) q[tid] = __bfloat162float(((const bf16*)s)[(size_t)g * 256 + tid]);
    __syncthreads();
    for (int i = wid; i < cnt; i += 4) {
        const bf16* nr = node + (size_t)(n0 + i) * TH;
        float p = __bfloat162float(nr[lane]) * q[lane]
                + __bfloat162float(nr[lane + 64]) * q[lane + 64];
        for (int off = 32; off; off >>= 1) p += __shfl_down(p, off);
        if (lane == 0) es[i] = p;
    }
    __syncthreads();
    float m = -1e30f;
    for (int i = tid; i < cnt; i += 256) m = fmaxf(m, es[i]);
    for (int off = 32; off; off >>= 1) m = fmaxf(m, __shfl_down(m, off));
    if (lane == 0) red[wid] = m;
    __syncthreads();
    m = fmaxf(fmaxf(red[0], red[1]), fmaxf(red[2], red[3]));
    float sm = 0.f;
    for (int i = tid; i < cnt; i += 256) { float ex = __expf(es[i] - m); es[i] = ex; sm += ex; }
    for (int off = 32; off; off >>= 1) sm += __shfl_down(sm, off);
    if (lane == 0) red[4 + wid] = sm;
    __syncthreads();
    sm = red[4] + red[5] + red[6] + red[7];
    float inv = 1.f / fmaxf(sm, 1e-9f);
    int c = tid & 127, half = tid >> 7;
    float r = 0.f;
    for (int i = half; i < cnt; i += 2)
        r += es[i] * __bfloat162float(node[(size_t)(n0 + i) * TH + c]);
    __syncthreads();
    if (half == 1) es[c] = r;
    __syncthreads();
    if (half == 0) {
        bf16 rv = __float2bfloat16((r + es[c]) * inv);
        s[(size_t)g * 256 + 128 + c] = *(ushort*)&rv;
    }
}

// ================= final FC (s bf16) =================
__global__ __launch_bounds__(128) void final_fc(const ushort* __restrict__ s,
                                                const float* __restrict__ w1,
                                                const float* __restrict__ b1,
                                                const float* __restrict__ w2,
                                                const float* __restrict__ b2,
                                                float* __restrict__ out) {
    __shared__ float q[256];
    __shared__ float red[2];
    int g = blockIdx.x, t = threadIdx.x;
    q[t] = __bfloat162float(((const bf16*)s)[(size_t)g * 256 + t]);
    q[t + 128] = __bfloat162float(((const bf16*)s)[(size_t)g * 256 + 128 + t]);
    __syncthreads();
    float acc = b1[t];
    for (int k = 0; k < 256; ++k) acc = fmaf(q[k], w1[k * TH + t], acc);
    acc = fmaxf(acc, 0.f);
    float p = acc * w2[t];
    for (int off = 32; off; off >>= 1) p += __shfl_down(p, off);
    if ((t & 63) == 0) red[t >> 6] = p;
    __syncthreads();
    if (t == 0) out[g] = red[0] + red[1] + b2[0];
}

// ---------------------------------------------------------------------------
static void launch_mlp2(const void* A, const bf16* W1t, const float* b1,
                        const bf16* W2t, const float* b2, void* C, int M, hipStream_t s) {
    hipLaunchKernelGGL(mlp2_fused, dim3((M + 127) / 128), dim3(256), 0, s,
                       (const ushort*)A, (const ushort*)W1t, b1, (const ushort*)W2t, b2,
                       (ushort*)C, M);
}

extern "C" void kernel_launch(void* const* d_in, const int* in_sizes, int n_in,
                              void* d_out, int out_size, void* d_ws, size_t ws_size,
                              hipStream_t stream) {
    const float* x         = (const float*)d_in[0];
    const float* edge_attr = (const float*)d_in[1];
    const int*   edge_index= (const int*)d_in[2];
    const int*   batch     = (const int*)d_in[3];
    const float* node_w    = (const float*)d_in[4];
    const float* node_b    = (const float*)d_in[5];
    const float* edge_w    = (const float*)d_in[6];
    const float* edge_b    = (const float*)d_in[7];
    const float* eps       = (const float*)d_in[8];
    const float* gin_w1    = (const float*)d_in[9];
    const float* gin_b1    = (const float*)d_in[10];
    const float* gin_w2    = (const float*)d_in[11];
    const float* gin_b2    = (const float*)d_in[12];
    const float* em_w1     = (const float*)d_in[13];
    const float* em_b1     = (const float*)d_in[14];
    const float* em_w2     = (const float*)d_in[15];
    const float* em_b2     = (const float*)d_in[16];
    const float* gru_wih   = (const float*)d_in[17];
    const float* gru_whh   = (const float*)d_in[18];
    const float* gru_bih   = (const float*)d_in[19];
    const float* gru_bhh   = (const float*)d_in[20];
    const float* lstm_wih  = (const float*)d_in[21];
    const float* lstm_whh  = (const float*)d_in[22];
    const float* lstm_bih  = (const float*)d_in[23];
    const float* lstm_bhh  = (const float*)d_in[24];
    const float* fc_w1     = (const float*)d_in[25];
    const float* fc_b1     = (const float*)d_in[26];
    const float* fc_w2     = (const float*)d_in[27];
    const float* fc_b2     = (const float*)d_in[28];
    float* out = (float*)d_out;
    const int* ei_src = edge_index;
    const int* ei_dst = edge_index + TE;

    // ---- workspace layout ----
    char* base = (char*)d_ws;
    size_t off = 0;
    auto alloc = [&](size_t bytes) { void* p = base + off; off += (bytes + 15) & ~size_t(15); return p; };
    bf16*  nodeb = (bf16*)alloc((size_t)TN * TH * 2);   // 25.6 MB
    bf16*  zb    = (bf16*)alloc((size_t)TN * TH * 2);   // 25.6 MB
    bf16*  e1b   = (bf16*)alloc((size_t)TE * TH * 2);   // 51.2 MB (set2set overlay later)
    int*   deg   = (int*)alloc((size_t)TN * 4);
    int*   rowptr= (int*)alloc((size_t)(TN + 1) * 4);
    int*   cur   = (int*)alloc((size_t)TN * 4);
    int*   srcp  = (int*)alloc((size_t)TE * 4);
    int*   epos  = (int*)alloc((size_t)TE * 4);
    int*   bsum  = (int*)alloc(512 * 4);
    int*   bsumx = (int*)alloc(512 * 4);
    int*   gptr  = (int*)alloc((size_t)(TG + 1) * 4);
    bf16*  w6    = (bf16*)alloc(6 * TH * TH * 2);
    bf16*  wgru  = (bf16*)alloc(2 * 384 * TH * 2);
    bf16*  wl    = (bf16*)alloc(512 * 256 * 2);
    if (ws_size < off) return;

    bf16* w_gin1_0 = w6;
    bf16* w_gin1_1 = w6 + 1 * TH * TH;
    bf16* w_gin2_0 = w6 + 2 * TH * TH;
    bf16* w_gin2_1 = w6 + 3 * TH * TH;
    bf16* w_em1    = w6 + 4 * TH * TH;
    bf16* w_em2    = w6 + 5 * TH * TH;
    bf16* w_wih    = wgru;
    bf16* w_whh    = wgru + 384 * TH;

    // set2set state overlays e1b (dead after layer-1 aggregation)
    ushort* sbuf = (ushort*)e1b;                     // [G][256] bf16
    float*  cl   = (float*)(sbuf + (size_t)TG * 256); // [G][128] fp32

    // ---- CSR + gptr ----
    hipMemsetAsync(deg, 0, (size_t)TN * 4, stream);
    hipMemsetAsync(cur, 0, (size_t)TN * 4, stream);
    count_deg<<<(TE + 255) / 256, 256, 0, stream>>>(ei_dst, deg, TE);
    int nb = (TN + 255) / 256;
    scan_block<<<nb, 256, 0, stream>>>(deg, rowptr, bsum, TN);
    scan_bsum<<<1, 512, 0, stream>>>(bsum, bsumx, nb);
    add_off<<<nb, 256, 0, stream>>>(rowptr, bsumx, TN, TE);
    fill_csr<<<(TE + 255) / 256, 256, 0, stream>>>(ei_src, ei_dst, rowptr, cur, srcp, epos, TE);
    build_gptr<<<(TN + 255) / 256, 256, 0, stream>>>(batch, gptr, TN, TG);

    // ---- weights ----
    conv6<<<(6 * TH * TH + 255) / 256, 256, 0, stream>>>(
        gin_w1, gin_w1 + TH * TH, gin_w2, gin_w2 + TH * TH, em_w1, em_w2, w6);
    conv2<<<(2 * 384 * TH + 255) / 256, 256, 0, stream>>>(gru_wih, gru_whh, wgru);
    convL<<<(512 * 256 + 255) / 256, 256, 0, stream>>>(lstm_wih, lstm_whh, wl);

    // ---- projections (edges scattered into CSR slot order) ----
    proj16<14, false><<<(TN + 15) / 16, 256, 0, stream>>>(x, node_w, node_b, (ushort*)nodeb, nullptr, TN);
    proj16<4,  true ><<<(TE + 15) / 16, 256, 0, stream>>>(edge_attr, edge_w, edge_b, (ushort*)e1b, epos, TE);

    // ---- layer 0 ----
    aggregate_k<<<(TN + 1) / 2, 256, 0, stream>>>(nodeb, e1b, srcp, rowptr, eps, 0, zb, TN);
    launch_mlp2(zb, w_gin1_0, gin_b1, w_gin2_0, gin_b2, zb, TN, stream);
    gru_fused<<<(TN + 63) / 64, 256, 0, stream>>>(
        (const ushort*)zb, (const ushort*)w_wih, (const ushort*)w_whh,
        gru_bih, gru_bhh, (ushort*)nodeb, TN);

    // ---- edge MLP (in-place, slot order preserved), layer 1 ----
    launch_mlp2(e1b, w_em1, em_b1, w_em2, em_b2, e1b, TE, stream);
    aggregate_k<<<(TN + 1) / 2, 256, 0, stream>>>(nodeb, e1b, srcp, rowptr, eps, 1, zb, TN);
    launch_mlp2(zb, w_gin1_1, gin_b1 + TH, w_gin2_1, gin_b2 + TH, zb, TN, stream);
    gru_fused<<<(TN + 63) / 64, 256, 0, stream>>>(
        (const ushort*)zb, (const ushort*)w_wih, (const ushort*)w_whh,
        gru_bih, gru_bhh, (ushort*)nodeb, TN);

    // ---- Set2Set (3 steps; s=[hl|r] bf16, cl fp32) ----
    hipMemsetAsync(sbuf, 0, (size_t)TG * 256 * 2 + (size_t)TG * 128 * 4, stream);
    for (int st = 0; st < 3; ++st) {
        lstm_fused<<<(TG + 31) / 32, 256, 0, stream>>>(
            sbuf, (const ushort*)wl, lstm_bih, lstm_bhh, cl, TG);
        att_fused<<<TG, 256, 0, stream>>>(nodeb, sbuf, gptr);
    }

    // ---- final FC ----
    final_fc<<<TG, 128, 0, stream>>>(sbuf, fc_w1, fc_b1, fc_w2, fc_b2, out);
}

// Round 7
// 671.811 us; speedup vs baseline: 5.2746x; 1.2016x over previous
//
#include <hip/hip_runtime.h>
#include <hip/hip_bf16.h>

constexpr int TN = 100000;   // nodes
constexpr int TE = 200000;   // edges
constexpr int TG = 4000;     // graphs
constexpr int TH = 128;      // hidden

using short8 = __attribute__((ext_vector_type(8))) short;
using f32x4  = __attribute__((ext_vector_type(4))) float;
typedef __hip_bfloat16 bf16;

#define DEVINL __device__ __forceinline__
DEVINL float sigm(float x)  { return 1.f / (1.f + __expf(-x)); }
DEVINL float ftanh(float x) { return 1.f - 2.f / (__expf(2.f * x) + 1.f); }
DEVINL void unpack8(uint4 v, float* f) {
    const ushort* u = (const ushort*)&v;
#pragma unroll
    for (int j = 0; j < 8; ++j) f[j] = __bfloat162float(*(const bf16*)&u[j]);
}

// ================= weight conversion =================
__global__ void conv6(const float* __restrict__ s0, const float* __restrict__ s1,
                      const float* __restrict__ s2, const float* __restrict__ s3,
                      const float* __restrict__ s4, const float* __restrict__ s5,
                      bf16* __restrict__ dst) {
    int i = blockIdx.x * 256 + threadIdx.x;
    if (i >= 6 * TH * TH) return;
    int m = i >> 14, r = i & 16383;
    int n = r >> 7, k = r & 127;
    const float* s = (m == 0) ? s0 : (m == 1) ? s1 : (m == 2) ? s2
                   : (m == 3) ? s3 : (m == 4) ? s4 : s5;
    dst[i] = __float2bfloat16(s[k * TH + n]);
}
__global__ void conv2(const float* __restrict__ a, const float* __restrict__ b,
                      bf16* __restrict__ dst) {
    int i = blockIdx.x * 256 + threadIdx.x;
    if (i >= 2 * 384 * TH) return;
    const float* s = (i < 384 * TH) ? a : b;
    int r = (i < 384 * TH) ? i : i - 384 * TH;
    dst[i] = __float2bfloat16(s[r]);
}
__global__ void convL(const float* __restrict__ wih, const float* __restrict__ whh,
                      bf16* __restrict__ dst) {
    int i = blockIdx.x * 256 + threadIdx.x;
    if (i >= 512 * 256) return;
    int c = i >> 8, k = i & 255;
    float v = (k < 128) ? wih[c * 256 + k] + whh[c * 128 + k] : wih[c * 256 + k];
    dst[i] = __float2bfloat16(v);
}

// ================= projection: 64 rows/block, 4 rows x 8 ch per thread ============
template<int K, bool PERM>
__global__ __launch_bounds__(256) void proj64(const float* __restrict__ X,
                                              const float* __restrict__ W,
                                              const float* __restrict__ b,
                                              ushort* __restrict__ out,
                                              const int* __restrict__ perm, int M) {
    __shared__ float xs[64][K];
    int tid = threadIdx.x;
    int bm = blockIdx.x * 64;
    for (int i = tid; i < 64 * K; i += 256) {
        int r = i / K, k = i % K;
        xs[r][k] = (bm + r < M) ? X[(size_t)(bm + r) * K + k] : 0.f;
    }
    __syncthreads();
    int rb = tid >> 4, h0 = (tid & 15) * 8;
    float acc[4][8];
#pragma unroll
    for (int j = 0; j < 4; ++j)
#pragma unroll
        for (int c = 0; c < 8; ++c) acc[j][c] = b[h0 + c];
#pragma unroll
    for (int k = 0; k < K; ++k) {
        float4 w0 = *(const float4*)(W + k * TH + h0);
        float4 w1 = *(const float4*)(W + k * TH + h0 + 4);
#pragma unroll
        for (int j = 0; j < 4; ++j) {
            float xv = xs[rb + 16 * j][k];
            acc[j][0] = fmaf(xv, w0.x, acc[j][0]); acc[j][1] = fmaf(xv, w0.y, acc[j][1]);
            acc[j][2] = fmaf(xv, w0.z, acc[j][2]); acc[j][3] = fmaf(xv, w0.w, acc[j][3]);
            acc[j][4] = fmaf(xv, w1.x, acc[j][4]); acc[j][5] = fmaf(xv, w1.y, acc[j][5]);
            acc[j][6] = fmaf(xv, w1.z, acc[j][6]); acc[j][7] = fmaf(xv, w1.w, acc[j][7]);
        }
    }
#pragma unroll
    for (int j = 0; j < 4; ++j) {
        int row = bm + rb + 16 * j;
        if (row >= M) continue;
        ushort o[8];
#pragma unroll
        for (int c = 0; c < 8; ++c) {
            bf16 v = __float2bfloat16(acc[j][c]);
            o[c] = *(ushort*)&v;
        }
        int orow = PERM ? perm[row] : row;
        *(uint4*)(out + (size_t)orow * TH + h0) = *(uint4*)o;
    }
}

// ================= CSR build =================
__global__ void count_deg(const int* __restrict__ ei_dst, int* __restrict__ deg, int En) {
    int e = blockIdx.x * 256 + threadIdx.x;
    if (e < En) atomicAdd(&deg[ei_dst[e]], 1);
}
__global__ void scan_block(const int* __restrict__ deg, int* __restrict__ rowptr,
                           int* __restrict__ bsum, int Nn) {
    __shared__ int sm[256];
    int tid = threadIdx.x;
    int gid = blockIdx.x * 256 + tid;
    int v = (gid < Nn) ? deg[gid] : 0;
    int x = v;
    sm[tid] = x; __syncthreads();
    for (int off = 1; off < 256; off <<= 1) {
        int t = (tid >= off) ? sm[tid - off] : 0;
        __syncthreads();
        x += t; sm[tid] = x;
        __syncthreads();
    }
    if (gid < Nn) rowptr[gid] = x - v;
    if (tid == 255) bsum[blockIdx.x] = x;
}
__global__ void scan_bsum(const int* __restrict__ bsum, int* __restrict__ bsumx, int nb) {
    __shared__ int sm[512];
    int tid = threadIdx.x;
    int v = (tid < nb) ? bsum[tid] : 0;
    int x = v;
    sm[tid] = x; __syncthreads();
    for (int off = 1; off < 512; off <<= 1) {
        int t = (tid >= off) ? sm[tid - off] : 0;
        __syncthreads();
        x += t; sm[tid] = x;
        __syncthreads();
    }
    if (tid < nb) bsumx[tid] = x - v;
}
__global__ void add_off(int* __restrict__ rowptr, const int* __restrict__ bsumx,
                        int Nn, int Etot) {
    int gid = blockIdx.x * 256 + threadIdx.x;
    if (gid < Nn) rowptr[gid] += bsumx[gid >> 8];
    if (gid == 0) rowptr[Nn] = Etot;
}
__global__ void fill_csr(const int* __restrict__ ei_src, const int* __restrict__ ei_dst,
                         const int* __restrict__ rowptr, int* __restrict__ cur,
                         int* __restrict__ srcp, int* __restrict__ epos, int En) {
    int e = blockIdx.x * 256 + threadIdx.x;
    if (e >= En) return;
    int d = ei_dst[e];
    int p = atomicAdd(&cur[d], 1);
    int slot = rowptr[d] + p;
    srcp[slot] = ei_src[e];
    epos[e] = slot;
}
__global__ void build_gptr(const int* __restrict__ batch, int* __restrict__ gptr,
                           int Nn, int Gn) {
    int n = blockIdx.x * 256 + threadIdx.x;
    if (n >= Nn) return;
    int bc = batch[n];
    int bp = (n == 0) ? -1 : batch[n - 1];
    for (int g = bp + 1; g <= bc; ++g) gptr[g] = n;
    if (n == Nn - 1) for (int g = bc + 1; g <= Gn; ++g) gptr[g] = Nn;
}

// ========== aggregation, 8 channels/thread (16 threads per node) ==========
__global__ __launch_bounds__(256) void aggregate_v8(
    const ushort* __restrict__ node, const ushort* __restrict__ ef,
    const int* __restrict__ srcp, const int* __restrict__ rowptr,
    const float* __restrict__ eps, int l, ushort* __restrict__ zb, int Nn) {
    int t = blockIdx.x * 256 + threadIdx.x;
    int n = t >> 4;
    if (n >= Nn) return;
    int c8 = (t & 15) * 8;
    float se = 1.f + eps[l];
    float acc[8];
    uint4 nv = *(const uint4*)(node + (size_t)n * TH + c8);
    unpack8(nv, acc);
#pragma unroll
    for (int j = 0; j < 8; ++j) acc[j] *= se;
    int s0 = rowptr[n], s1 = rowptr[n + 1];
    for (int i = s0; i < s1; ++i) {
        int src = srcp[i];
        uint4 av = *(const uint4*)(node + (size_t)src * TH + c8);
        uint4 bv = *(const uint4*)(ef + (size_t)i * TH + c8);
        float af[8], bf[8];
        unpack8(av, af); unpack8(bv, bf);
#pragma unroll
        for (int j = 0; j < 8; ++j) acc[j] += fmaxf(af[j] + bf[j], 0.f);
    }
    ushort o[8];
#pragma unroll
    for (int j = 0; j < 8; ++j) {
        bf16 v = __float2bfloat16(acc[j]);
        o[j] = *(ushort*)&v;
    }
    *(uint4*)(zb + (size_t)n * TH + c8) = *(uint4*)o;
}

// ================= fused 2-layer MLP (weights preloaded to registers) =================
__global__ __launch_bounds__(256) void mlp2_fused(
    const ushort* __restrict__ A, const ushort* __restrict__ W1t,
    const float* __restrict__ b1, const ushort* __restrict__ W2t,
    const float* __restrict__ b2, ushort* __restrict__ C, int M)
{
    __shared__ ushort As[128 * 128];
    __shared__ ushort Ts[128 * 128];
    const int tid = threadIdx.x;
    const int bm = blockIdx.x * 128;
    const int lane = tid & 63, w = tid >> 6;
    const int lr = lane & 15, lq = lane >> 4;
    const int wm = (w & 1) * 64, wn = (w >> 1) * 64;
    short8 wf[4][4];
#pragma unroll
    for (int ni = 0; ni < 4; ++ni)
#pragma unroll
        for (int ks = 0; ks < 4; ++ks)
            wf[ni][ks] = *(const short8*)(W1t + (size_t)(wn + ni * 16 + lr) * 128 + ks * 32 + lq * 8);
#pragma unroll
    for (int p = 0; p < 8; ++p) {
        int ch = p * 256 + tid;
        int r = ch >> 4, c = ch & 15;
        int row = bm + r;
        uint4 v = make_uint4(0u, 0u, 0u, 0u);
        if (row < M) v = *(const uint4*)(A + (size_t)row * 128 + c * 8);
        *(uint4*)(&As[r * 128 + ((c ^ (r & 15)) * 8)]) = v;
    }
    __syncthreads();
    {
        f32x4 acc[4][4] = {};
#pragma unroll
        for (int ks = 0; ks < 4; ++ks) {
            int cb = ks * 4 + lq;
            short8 af[4];
#pragma unroll
            for (int mi = 0; mi < 4; ++mi)
                af[mi] = *(const short8*)(&As[(wm + mi * 16 + lr) * 128 + ((cb ^ lr) * 8)]);
#pragma unroll
            for (int mi = 0; mi < 4; ++mi)
#pragma unroll
                for (int ni = 0; ni < 4; ++ni)
                    acc[mi][ni] = __builtin_amdgcn_mfma_f32_16x16x32_bf16(af[mi], wf[ni][ks], acc[mi][ni], 0, 0, 0);
        }
#pragma unroll
        for (int mi = 0; mi < 4; ++mi)
#pragma unroll
            for (int reg = 0; reg < 4; ++reg) {
                int row = wm + mi * 16 + lq * 4 + reg;
#pragma unroll
                for (int ni = 0; ni < 4; ++ni) {
                    int col = wn + ni * 16 + lr;
                    float v = fmaxf(acc[mi][ni][reg] + b1[col], 0.f);
                    bf16 bv = __float2bfloat16(v);
                    Ts[row * 128 + (((col >> 3) ^ (row & 15)) * 8) + (col & 7)] = *(ushort*)&bv;
                }
            }
    }
#pragma unroll
    for (int ni = 0; ni < 4; ++ni)
#pragma unroll
        for (int ks = 0; ks < 4; ++ks)
            wf[ni][ks] = *(const short8*)(W2t + (size_t)(wn + ni * 16 + lr) * 128 + ks * 32 + lq * 8);
    __syncthreads();
    {
        f32x4 acc[4][4] = {};
#pragma unroll
        for (int ks = 0; ks < 4; ++ks) {
            int cb = ks * 4 + lq;
            short8 af[4];
#pragma unroll
            for (int mi = 0; mi < 4; ++mi)
                af[mi] = *(const short8*)(&Ts[(wm + mi * 16 + lr) * 128 + ((cb ^ lr) * 8)]);
#pragma unroll
            for (int mi = 0; mi < 4; ++mi)
#pragma unroll
                for (int ni = 0; ni < 4; ++ni)
                    acc[mi][ni] = __builtin_amdgcn_mfma_f32_16x16x32_bf16(af[mi], wf[ni][ks], acc[mi][ni], 0, 0, 0);
        }
#pragma unroll
        for (int mi = 0; mi < 4; ++mi)
#pragma unroll
            for (int reg = 0; reg < 4; ++reg) {
                int row = bm + wm + mi * 16 + lq * 4 + reg;
                if (row >= M) continue;
#pragma unroll
                for (int ni = 0; ni < 4; ++ni) {
                    int col = wn + ni * 16 + lr;
                    bf16 bv = __float2bfloat16(acc[mi][ni][reg] + b2[col]);
                    C[(size_t)row * 128 + col] = *(ushort*)&bv;
                }
            }
    }
}

// ================= fused GRU (32 rows/block — measured-best occupancy) =================
__global__ __launch_bounds__(256) void gru_fused(
    const ushort* __restrict__ mfeat, const ushort* __restrict__ wih,
    const ushort* __restrict__ whh, const float* __restrict__ bih,
    const float* __restrict__ bhh, ushort* __restrict__ node, int Nn)
{
    __shared__ ushort Ms[32 * 128];
    __shared__ ushort Hs[32 * 128];
    const int tid = threadIdx.x;
    const int bm = blockIdx.x * 32;
#pragma unroll
    for (int p = 0; p < 4; ++p) {
        int ch = p * 256 + tid;          // 1024 = 2 bufs x 32 rows x 16 chunks
        bool isH = ch >= 512;
        int r = (ch >> 4) & 31, c = ch & 15;
        int row = bm + r;
        uint4 v = make_uint4(0u, 0u, 0u, 0u);
        if (row < Nn) v = *(const uint4*)((isH ? node : mfeat) + (size_t)row * 128 + c * 8);
        ushort* dst = isH ? Hs : Ms;
        *(uint4*)(&dst[r * 128 + ((c ^ (r & 15)) * 8)]) = v;
    }
    __syncthreads();
    const int lane = tid & 63, w = tid >> 6;
    const int lr = lane & 15, lq = lane >> 4;
    f32x4 aR[2][2] = {}, aZ[2][2] = {}, aN[2][2] = {}, aH[2][2] = {};
#pragma unroll
    for (int ks = 0; ks < 4; ++ks) {
        int cb = ks * 4 + lq;
        short8 am[2], ah[2];
#pragma unroll
        for (int rt = 0; rt < 2; ++rt) {
            int off = (rt * 16 + lr) * 128 + ((cb ^ lr) * 8);
            am[rt] = *(const short8*)(&Ms[off]);
            ah[rt] = *(const short8*)(&Hs[off]);
        }
        int koff = ks * 32 + lq * 8;
        // bulk-issue all 12 weight loads for this k-step
        short8 wv[2][6];
#pragma unroll
        for (int c2 = 0; c2 < 2; ++c2) {
            int col = w * 32 + c2 * 16 + lr;
            wv[c2][0] = *(const short8*)(wih + (size_t)col * 128 + koff);
            wv[c2][1] = *(const short8*)(wih + (size_t)(128 + col) * 128 + koff);
            wv[c2][2] = *(const short8*)(wih + (size_t)(256 + col) * 128 + koff);
            wv[c2][3] = *(const short8*)(whh + (size_t)col * 128 + koff);
            wv[c2][4] = *(const short8*)(whh + (size_t)(128 + col) * 128 + koff);
            wv[c2][5] = *(const short8*)(whh + (size_t)(256 + col) * 128 + koff);
        }
#pragma unroll
        for (int c2 = 0; c2 < 2; ++c2)
#pragma unroll
            for (int rt = 0; rt < 2; ++rt) {
                aR[rt][c2] = __builtin_amdgcn_mfma_f32_16x16x32_bf16(am[rt], wv[c2][0], aR[rt][c2], 0, 0, 0);
                aR[rt][c2] = __builtin_amdgcn_mfma_f32_16x16x32_bf16(ah[rt], wv[c2][3], aR[rt][c2], 0, 0, 0);
                aZ[rt][c2] = __builtin_amdgcn_mfma_f32_16x16x32_bf16(am[rt], wv[c2][1], aZ[rt][c2], 0, 0, 0);
                aZ[rt][c2] = __builtin_amdgcn_mfma_f32_16x16x32_bf16(ah[rt], wv[c2][4], aZ[rt][c2], 0, 0, 0);
                aN[rt][c2] = __builtin_amdgcn_mfma_f32_16x16x32_bf16(am[rt], wv[c2][2], aN[rt][c2], 0, 0, 0);
                aH[rt][c2] = __builtin_amdgcn_mfma_f32_16x16x32_bf16(ah[rt], wv[c2][5], aH[rt][c2], 0, 0, 0);
            }
    }
#pragma unroll
    for (int c2 = 0; c2 < 2; ++c2) {
        int h = w * 32 + c2 * 16 + lr;
        float br = bih[h] + bhh[h];
        float bz = bih[128 + h] + bhh[128 + h];
        float bin = bih[256 + h], bhn = bhh[256 + h];
#pragma unroll
        for (int rt = 0; rt < 2; ++rt)
#pragma unroll
            for (int reg = 0; reg < 4; ++reg) {
                int lrow = rt * 16 + lq * 4 + reg;
                int row = bm + lrow;
                if (row >= Nn) continue;
                float r = sigm(aR[rt][c2][reg] + br);
                float z = sigm(aZ[rt][c2][reg] + bz);
                float n = ftanh(aN[rt][c2][reg] + bin + r * (aH[rt][c2][reg] + bhn));
                int hofs = lrow * 128 + (((h >> 3) ^ (lrow & 15)) * 8) + (h & 7);
                float hold = __bfloat162float(*(const bf16*)&Hs[hofs]);
                bf16 hv = __float2bfloat16((1.f - z) * n + z * hold);
                node[(size_t)row * 128 + h] = *(ushort*)&hv;
            }
    }
}

// ================= fused LSTM step =================
__global__ __launch_bounds__(256) void lstm_fused(
    ushort* __restrict__ s, const ushort* __restrict__ Wl,
    const float* __restrict__ bih, const float* __restrict__ bhh,
    float* __restrict__ cl, int Gn)
{
    __shared__ ushort Ss[32 * 256];
    const int tid = threadIdx.x;
    const int bm = blockIdx.x * 32;
#pragma unroll
    for (int p = 0; p < 4; ++p) {
        int ch = p * 256 + tid;
        int r = ch >> 5, c = ch & 31;
        int row = bm + r;
        uint4 v = make_uint4(0u, 0u, 0u, 0u);
        if (row < Gn) v = *(const uint4*)(s + (size_t)row * 256 + c * 8);
        *(uint4*)(&Ss[r * 256 + ((c ^ (r & 15)) * 8)]) = v;
    }
    __syncthreads();
    const int lane = tid & 63, w = tid >> 6;
    const int lr = lane & 15, lq = lane >> 4;
    f32x4 acc[2][4][2] = {};
#pragma unroll
    for (int ks = 0; ks < 8; ++ks) {
        int cb = ks * 4 + lq;
        short8 am[2];
#pragma unroll
        for (int rt = 0; rt < 2; ++rt)
            am[rt] = *(const short8*)(&Ss[(rt * 16 + lr) * 256 + ((cb ^ lr) * 8)]);
        int koff = ks * 32 + lq * 8;
#pragma unroll
        for (int g = 0; g < 4; ++g)
#pragma unroll
            for (int sub = 0; sub < 2; ++sub) {
                int col = g * 128 + w * 32 + sub * 16 + lr;
                short8 bf = *(const short8*)(Wl + (size_t)col * 256 + koff);
#pragma unroll
                for (int rt = 0; rt < 2; ++rt)
                    acc[rt][g][sub] = __builtin_amdgcn_mfma_f32_16x16x32_bf16(am[rt], bf, acc[rt][g][sub], 0, 0, 0);
            }
    }
#pragma unroll
    for (int sub = 0; sub < 2; ++sub) {
        int h = w * 32 + sub * 16 + lr;
        float bi = bih[h] + bhh[h];
        float bff = bih[128 + h] + bhh[128 + h];
        float bg = bih[256 + h] + bhh[256 + h];
        float bo = bih[384 + h] + bhh[384 + h];
#pragma unroll
        for (int rt = 0; rt < 2; ++rt)
#pragma unroll
            for (int reg = 0; reg < 4; ++reg) {
                int row = bm + rt * 16 + lq * 4 + reg;
                if (row >= Gn) continue;
                float iv = sigm(acc[rt][0][sub][reg] + bi);
                float fv = sigm(acc[rt][1][sub][reg] + bff);
                float gv = ftanh(acc[rt][2][sub][reg] + bg);
                float ov = sigm(acc[rt][3][sub][reg] + bo);
                float c = fv * cl[(size_t)row * 128 + h] + iv * gv;
                cl[(size_t)row * 128 + h] = c;
                bf16 hv = __float2bfloat16(ov * ftanh(c));
                s[(size_t)row * 256 + h] = *(ushort*)&hv;
            }
    }
}

// ================= fused per-graph attention =================
__global__ __launch_bounds__(256) void att_fused(
    const bf16* __restrict__ node, ushort* __restrict__ s,
    const int* __restrict__ gptr)
{
    __shared__ float q[128];
    __shared__ float es[512];
    __shared__ float red[8];
    int g = blockIdx.x;
    int tid = threadIdx.x, lane = tid & 63, wid = tid >> 6;
    int n0 = gptr[g], n1 = gptr[g + 1];
    int cnt = n1 - n0; if (cnt > 512) cnt = 512;
    if (tid < 128) q[tid] = __bfloat162float(((const bf16*)s)[(size_t)g * 256 + tid]);
    __syncthreads();
    for (int i = wid; i < cnt; i += 4) {
        const bf16* nr = node + (size_t)(n0 + i) * TH;
        float p = __bfloat162float(nr[lane]) * q[lane]
                + __bfloat162float(nr[lane + 64]) * q[lane + 64];
        for (int off = 32; off; off >>= 1) p += __shfl_down(p, off);
        if (lane == 0) es[i] = p;
    }
    __syncthreads();
    float m = -1e30f;
    for (int i = tid; i < cnt; i += 256) m = fmaxf(m, es[i]);
    for (int off = 32; off; off >>= 1) m = fmaxf(m, __shfl_down(m, off));
    if (lane == 0) red[wid] = m;
    __syncthreads();
    m = fmaxf(fmaxf(red[0], red[1]), fmaxf(red[2], red[3]));
    float sm = 0.f;
    for (int i = tid; i < cnt; i += 256) { float ex = __expf(es[i] - m); es[i] = ex; sm += ex; }
    for (int off = 32; off; off >>= 1) sm += __shfl_down(sm, off);
    if (lane == 0) red[4 + wid] = sm;
    __syncthreads();
    sm = red[4] + red[5] + red[6] + red[7];
    float inv = 1.f / fmaxf(sm, 1e-9f);
    int c = tid & 127, half = tid >> 7;
    float r = 0.f;
    for (int i = half; i < cnt; i += 2)
        r += es[i] * __bfloat162float(node[(size_t)(n0 + i) * TH + c]);
    __syncthreads();
    if (half == 1) es[c] = r;
    __syncthreads();
    if (half == 0) {
        bf16 rv = __float2bfloat16((r + es[c]) * inv);
        s[(size_t)g * 256 + 128 + c] = *(ushort*)&rv;
    }
}

// ================= final FC =================
__global__ __launch_bounds__(128) void final_fc(const ushort* __restrict__ s,
                                                const float* __restrict__ w1,
                                                const float* __restrict__ b1,
                                                const float* __restrict__ w2,
                                                const float* __restrict__ b2,
                                                float* __restrict__ out) {
    __shared__ float q[256];
    __shared__ float red[2];
    int g = blockIdx.x, t = threadIdx.x;
    q[t] = __bfloat162float(((const bf16*)s)[(size_t)g * 256 + t]);
    q[t + 128] = __bfloat162float(((const bf16*)s)[(size_t)g * 256 + 128 + t]);
    __syncthreads();
    float acc = b1[t];
    for (int k = 0; k < 256; ++k) acc = fmaf(q[k], w1[k * TH + t], acc);
    acc = fmaxf(acc, 0.f);
    float p = acc * w2[t];
    for (int off = 32; off; off >>= 1) p += __shfl_down(p, off);
    if ((t & 63) == 0) red[t >> 6] = p;
    __syncthreads();
    if (t == 0) out[g] = red[0] + red[1] + b2[0];
}

// ---------------------------------------------------------------------------
static void launch_mlp2(const void* A, const bf16* W1t, const float* b1,
                        const bf16* W2t, const float* b2, void* C, int M, hipStream_t s) {
    hipLaunchKernelGGL(mlp2_fused, dim3((M + 127) / 128), dim3(256), 0, s,
                       (const ushort*)A, (const ushort*)W1t, b1, (const ushort*)W2t, b2,
                       (ushort*)C, M);
}

extern "C" void kernel_launch(void* const* d_in, const int* in_sizes, int n_in,
                              void* d_out, int out_size, void* d_ws, size_t ws_size,
                              hipStream_t stream) {
    const float* x         = (const float*)d_in[0];
    const float* edge_attr = (const float*)d_in[1];
    const int*   edge_index= (const int*)d_in[2];
    const int*   batch     = (const int*)d_in[3];
    const float* node_w    = (const float*)d_in[4];
    const float* node_b    = (const float*)d_in[5];
    const float* edge_w    = (const float*)d_in[6];
    const float* edge_b    = (const float*)d_in[7];
    const float* eps       = (const float*)d_in[8];
    const float* gin_w1    = (const float*)d_in[9];
    const float* gin_b1    = (const float*)d_in[10];
    const float* gin_w2    = (const float*)d_in[11];
    const float* gin_b2    = (const float*)d_in[12];
    const float* em_w1     = (const float*)d_in[13];
    const float* em_b1     = (const float*)d_in[14];
    const float* em_w2     = (const float*)d_in[15];
    const float* em_b2     = (const float*)d_in[16];
    const float* gru_wih   = (const float*)d_in[17];
    const float* gru_whh   = (const float*)d_in[18];
    const float* gru_bih   = (const float*)d_in[19];
    const float* gru_bhh   = (const float*)d_in[20];
    const float* lstm_wih  = (const float*)d_in[21];
    const float* lstm_whh  = (const float*)d_in[22];
    const float* lstm_bih  = (const float*)d_in[23];
    const float* lstm_bhh  = (const float*)d_in[24];
    const float* fc_w1     = (const float*)d_in[25];
    const float* fc_b1     = (const float*)d_in[26];
    const float* fc_w2     = (const float*)d_in[27];
    const float* fc_b2     = (const float*)d_in[28];
    float* out = (float*)d_out;
    const int* ei_src = edge_index;
    const int* ei_dst = edge_index + TE;

    // ---- workspace layout ----
    char* base = (char*)d_ws;
    size_t off = 0;
    auto alloc = [&](size_t bytes) { void* p = base + off; off += (bytes + 15) & ~size_t(15); return p; };
    bf16*  nodeb = (bf16*)alloc((size_t)TN * TH * 2);   // 25.6 MB
    bf16*  zb    = (bf16*)alloc((size_t)TN * TH * 2);   // 25.6 MB
    bf16*  e1b   = (bf16*)alloc((size_t)TE * TH * 2);   // 51.2 MB (set2set overlay later)
    int*   deg   = (int*)alloc((size_t)TN * 4);
    int*   rowptr= (int*)alloc((size_t)(TN + 1) * 4);
    int*   cur   = (int*)alloc((size_t)TN * 4);
    int*   srcp  = (int*)alloc((size_t)TE * 4);
    int*   epos  = (int*)alloc((size_t)TE * 4);
    int*   bsum  = (int*)alloc(512 * 4);
    int*   bsumx = (int*)alloc(512 * 4);
    int*   gptr  = (int*)alloc((size_t)(TG + 1) * 4);
    bf16*  w6    = (bf16*)alloc(6 * TH * TH * 2);
    bf16*  wgru  = (bf16*)alloc(2 * 384 * TH * 2);
    bf16*  wl    = (bf16*)alloc(512 * 256 * 2);
    if (ws_size < off) return;

    bf16* w_gin1_0 = w6;
    bf16* w_gin1_1 = w6 + 1 * TH * TH;
    bf16* w_gin2_0 = w6 + 2 * TH * TH;
    bf16* w_gin2_1 = w6 + 3 * TH * TH;
    bf16* w_em1    = w6 + 4 * TH * TH;
    bf16* w_em2    = w6 + 5 * TH * TH;
    bf16* w_wih    = wgru;
    bf16* w_whh    = wgru + 384 * TH;

    ushort* sbuf = (ushort*)e1b;                      // [G][256] bf16
    float*  cl   = (float*)(sbuf + (size_t)TG * 256); // [G][128] fp32

    // ---- CSR + gptr ----
    hipMemsetAsync(deg, 0, (size_t)TN * 4, stream);
    hipMemsetAsync(cur, 0, (size_t)TN * 4, stream);
    count_deg<<<(TE + 255) / 256, 256, 0, stream>>>(ei_dst, deg, TE);
    int nb = (TN + 255) / 256;
    scan_block<<<nb, 256, 0, stream>>>(deg, rowptr, bsum, TN);
    scan_bsum<<<1, 512, 0, stream>>>(bsum, bsumx, nb);
    add_off<<<nb, 256, 0, stream>>>(rowptr, bsumx, TN, TE);
    fill_csr<<<(TE + 255) / 256, 256, 0, stream>>>(ei_src, ei_dst, rowptr, cur, srcp, epos, TE);
    build_gptr<<<(TN + 255) / 256, 256, 0, stream>>>(batch, gptr, TN, TG);

    // ---- weights ----
    conv6<<<(6 * TH * TH + 255) / 256, 256, 0, stream>>>(
        gin_w1, gin_w1 + TH * TH, gin_w2, gin_w2 + TH * TH, em_w1, em_w2, w6);
    conv2<<<(2 * 384 * TH + 255) / 256, 256, 0, stream>>>(gru_wih, gru_whh, wgru);
    convL<<<(512 * 256 + 255) / 256, 256, 0, stream>>>(lstm_wih, lstm_whh, wl);

    // ---- projections (edges scattered into CSR slot order) ----
    proj64<14, false><<<(TN + 63) / 64, 256, 0, stream>>>(x, node_w, node_b, (ushort*)nodeb, nullptr, TN);
    proj64<4,  true ><<<(TE + 63) / 64, 256, 0, stream>>>(edge_attr, edge_w, edge_b, (ushort*)e1b, epos, TE);

    // ---- layer 0 ----
    aggregate_v8<<<(TN * 16 + 255) / 256, 256, 0, stream>>>(
        (const ushort*)nodeb, (const ushort*)e1b, srcp, rowptr, eps, 0, (ushort*)zb, TN);
    launch_mlp2(zb, w_gin1_0, gin_b1, w_gin2_0, gin_b2, zb, TN, stream);
    gru_fused<<<(TN + 31) / 32, 256, 0, stream>>>(
        (const ushort*)zb, (const ushort*)w_wih, (const ushort*)w_whh,
        gru_bih, gru_bhh, (ushort*)nodeb, TN);

    // ---- edge MLP (in-place, slot order preserved), layer 1 ----
    launch_mlp2(e1b, w_em1, em_b1, w_em2, em_b2, e1b, TE, stream);
    aggregate_v8<<<(TN * 16 + 255) / 256, 256, 0, stream>>>(
        (const ushort*)nodeb, (const ushort*)e1b, srcp, rowptr, eps, 1, (ushort*)zb, TN);
    launch_mlp2(zb, w_gin1_1, gin_b1 + TH, w_gin2_1, gin_b2 + TH, zb, TN, stream);
    gru_fused<<<(TN + 31) / 32, 256, 0, stream>>>(
        (const ushort*)zb, (const ushort*)w_wih, (const ushort*)w_whh,
        gru_bih, gru_bhh, (ushort*)nodeb, TN);

    // ---- Set2Set (3 steps) ----
    hipMemsetAsync(sbuf, 0, (size_t)TG * 256 * 2 + (size_t)TG * 128 * 4, stream);
    for (int st = 0; st < 3; ++st) {
        lstm_fused<<<(TG + 31) / 32, 256, 0, stream>>>(
            sbuf, (const ushort*)wl, lstm_bih, lstm_bhh, cl, TG);
        att_fused<<<TG, 256, 0, stream>>>(nodeb, sbuf, gptr);
    }

    // ---- final FC ----
    final_fc<<<TG, 128, 0, stream>>>(sbuf, fc_w1, fc_b1, fc_w2, fc_b2, out);
}

// Round 8
// 641.494 us; speedup vs baseline: 5.5239x; 1.0473x over previous
//
#include <hip/hip_runtime.h>
#include <hip/hip_bf16.h>

constexpr int TN = 100000;   // nodes
constexpr int TE = 200000;   // edges
constexpr int TG = 4000;     // graphs
constexpr int TH = 128;      // hidden

using short8 = __attribute__((ext_vector_type(8))) short;
using f32x4  = __attribute__((ext_vector_type(4))) float;
typedef __hip_bfloat16 bf16;

#define DEVINL __device__ __forceinline__
DEVINL float sigm(float x)  { return 1.f / (1.f + __expf(-x)); }
DEVINL float ftanh(float x) { return 1.f - 2.f / (__expf(2.f * x) + 1.f); }
DEVINL void unpack8(uint4 v, float* f) {
    const ushort* u = (const ushort*)&v;
#pragma unroll
    for (int j = 0; j < 8; ++j) f[j] = __bfloat162float(*(const bf16*)&u[j]);
}

// ================= weight conversion =================
__global__ void conv6(const float* __restrict__ s0, const float* __restrict__ s1,
                      const float* __restrict__ s2, const float* __restrict__ s3,
                      const float* __restrict__ s4, const float* __restrict__ s5,
                      bf16* __restrict__ dst) {
    int i = blockIdx.x * 256 + threadIdx.x;
    if (i >= 6 * TH * TH) return;
    int m = i >> 14, r = i & 16383;
    int n = r >> 7, k = r & 127;
    const float* s = (m == 0) ? s0 : (m == 1) ? s1 : (m == 2) ? s2
                   : (m == 3) ? s3 : (m == 4) ? s4 : s5;
    dst[i] = __float2bfloat16(s[k * TH + n]);
}
__global__ void conv2(const float* __restrict__ a, const float* __restrict__ b,
                      bf16* __restrict__ dst) {
    int i = blockIdx.x * 256 + threadIdx.x;
    if (i >= 2 * 384 * TH) return;
    const float* s = (i < 384 * TH) ? a : b;
    int r = (i < 384 * TH) ? i : i - 384 * TH;
    dst[i] = __float2bfloat16(s[r]);
}
__global__ void convL(const float* __restrict__ wih, const float* __restrict__ whh,
                      bf16* __restrict__ dst) {
    int i = blockIdx.x * 256 + threadIdx.x;
    if (i >= 512 * 256) return;
    int c = i >> 8, k = i & 255;
    float v = (k < 128) ? wih[c * 256 + k] + whh[c * 128 + k] : wih[c * 256 + k];
    dst[i] = __float2bfloat16(v);
}

// ================= projection: 64 rows/block, 4 rows x 8 ch per thread ============
template<int K, bool PERM>
__global__ __launch_bounds__(256) void proj64(const float* __restrict__ X,
                                              const float* __restrict__ W,
                                              const float* __restrict__ b,
                                              ushort* __restrict__ out,
                                              const int* __restrict__ perm, int M) {
    __shared__ float xs[64][K];
    int tid = threadIdx.x;
    int bm = blockIdx.x * 64;
    for (int i = tid; i < 64 * K; i += 256) {
        int r = i / K, k = i % K;
        xs[r][k] = (bm + r < M) ? X[(size_t)(bm + r) * K + k] : 0.f;
    }
    __syncthreads();
    int rb = tid >> 4, h0 = (tid & 15) * 8;
    float acc[4][8];
#pragma unroll
    for (int j = 0; j < 4; ++j)
#pragma unroll
        for (int c = 0; c < 8; ++c) acc[j][c] = b[h0 + c];
#pragma unroll
    for (int k = 0; k < K; ++k) {
        float4 w0 = *(const float4*)(W + k * TH + h0);
        float4 w1 = *(const float4*)(W + k * TH + h0 + 4);
#pragma unroll
        for (int j = 0; j < 4; ++j) {
            float xv = xs[rb + 16 * j][k];
            acc[j][0] = fmaf(xv, w0.x, acc[j][0]); acc[j][1] = fmaf(xv, w0.y, acc[j][1]);
            acc[j][2] = fmaf(xv, w0.z, acc[j][2]); acc[j][3] = fmaf(xv, w0.w, acc[j][3]);
            acc[j][4] = fmaf(xv, w1.x, acc[j][4]); acc[j][5] = fmaf(xv, w1.y, acc[j][5]);
            acc[j][6] = fmaf(xv, w1.z, acc[j][6]); acc[j][7] = fmaf(xv, w1.w, acc[j][7]);
        }
    }
#pragma unroll
    for (int j = 0; j < 4; ++j) {
        int row = bm + rb + 16 * j;
        if (row >= M) continue;
        ushort o[8];
#pragma unroll
        for (int c = 0; c < 8; ++c) {
            bf16 v = __float2bfloat16(acc[j][c]);
            o[c] = *(ushort*)&v;
        }
        int orow = PERM ? perm[row] : row;
        *(uint4*)(out + (size_t)orow * TH + h0) = *(uint4*)o;
    }
}

// ================= CSR build =================
__global__ void count_deg(const int* __restrict__ ei_dst, int* __restrict__ deg, int En) {
    int e = blockIdx.x * 256 + threadIdx.x;
    if (e < En) atomicAdd(&deg[ei_dst[e]], 1);
}
__global__ void scan_block(const int* __restrict__ deg, int* __restrict__ rowptr,
                           int* __restrict__ bsum, int Nn) {
    __shared__ int sm[256];
    int tid = threadIdx.x;
    int gid = blockIdx.x * 256 + tid;
    int v = (gid < Nn) ? deg[gid] : 0;
    int x = v;
    sm[tid] = x; __syncthreads();
    for (int off = 1; off < 256; off <<= 1) {
        int t = (tid >= off) ? sm[tid - off] : 0;
        __syncthreads();
        x += t; sm[tid] = x;
        __syncthreads();
    }
    if (gid < Nn) rowptr[gid] = x - v;
    if (tid == 255) bsum[blockIdx.x] = x;
}
__global__ void scan_bsum(const int* __restrict__ bsum, int* __restrict__ bsumx, int nb) {
    __shared__ int sm[512];
    int tid = threadIdx.x;
    int v = (tid < nb) ? bsum[tid] : 0;
    int x = v;
    sm[tid] = x; __syncthreads();
    for (int off = 1; off < 512; off <<= 1) {
        int t = (tid >= off) ? sm[tid - off] : 0;
        __syncthreads();
        x += t; sm[tid] = x;
        __syncthreads();
    }
    if (tid < nb) bsumx[tid] = x - v;
}
__global__ void add_off(int* __restrict__ rowptr, const int* __restrict__ bsumx,
                        int Nn, int Etot) {
    int gid = blockIdx.x * 256 + threadIdx.x;
    if (gid < Nn) rowptr[gid] += bsumx[gid >> 8];
    if (gid == 0) rowptr[Nn] = Etot;
}
__global__ void fill_csr(const int* __restrict__ ei_src, const int* __restrict__ ei_dst,
                         const int* __restrict__ rowptr, int* __restrict__ cur,
                         int* __restrict__ srcp, int* __restrict__ epos, int En) {
    int e = blockIdx.x * 256 + threadIdx.x;
    if (e >= En) return;
    int d = ei_dst[e];
    int p = atomicAdd(&cur[d], 1);
    int slot = rowptr[d] + p;
    srcp[slot] = ei_src[e];
    epos[e] = slot;
}
__global__ void build_gptr(const int* __restrict__ batch, int* __restrict__ gptr,
                           int Nn, int Gn) {
    int n = blockIdx.x * 256 + threadIdx.x;
    if (n >= Nn) return;
    int bc = batch[n];
    int bp = (n == 0) ? -1 : batch[n - 1];
    for (int g = bp + 1; g <= bc; ++g) gptr[g] = n;
    if (n == Nn - 1) for (int g = bc + 1; g <= Gn; ++g) gptr[g] = Nn;
}

// ========== aggregation, 8 channels/thread (16 threads per node) ==========
__global__ __launch_bounds__(256) void aggregate_v8(
    const ushort* __restrict__ node, const ushort* __restrict__ ef,
    const int* __restrict__ srcp, const int* __restrict__ rowptr,
    const float* __restrict__ eps, int l, ushort* __restrict__ zb, int Nn) {
    int t = blockIdx.x * 256 + threadIdx.x;
    int n = t >> 4;
    if (n >= Nn) return;
    int c8 = (t & 15) * 8;
    float se = 1.f + eps[l];
    float acc[8];
    uint4 nv = *(const uint4*)(node + (size_t)n * TH + c8);
    unpack8(nv, acc);
#pragma unroll
    for (int j = 0; j < 8; ++j) acc[j] *= se;
    int s0 = rowptr[n], s1 = rowptr[n + 1];
    for (int i = s0; i < s1; ++i) {
        int src = srcp[i];
        uint4 av = *(const uint4*)(node + (size_t)src * TH + c8);
        uint4 bv = *(const uint4*)(ef + (size_t)i * TH + c8);
        float af[8], bf[8];
        unpack8(av, af); unpack8(bv, bf);
#pragma unroll
        for (int j = 0; j < 8; ++j) acc[j] += fmaxf(af[j] + bf[j], 0.f);
    }
    ushort o[8];
#pragma unroll
    for (int j = 0; j < 8; ++j) {
        bf16 v = __float2bfloat16(acc[j]);
        o[j] = *(ushort*)&v;
    }
    *(uint4*)(zb + (size_t)n * TH + c8) = *(uint4*)o;
}

// ================= fused 2-layer MLP (weights preloaded to registers) =================
__global__ __launch_bounds__(256) void mlp2_fused(
    const ushort* __restrict__ A, const ushort* __restrict__ W1t,
    const float* __restrict__ b1, const ushort* __restrict__ W2t,
    const float* __restrict__ b2, ushort* __restrict__ C, int M)
{
    __shared__ ushort As[128 * 128];
    __shared__ ushort Ts[128 * 128];
    const int tid = threadIdx.x;
    const int bm = blockIdx.x * 128;
    const int lane = tid & 63, w = tid >> 6;
    const int lr = lane & 15, lq = lane >> 4;
    const int wm = (w & 1) * 64, wn = (w >> 1) * 64;
    short8 wf[4][4];
#pragma unroll
    for (int ni = 0; ni < 4; ++ni)
#pragma unroll
        for (int ks = 0; ks < 4; ++ks)
            wf[ni][ks] = *(const short8*)(W1t + (size_t)(wn + ni * 16 + lr) * 128 + ks * 32 + lq * 8);
#pragma unroll
    for (int p = 0; p < 8; ++p) {
        int ch = p * 256 + tid;
        int r = ch >> 4, c = ch & 15;
        int row = bm + r;
        uint4 v = make_uint4(0u, 0u, 0u, 0u);
        if (row < M) v = *(const uint4*)(A + (size_t)row * 128 + c * 8);
        *(uint4*)(&As[r * 128 + ((c ^ (r & 15)) * 8)]) = v;
    }
    __syncthreads();
    {
        f32x4 acc[4][4] = {};
#pragma unroll
        for (int ks = 0; ks < 4; ++ks) {
            int cb = ks * 4 + lq;
            short8 af[4];
#pragma unroll
            for (int mi = 0; mi < 4; ++mi)
                af[mi] = *(const short8*)(&As[(wm + mi * 16 + lr) * 128 + ((cb ^ lr) * 8)]);
#pragma unroll
            for (int mi = 0; mi < 4; ++mi)
#pragma unroll
                for (int ni = 0; ni < 4; ++ni)
                    acc[mi][ni] = __builtin_amdgcn_mfma_f32_16x16x32_bf16(af[mi], wf[ni][ks], acc[mi][ni], 0, 0, 0);
        }
#pragma unroll
        for (int mi = 0; mi < 4; ++mi)
#pragma unroll
            for (int reg = 0; reg < 4; ++reg) {
                int row = wm + mi * 16 + lq * 4 + reg;
#pragma unroll
                for (int ni = 0; ni < 4; ++ni) {
                    int col = wn + ni * 16 + lr;
                    float v = fmaxf(acc[mi][ni][reg] + b1[col], 0.f);
                    bf16 bv = __float2bfloat16(v);
                    Ts[row * 128 + (((col >> 3) ^ (row & 15)) * 8) + (col & 7)] = *(ushort*)&bv;
                }
            }
    }
#pragma unroll
    for (int ni = 0; ni < 4; ++ni)
#pragma unroll
        for (int ks = 0; ks < 4; ++ks)
            wf[ni][ks] = *(const short8*)(W2t + (size_t)(wn + ni * 16 + lr) * 128 + ks * 32 + lq * 8);
    __syncthreads();
    {
        f32x4 acc[4][4] = {};
#pragma unroll
        for (int ks = 0; ks < 4; ++ks) {
            int cb = ks * 4 + lq;
            short8 af[4];
#pragma unroll
            for (int mi = 0; mi < 4; ++mi)
                af[mi] = *(const short8*)(&Ts[(wm + mi * 16 + lr) * 128 + ((cb ^ lr) * 8)]);
#pragma unroll
            for (int mi = 0; mi < 4; ++mi)
#pragma unroll
                for (int ni = 0; ni < 4; ++ni)
                    acc[mi][ni] = __builtin_amdgcn_mfma_f32_16x16x32_bf16(af[mi], wf[ni][ks], acc[mi][ni], 0, 0, 0);
        }
#pragma unroll
        for (int mi = 0; mi < 4; ++mi)
#pragma unroll
            for (int reg = 0; reg < 4; ++reg) {
                int row = bm + wm + mi * 16 + lq * 4 + reg;
                if (row >= M) continue;
#pragma unroll
                for (int ni = 0; ni < 4; ++ni) {
                    int col = wn + ni * 16 + lr;
                    bf16 bv = __float2bfloat16(acc[mi][ni][reg] + b2[col]);
                    C[(size_t)row * 128 + col] = *(ushort*)&bv;
                }
            }
    }
}

// ===== fused GRU: 512 threads, 8 waves, 32 rows/block, 16 cols/wave =====
// Halves per-wave accumulators (32 f32) vs round-7 to lift unified-RF occupancy.
__global__ __launch_bounds__(512, 4) void gru_fused(
    const ushort* __restrict__ mfeat, const ushort* __restrict__ wih,
    const ushort* __restrict__ whh, const float* __restrict__ bih,
    const float* __restrict__ bhh, ushort* __restrict__ node, int Nn)
{
    __shared__ ushort Ms[32 * 128];
    __shared__ ushort Hs[32 * 128];
    const int tid = threadIdx.x;
    const int bm = blockIdx.x * 32;
#pragma unroll
    for (int p = 0; p < 2; ++p) {
        int ch = p * 512 + tid;          // 1024 = 2 bufs x 32 rows x 16 chunks
        bool isH = ch >= 512;
        int r = (ch >> 4) & 31, c = ch & 15;
        int row = bm + r;
        uint4 v = make_uint4(0u, 0u, 0u, 0u);
        if (row < Nn) v = *(const uint4*)((isH ? node : mfeat) + (size_t)row * 128 + c * 8);
        ushort* dst = isH ? Hs : Ms;
        *(uint4*)(&dst[r * 128 + ((c ^ (r & 15)) * 8)]) = v;
    }
    __syncthreads();
    const int lane = tid & 63, w = tid >> 6;      // w in [0,8): 16-col slice
    const int lr = lane & 15, lq = lane >> 4;
    const int cw = w * 16;                        // wave's column base
    f32x4 aR[2] = {}, aZ[2] = {}, aN[2] = {}, aH[2] = {};
#pragma unroll
    for (int ks = 0; ks < 4; ++ks) {
        int cb = ks * 4 + lq;
        short8 am[2], ah[2];
#pragma unroll
        for (int rt = 0; rt < 2; ++rt) {
            int off = (rt * 16 + lr) * 128 + ((cb ^ lr) * 8);
            am[rt] = *(const short8*)(&Ms[off]);
            ah[rt] = *(const short8*)(&Hs[off]);
        }
        int koff = ks * 32 + lq * 8;
        int col = cw + lr;
        short8 wv0 = *(const short8*)(wih + (size_t)col * 128 + koff);
        short8 wv1 = *(const short8*)(wih + (size_t)(128 + col) * 128 + koff);
        short8 wv2 = *(const short8*)(wih + (size_t)(256 + col) * 128 + koff);
        short8 wv3 = *(const short8*)(whh + (size_t)col * 128 + koff);
        short8 wv4 = *(const short8*)(whh + (size_t)(128 + col) * 128 + koff);
        short8 wv5 = *(const short8*)(whh + (size_t)(256 + col) * 128 + koff);
#pragma unroll
        for (int rt = 0; rt < 2; ++rt) {
            aR[rt] = __builtin_amdgcn_mfma_f32_16x16x32_bf16(am[rt], wv0, aR[rt], 0, 0, 0);
            aR[rt] = __builtin_amdgcn_mfma_f32_16x16x32_bf16(ah[rt], wv3, aR[rt], 0, 0, 0);
            aZ[rt] = __builtin_amdgcn_mfma_f32_16x16x32_bf16(am[rt], wv1, aZ[rt], 0, 0, 0);
            aZ[rt] = __builtin_amdgcn_mfma_f32_16x16x32_bf16(ah[rt], wv4, aZ[rt], 0, 0, 0);
            aN[rt] = __builtin_amdgcn_mfma_f32_16x16x32_bf16(am[rt], wv2, aN[rt], 0, 0, 0);
            aH[rt] = __builtin_amdgcn_mfma_f32_16x16x32_bf16(ah[rt], wv5, aH[rt], 0, 0, 0);
        }
    }
    {
        int h = cw + lr;
        float br = bih[h] + bhh[h];
        float bz = bih[128 + h] + bhh[128 + h];
        float bin = bih[256 + h], bhn = bhh[256 + h];
#pragma unroll
        for (int rt = 0; rt < 2; ++rt)
#pragma unroll
            for (int reg = 0; reg < 4; ++reg) {
                int lrow = rt * 16 + lq * 4 + reg;
                int row = bm + lrow;
                if (row >= Nn) continue;
                float r = sigm(aR[rt][reg] + br);
                float z = sigm(aZ[rt][reg] + bz);
                float n = ftanh(aN[rt][reg] + bin + r * (aH[rt][reg] + bhn));
                int hofs = lrow * 128 + (((h >> 3) ^ (lrow & 15)) * 8) + (h & 7);
                float hold = __bfloat162float(*(const bf16*)&Hs[hofs]);
                bf16 hv = __float2bfloat16((1.f - z) * n + z * hold);
                node[(size_t)row * 128 + h] = *(ushort*)&hv;
            }
    }
}

// ================= fused LSTM step =================
__global__ __launch_bounds__(256) void lstm_fused(
    ushort* __restrict__ s, const ushort* __restrict__ Wl,
    const float* __restrict__ bih, const float* __restrict__ bhh,
    float* __restrict__ cl, int Gn)
{
    __shared__ ushort Ss[32 * 256];
    const int tid = threadIdx.x;
    const int bm = blockIdx.x * 32;
#pragma unroll
    for (int p = 0; p < 4; ++p) {
        int ch = p * 256 + tid;
        int r = ch >> 5, c = ch & 31;
        int row = bm + r;
        uint4 v = make_uint4(0u, 0u, 0u, 0u);
        if (row < Gn) v = *(const uint4*)(s + (size_t)row * 256 + c * 8);
        *(uint4*)(&Ss[r * 256 + ((c ^ (r & 15)) * 8)]) = v;
    }
    __syncthreads();
    const int lane = tid & 63, w = tid >> 6;
    const int lr = lane & 15, lq = lane >> 4;
    f32x4 acc[2][4][2] = {};
#pragma unroll
    for (int ks = 0; ks < 8; ++ks) {
        int cb = ks * 4 + lq;
        short8 am[2];
#pragma unroll
        for (int rt = 0; rt < 2; ++rt)
            am[rt] = *(const short8*)(&Ss[(rt * 16 + lr) * 256 + ((cb ^ lr) * 8)]);
        int koff = ks * 32 + lq * 8;
#pragma unroll
        for (int g = 0; g < 4; ++g)
#pragma unroll
            for (int sub = 0; sub < 2; ++sub) {
                int col = g * 128 + w * 32 + sub * 16 + lr;
                short8 bf = *(const short8*)(Wl + (size_t)col * 256 + koff);
#pragma unroll
                for (int rt = 0; rt < 2; ++rt)
                    acc[rt][g][sub] = __builtin_amdgcn_mfma_f32_16x16x32_bf16(am[rt], bf, acc[rt][g][sub], 0, 0, 0);
            }
    }
#pragma unroll
    for (int sub = 0; sub < 2; ++sub) {
        int h = w * 32 + sub * 16 + lr;
        float bi = bih[h] + bhh[h];
        float bff = bih[128 + h] + bhh[128 + h];
        float bg = bih[256 + h] + bhh[256 + h];
        float bo = bih[384 + h] + bhh[384 + h];
#pragma unroll
        for (int rt = 0; rt < 2; ++rt)
#pragma unroll
            for (int reg = 0; reg < 4; ++reg) {
                int row = bm + rt * 16 + lq * 4 + reg;
                if (row >= Gn) continue;
                float iv = sigm(acc[rt][0][sub][reg] + bi);
                float fv = sigm(acc[rt][1][sub][reg] + bff);
                float gv = ftanh(acc[rt][2][sub][reg] + bg);
                float ov = sigm(acc[rt][3][sub][reg] + bo);
                float c = fv * cl[(size_t)row * 128 + h] + iv * gv;
                cl[(size_t)row * 128 + h] = c;
                bf16 hv = __float2bfloat16(ov * ftanh(c));
                s[(size_t)row * 256 + h] = *(ushort*)&hv;
            }
    }
}

// ================= fused per-graph attention (vectorized r-accum) ==============
__global__ __launch_bounds__(256) void att_fused(
    const bf16* __restrict__ node, ushort* __restrict__ s,
    const int* __restrict__ gptr)
{
    __shared__ float q[128];
    __shared__ float es[512];
    __shared__ float red[8];
    __shared__ float part[16][128];
    int g = blockIdx.x;
    int tid = threadIdx.x, lane = tid & 63, wid = tid >> 6;
    int n0 = gptr[g], n1 = gptr[g + 1];
    int cnt = n1 - n0; if (cnt > 512) cnt = 512;
    if (tid < 128) q[tid] = __bfloat162float(((const bf16*)s)[(size_t)g * 256 + tid]);
    __syncthreads();
    for (int i = wid; i < cnt; i += 4) {
        const bf16* nr = node + (size_t)(n0 + i) * TH;
        float p = __bfloat162float(nr[lane]) * q[lane]
                + __bfloat162float(nr[lane + 64]) * q[lane + 64];
        for (int off = 32; off; off >>= 1) p += __shfl_down(p, off);
        if (lane == 0) es[i] = p;
    }
    __syncthreads();
    float m = -1e30f;
    for (int i = tid; i < cnt; i += 256) m = fmaxf(m, es[i]);
    for (int off = 32; off; off >>= 1) m = fmaxf(m, __shfl_down(m, off));
    if (lane == 0) red[wid] = m;
    __syncthreads();
    m = fmaxf(fmaxf(red[0], red[1]), fmaxf(red[2], red[3]));
    float sm = 0.f;
    for (int i = tid; i < cnt; i += 256) { float ex = __expf(es[i] - m); es[i] = ex; sm += ex; }
    for (int off = 32; off; off >>= 1) sm += __shfl_down(sm, off);
    if (lane == 0) red[4 + wid] = sm;
    __syncthreads();
    sm = red[4] + red[5] + red[6] + red[7];
    float inv = 1.f / fmaxf(sm, 1e-9f);
    // vectorized weighted sum: thread (gr = tid>>4, c8 = (tid&15)*8)
    int gr = tid >> 4, c8 = (tid & 15) * 8;
    float racc[8] = {};
    for (int i = gr; i < cnt; i += 16) {
        uint4 v = *(const uint4*)((const ushort*)node + (size_t)(n0 + i) * TH + c8);
        float f[8]; unpack8(v, f);
        float a = es[i];
#pragma unroll
        for (int j = 0; j < 8; ++j) racc[j] = fmaf(a, f[j], racc[j]);
    }
#pragma unroll
    for (int j = 0; j < 8; ++j) part[gr][c8 + j] = racc[j];
    __syncthreads();
    if (tid < 128) {
        float r = 0.f;
#pragma unroll
        for (int k = 0; k < 16; ++k) r += part[k][tid];
        bf16 rv = __float2bfloat16(r * inv);
        s[(size_t)g * 256 + 128 + tid] = *(ushort*)&rv;
    }
}

// ================= final FC =================
__global__ __launch_bounds__(128) void final_fc(const ushort* __restrict__ s,
                                                const float* __restrict__ w1,
                                                const float* __restrict__ b1,
                                                const float* __restrict__ w2,
                                                const float* __restrict__ b2,
                                                float* __restrict__ out) {
    __shared__ float q[256];
    __shared__ float red[2];
    int g = blockIdx.x, t = threadIdx.x;
    q[t] = __bfloat162float(((const bf16*)s)[(size_t)g * 256 + t]);
    q[t + 128] = __bfloat162float(((const bf16*)s)[(size_t)g * 256 + 128 + t]);
    __syncthreads();
    float acc = b1[t];
    for (int k = 0; k < 256; ++k) acc = fmaf(q[k], w1[k * TH + t], acc);
    acc = fmaxf(acc, 0.f);
    float p = acc * w2[t];
    for (int off = 32; off; off >>= 1) p += __shfl_down(p, off);
    if ((t & 63) == 0) red[t >> 6] = p;
    __syncthreads();
    if (t == 0) out[g] = red[0] + red[1] + b2[0];
}

// ---------------------------------------------------------------------------
static void launch_mlp2(const void* A, const bf16* W1t, const float* b1,
                        const bf16* W2t, const float* b2, void* C, int M, hipStream_t s) {
    hipLaunchKernelGGL(mlp2_fused, dim3((M + 127) / 128), dim3(256), 0, s,
                       (const ushort*)A, (const ushort*)W1t, b1, (const ushort*)W2t, b2,
                       (ushort*)C, M);
}

extern "C" void kernel_launch(void* const* d_in, const int* in_sizes, int n_in,
                              void* d_out, int out_size, void* d_ws, size_t ws_size,
                              hipStream_t stream) {
    const float* x         = (const float*)d_in[0];
    const float* edge_attr = (const float*)d_in[1];
    const int*   edge_index= (const int*)d_in[2];
    const int*   batch     = (const int*)d_in[3];
    const float* node_w    = (const float*)d_in[4];
    const float* node_b    = (const float*)d_in[5];
    const float* edge_w    = (const float*)d_in[6];
    const float* edge_b    = (const float*)d_in[7];
    const float* eps       = (const float*)d_in[8];
    const float* gin_w1    = (const float*)d_in[9];
    const float* gin_b1    = (const float*)d_in[10];
    const float* gin_w2    = (const float*)d_in[11];
    const float* gin_b2    = (const float*)d_in[12];
    const float* em_w1     = (const float*)d_in[13];
    const float* em_b1     = (const float*)d_in[14];
    const float* em_w2     = (const float*)d_in[15];
    const float* em_b2     = (const float*)d_in[16];
    const float* gru_wih   = (const float*)d_in[17];
    const float* gru_whh   = (const float*)d_in[18];
    const float* gru_bih   = (const float*)d_in[19];
    const float* gru_bhh   = (const float*)d_in[20];
    const float* lstm_wih  = (const float*)d_in[21];
    const float* lstm_whh  = (const float*)d_in[22];
    const float* lstm_bih  = (const float*)d_in[23];
    const float* lstm_bhh  = (const float*)d_in[24];
    const float* fc_w1     = (const float*)d_in[25];
    const float* fc_b1     = (const float*)d_in[26];
    const float* fc_w2     = (const float*)d_in[27];
    const float* fc_b2     = (const float*)d_in[28];
    float* out = (float*)d_out;
    const int* ei_src = edge_index;
    const int* ei_dst = edge_index + TE;

    // ---- workspace layout ----
    char* base = (char*)d_ws;
    size_t off = 0;
    auto alloc = [&](size_t bytes) { void* p = base + off; off += (bytes + 15) & ~size_t(15); return p; };
    bf16*  nodeb = (bf16*)alloc((size_t)TN * TH * 2);   // 25.6 MB
    bf16*  zb    = (bf16*)alloc((size_t)TN * TH * 2);   // 25.6 MB
    bf16*  e1b   = (bf16*)alloc((size_t)TE * TH * 2);   // 51.2 MB (set2set overlay later)
    int*   deg   = (int*)alloc((size_t)TN * 4);
    int*   rowptr= (int*)alloc((size_t)(TN + 1) * 4);
    int*   cur   = (int*)alloc((size_t)TN * 4);
    int*   srcp  = (int*)alloc((size_t)TE * 4);
    int*   epos  = (int*)alloc((size_t)TE * 4);
    int*   bsum  = (int*)alloc(512 * 4);
    int*   bsumx = (int*)alloc(512 * 4);
    int*   gptr  = (int*)alloc((size_t)(TG + 1) * 4);
    bf16*  w6    = (bf16*)alloc(6 * TH * TH * 2);
    bf16*  wgru  = (bf16*)alloc(2 * 384 * TH * 2);
    bf16*  wl    = (bf16*)alloc(512 * 256 * 2);
    if (ws_size < off) return;

    bf16* w_gin1_0 = w6;
    bf16* w_gin1_1 = w6 + 1 * TH * TH;
    bf16* w_gin2_0 = w6 + 2 * TH * TH;
    bf16* w_gin2_1 = w6 + 3 * TH * TH;
    bf16* w_em1    = w6 + 4 * TH * TH;
    bf16* w_em2    = w6 + 5 * TH * TH;
    bf16* w_wih    = wgru;
    bf16* w_whh    = wgru + 384 * TH;

    ushort* sbuf = (ushort*)e1b;                      // [G][256] bf16
    float*  cl   = (float*)(sbuf + (size_t)TG * 256); // [G][128] fp32

    // ---- CSR + gptr ----
    hipMemsetAsync(deg, 0, (size_t)TN * 4, stream);
    hipMemsetAsync(cur, 0, (size_t)TN * 4, stream);
    count_deg<<<(TE + 255) / 256, 256, 0, stream>>>(ei_dst, deg, TE);
    int nb = (TN + 255) / 256;
    scan_block<<<nb, 256, 0, stream>>>(deg, rowptr, bsum, TN);
    scan_bsum<<<1, 512, 0, stream>>>(bsum, bsumx, nb);
    add_off<<<nb, 256, 0, stream>>>(rowptr, bsumx, TN, TE);
    fill_csr<<<(TE + 255) / 256, 256, 0, stream>>>(ei_src, ei_dst, rowptr, cur, srcp, epos, TE);
    build_gptr<<<(TN + 255) / 256, 256, 0, stream>>>(batch, gptr, TN, TG);

    // ---- weights ----
    conv6<<<(6 * TH * TH + 255) / 256, 256, 0, stream>>>(
        gin_w1, gin_w1 + TH * TH, gin_w2, gin_w2 + TH * TH, em_w1, em_w2, w6);
    conv2<<<(2 * 384 * TH + 255) / 256, 256, 0, stream>>>(gru_wih, gru_whh, wgru);
    convL<<<(512 * 256 + 255) / 256, 256, 0, stream>>>(lstm_wih, lstm_whh, wl);

    // ---- projections (edges scattered into CSR slot order) ----
    proj64<14, false><<<(TN + 63) / 64, 256, 0, stream>>>(x, node_w, node_b, (ushort*)nodeb, nullptr, TN);
    proj64<4,  true ><<<(TE + 63) / 64, 256, 0, stream>>>(edge_attr, edge_w, edge_b, (ushort*)e1b, epos, TE);

    // ---- layer 0 ----
    aggregate_v8<<<(TN * 16 + 255) / 256, 256, 0, stream>>>(
        (const ushort*)nodeb, (const ushort*)e1b, srcp, rowptr, eps, 0, (ushort*)zb, TN);
    launch_mlp2(zb, w_gin1_0, gin_b1, w_gin2_0, gin_b2, zb, TN, stream);
    gru_fused<<<(TN + 31) / 32, 512, 0, stream>>>(
        (const ushort*)zb, (const ushort*)w_wih, (const ushort*)w_whh,
        gru_bih, gru_bhh, (ushort*)nodeb, TN);

    // ---- edge MLP (in-place, slot order preserved), layer 1 ----
    launch_mlp2(e1b, w_em1, em_b1, w_em2, em_b2, e1b, TE, stream);
    aggregate_v8<<<(TN * 16 + 255) / 256, 256, 0, stream>>>(
        (const ushort*)nodeb, (const ushort*)e1b, srcp, rowptr, eps, 1, (ushort*)zb, TN);
    launch_mlp2(zb, w_gin1_1, gin_b1 + TH, w_gin2_1, gin_b2 + TH, zb, TN, stream);
    gru_fused<<<(TN + 31) / 32, 512, 0, stream>>>(
        (const ushort*)zb, (const ushort*)w_wih, (const ushort*)w_whh,
        gru_bih, gru_bhh, (ushort*)nodeb, TN);

    // ---- Set2Set (3 steps) ----
    hipMemsetAsync(sbuf, 0, (size_t)TG * 256 * 2 + (size_t)TG * 128 * 4, stream);
    for (int st = 0; st < 3; ++st) {
        lstm_fused<<<(TG + 31) / 32, 256, 0, stream>>>(
            sbuf, (const ushort*)wl, lstm_bih, lstm_bhh, cl, TG);
        att_fused<<<TG, 256, 0, stream>>>(nodeb, sbuf, gptr);
    }

    // ---- final FC ----
    final_fc<<<TG, 128, 0, stream>>>(sbuf, fc_w1, fc_b1, fc_w2, fc_b2, out);
}

// Round 10
// 621.253 us; speedup vs baseline: 5.7038x; 1.0326x over previous
//
#include <hip/hip_runtime.h>
#include <hip/hip_bf16.h>

constexpr int TN = 100000;   // nodes
constexpr int TE = 200000;   // edges
constexpr int TG = 4000;     // graphs
constexpr int TH = 128;      // hidden

using short8 = __attribute__((ext_vector_type(8))) short;
using f32x4  = __attribute__((ext_vector_type(4))) float;
typedef __hip_bfloat16 bf16;

#define DEVINL __device__ __forceinline__
DEVINL float sigm(float x)  { return 1.f / (1.f + __expf(-x)); }
DEVINL float ftanh(float x) { return 1.f - 2.f / (__expf(2.f * x) + 1.f); }
DEVINL void unpack8(uint4 v, float* f) {
    const ushort* u = (const ushort*)&v;
#pragma unroll
    for (int j = 0; j < 8; ++j) f[j] = __bfloat162float(*(const bf16*)&u[j]);
}

// ================= weight conversion =================
__global__ void conv6(const float* __restrict__ s0, const float* __restrict__ s1,
                      const float* __restrict__ s2, const float* __restrict__ s3,
                      const float* __restrict__ s4, const float* __restrict__ s5,
                      bf16* __restrict__ dst) {
    int i = blockIdx.x * 256 + threadIdx.x;
    if (i >= 6 * TH * TH) return;
    int m = i >> 14, r = i & 16383;
    int n = r >> 7, k = r & 127;
    const float* s = (m == 0) ? s0 : (m == 1) ? s1 : (m == 2) ? s2
                   : (m == 3) ? s3 : (m == 4) ? s4 : s5;
    dst[i] = __float2bfloat16(s[k * TH + n]);
}
__global__ void conv2(const float* __restrict__ a, const float* __restrict__ b,
                      bf16* __restrict__ dst) {
    int i = blockIdx.x * 256 + threadIdx.x;
    if (i >= 2 * 384 * TH) return;
    const float* s = (i < 384 * TH) ? a : b;
    int r = (i < 384 * TH) ? i : i - 384 * TH;
    dst[i] = __float2bfloat16(s[r]);
}
__global__ void convL(const float* __restrict__ wih, const float* __restrict__ whh,
                      bf16* __restrict__ dst) {
    int i = blockIdx.x * 256 + threadIdx.x;
    if (i >= 512 * 256) return;
    int c = i >> 8, k = i & 255;
    float v = (k < 128) ? wih[c * 256 + k] + whh[c * 128 + k] : wih[c * 256 + k];
    dst[i] = __float2bfloat16(v);
}

// ================= node projection: 64 rows/block ============
template<int K>
__global__ __launch_bounds__(256) void proj64(const float* __restrict__ X,
                                              const float* __restrict__ W,
                                              const float* __restrict__ b,
                                              ushort* __restrict__ out, int M) {
    __shared__ float xs[64][K];
    int tid = threadIdx.x;
    int bm = blockIdx.x * 64;
    for (int i = tid; i < 64 * K; i += 256) {
        int r = i / K, k = i % K;
        xs[r][k] = (bm + r < M) ? X[(size_t)(bm + r) * K + k] : 0.f;
    }
    __syncthreads();
    int rb = tid >> 4, h0 = (tid & 15) * 8;
    float acc[4][8];
#pragma unroll
    for (int j = 0; j < 4; ++j)
#pragma unroll
        for (int c = 0; c < 8; ++c) acc[j][c] = b[h0 + c];
#pragma unroll
    for (int k = 0; k < K; ++k) {
        float4 w0 = *(const float4*)(W + k * TH + h0);
        float4 w1 = *(const float4*)(W + k * TH + h0 + 4);
#pragma unroll
        for (int j = 0; j < 4; ++j) {
            float xv = xs[rb + 16 * j][k];
            acc[j][0] = fmaf(xv, w0.x, acc[j][0]); acc[j][1] = fmaf(xv, w0.y, acc[j][1]);
            acc[j][2] = fmaf(xv, w0.z, acc[j][2]); acc[j][3] = fmaf(xv, w0.w, acc[j][3]);
            acc[j][4] = fmaf(xv, w1.x, acc[j][4]); acc[j][5] = fmaf(xv, w1.y, acc[j][5]);
            acc[j][6] = fmaf(xv, w1.z, acc[j][6]); acc[j][7] = fmaf(xv, w1.w, acc[j][7]);
        }
    }
#pragma unroll
    for (int j = 0; j < 4; ++j) {
        int row = bm + rb + 16 * j;
        if (row >= M) continue;
        ushort o[8];
#pragma unroll
        for (int c = 0; c < 8; ++c) {
            bf16 v = __float2bfloat16(acc[j][c]);
            o[c] = *(ushort*)&v;
        }
        *(uint4*)(out + (size_t)row * TH + h0) = *(uint4*)o;
    }
}

// ===== proj_scatter: K=4 projection with CSR-slot scatter (layer-0 e0) =====
__global__ __launch_bounds__(256) void proj_scatter(
    const float* __restrict__ X, const float* __restrict__ W,
    const float* __restrict__ b, const int* __restrict__ perm,
    ushort* __restrict__ out, int M) {
    __shared__ float xs[64][4];
    int tid = threadIdx.x;
    int bm = blockIdx.x * 64;
    if (tid < 64) {
        float4 a = make_float4(0.f, 0.f, 0.f, 0.f);
        if (bm + tid < M) a = *(const float4*)(X + (size_t)(bm + tid) * 4);
        xs[tid][0] = a.x; xs[tid][1] = a.y; xs[tid][2] = a.z; xs[tid][3] = a.w;
    }
    __syncthreads();
    int rb = tid >> 4, h0 = (tid & 15) * 8;
    float acc[4][8];
#pragma unroll
    for (int j = 0; j < 4; ++j)
#pragma unroll
        for (int c = 0; c < 8; ++c) acc[j][c] = b[h0 + c];
#pragma unroll
    for (int k = 0; k < 4; ++k) {
        float4 w0 = *(const float4*)(W + k * TH + h0);
        float4 w1 = *(const float4*)(W + k * TH + h0 + 4);
#pragma unroll
        for (int j = 0; j < 4; ++j) {
            float xv = xs[rb + 16 * j][k];
            acc[j][0] = fmaf(xv, w0.x, acc[j][0]); acc[j][1] = fmaf(xv, w0.y, acc[j][1]);
            acc[j][2] = fmaf(xv, w0.z, acc[j][2]); acc[j][3] = fmaf(xv, w0.w, acc[j][3]);
            acc[j][4] = fmaf(xv, w1.x, acc[j][4]); acc[j][5] = fmaf(xv, w1.y, acc[j][5]);
            acc[j][6] = fmaf(xv, w1.z, acc[j][6]); acc[j][7] = fmaf(xv, w1.w, acc[j][7]);
        }
    }
#pragma unroll
    for (int j = 0; j < 4; ++j) {
        int row = bm + rb + 16 * j;
        if (row >= M) continue;
        ushort o[8];
#pragma unroll
        for (int c = 0; c < 8; ++c) {
            bf16 v = __float2bfloat16(acc[j][c]);
            o[c] = *(ushort*)&v;
        }
        *(uint4*)(out + (size_t)perm[row] * TH + h0) = *(uint4*)o;
    }
}

// ================= CSR build =================
__global__ void count_deg(const int* __restrict__ ei_dst, int* __restrict__ deg, int En) {
    int e = blockIdx.x * 256 + threadIdx.x;
    if (e < En) atomicAdd(&deg[ei_dst[e]], 1);
}
__global__ void scan_block(const int* __restrict__ deg, int* __restrict__ rowptr,
                           int* __restrict__ bsum, int Nn) {
    __shared__ int sm[256];
    int tid = threadIdx.x;
    int gid = blockIdx.x * 256 + tid;
    int v = (gid < Nn) ? deg[gid] : 0;
    int x = v;
    sm[tid] = x; __syncthreads();
    for (int off = 1; off < 256; off <<= 1) {
        int t = (tid >= off) ? sm[tid - off] : 0;
        __syncthreads();
        x += t; sm[tid] = x;
        __syncthreads();
    }
    if (gid < Nn) rowptr[gid] = x - v;
    if (tid == 255) bsum[blockIdx.x] = x;
}
__global__ void scan_bsum(const int* __restrict__ bsum, int* __restrict__ bsumx, int nb) {
    __shared__ int sm[512];
    int tid = threadIdx.x;
    int v = (tid < nb) ? bsum[tid] : 0;
    int x = v;
    sm[tid] = x; __syncthreads();
    for (int off = 1; off < 512; off <<= 1) {
        int t = (tid >= off) ? sm[tid - off] : 0;
        __syncthreads();
        x += t; sm[tid] = x;
        __syncthreads();
    }
    if (tid < nb) bsumx[tid] = x - v;
}
__global__ void add_off(int* __restrict__ rowptr, const int* __restrict__ bsumx,
                        int Nn, int Etot) {
    int gid = blockIdx.x * 256 + threadIdx.x;
    if (gid < Nn) rowptr[gid] += bsumx[gid >> 8];
    if (gid == 0) rowptr[Nn] = Etot;
}
__global__ void fill_csr(const int* __restrict__ ei_src, const int* __restrict__ ei_dst,
                         const int* __restrict__ rowptr, int* __restrict__ cur,
                         int* __restrict__ srcp, int* __restrict__ epos, int En) {
    int e = blockIdx.x * 256 + threadIdx.x;
    if (e >= En) return;
    int d = ei_dst[e];
    int p = atomicAdd(&cur[d], 1);
    int slot = rowptr[d] + p;
    srcp[slot] = ei_src[e];
    epos[e] = slot;
}
__global__ void build_gptr(const int* __restrict__ batch, int* __restrict__ gptr,
                           int Nn, int Gn) {
    int n = blockIdx.x * 256 + threadIdx.x;
    if (n >= Nn) return;
    int bc = batch[n];
    int bp = (n == 0) ? -1 : batch[n - 1];
    for (int g = bp + 1; g <= bc; ++g) gptr[g] = n;
    if (n == Nn - 1) for (int g = bc + 1; g <= Gn; ++g) gptr[g] = Nn;
}

// ========== aggregation, 8 ch/thread, 2-way unrolled gather ==========
__global__ __launch_bounds__(256) void aggregate_v8(
    const ushort* __restrict__ node, const ushort* __restrict__ ef,
    const int* __restrict__ srcp, const int* __restrict__ rowptr,
    const float* __restrict__ eps, int l, ushort* __restrict__ zb, int Nn) {
    int t = blockIdx.x * 256 + threadIdx.x;
    int n = t >> 4;
    if (n >= Nn) return;
    int c8 = (t & 15) * 8;
    float se = 1.f + eps[l];
    float acc[8];
    uint4 nv = *(const uint4*)(node + (size_t)n * TH + c8);
    unpack8(nv, acc);
#pragma unroll
    for (int j = 0; j < 8; ++j) acc[j] *= se;
    int s0 = rowptr[n], s1 = rowptr[n + 1];
    int i = s0;
    for (; i + 1 < s1; i += 2) {
        int sa = srcp[i], sb = srcp[i + 1];
        uint4 av0 = *(const uint4*)(node + (size_t)sa * TH + c8);
        uint4 bv0 = *(const uint4*)(ef + (size_t)i * TH + c8);
        uint4 av1 = *(const uint4*)(node + (size_t)sb * TH + c8);
        uint4 bv1 = *(const uint4*)(ef + (size_t)(i + 1) * TH + c8);
        float a0[8], b0[8], a1[8], b1[8];
        unpack8(av0, a0); unpack8(bv0, b0);
        unpack8(av1, a1); unpack8(bv1, b1);
#pragma unroll
        for (int j = 0; j < 8; ++j)
            acc[j] += fmaxf(a0[j] + b0[j], 0.f) + fmaxf(a1[j] + b1[j], 0.f);
    }
    if (i < s1) {
        int sa = srcp[i];
        uint4 av = *(const uint4*)(node + (size_t)sa * TH + c8);
        uint4 bv = *(const uint4*)(ef + (size_t)i * TH + c8);
        float af[8], bf[8];
        unpack8(av, af); unpack8(bv, bf);
#pragma unroll
        for (int j = 0; j < 8; ++j) acc[j] += fmaxf(af[j] + bf[j], 0.f);
    }
    ushort o[8];
#pragma unroll
    for (int j = 0; j < 8; ++j) {
        bf16 v = __float2bfloat16(acc[j]);
        o[j] = *(ushort*)&v;
    }
    *(uint4*)(zb + (size_t)n * TH + c8) = *(uint4*)o;
}

// ================= fused 2-layer MLP (weights preloaded to registers) =================
__global__ __launch_bounds__(256) void mlp2_fused(
    const ushort* __restrict__ A, const ushort* __restrict__ W1t,
    const float* __restrict__ b1, const ushort* __restrict__ W2t,
    const float* __restrict__ b2, ushort* __restrict__ C, int M)
{
    __shared__ ushort As[128 * 128];
    __shared__ ushort Ts[128 * 128];
    const int tid = threadIdx.x;
    const int bm = blockIdx.x * 128;
    const int lane = tid & 63, w = tid >> 6;
    const int lr = lane & 15, lq = lane >> 4;
    const int wm = (w & 1) * 64, wn = (w >> 1) * 64;
    short8 wf[4][4];
#pragma unroll
    for (int ni = 0; ni < 4; ++ni)
#pragma unroll
        for (int ks = 0; ks < 4; ++ks)
            wf[ni][ks] = *(const short8*)(W1t + (size_t)(wn + ni * 16 + lr) * 128 + ks * 32 + lq * 8);
#pragma unroll
    for (int p = 0; p < 8; ++p) {
        int ch = p * 256 + tid;
        int r = ch >> 4, c = ch & 15;
        int row = bm + r;
        uint4 v = make_uint4(0u, 0u, 0u, 0u);
        if (row < M) v = *(const uint4*)(A + (size_t)row * 128 + c * 8);
        *(uint4*)(&As[r * 128 + ((c ^ (r & 15)) * 8)]) = v;
    }
    __syncthreads();
    {
        f32x4 acc[4][4] = {};
#pragma unroll
        for (int ks = 0; ks < 4; ++ks) {
            int cb = ks * 4 + lq;
            short8 af[4];
#pragma unroll
            for (int mi = 0; mi < 4; ++mi)
                af[mi] = *(const short8*)(&As[(wm + mi * 16 + lr) * 128 + ((cb ^ lr) * 8)]);
#pragma unroll
            for (int mi = 0; mi < 4; ++mi)
#pragma unroll
                for (int ni = 0; ni < 4; ++ni)
                    acc[mi][ni] = __builtin_amdgcn_mfma_f32_16x16x32_bf16(af[mi], wf[ni][ks], acc[mi][ni], 0, 0, 0);
        }
#pragma unroll
        for (int mi = 0; mi < 4; ++mi)
#pragma unroll
            for (int reg = 0; reg < 4; ++reg) {
                int row = wm + mi * 16 + lq * 4 + reg;
#pragma unroll
                for (int ni = 0; ni < 4; ++ni) {
                    int col = wn + ni * 16 + lr;
                    float v = fmaxf(acc[mi][ni][reg] + b1[col], 0.f);
                    bf16 bv = __float2bfloat16(v);
                    Ts[row * 128 + (((col >> 3) ^ (row & 15)) * 8) + (col & 7)] = *(ushort*)&bv;
                }
            }
    }
#pragma unroll
    for (int ni = 0; ni < 4; ++ni)
#pragma unroll
        for (int ks = 0; ks < 4; ++ks)
            wf[ni][ks] = *(const short8*)(W2t + (size_t)(wn + ni * 16 + lr) * 128 + ks * 32 + lq * 8);
    __syncthreads();
    {
        f32x4 acc[4][4] = {};
#pragma unroll
        for (int ks = 0; ks < 4; ++ks) {
            int cb = ks * 4 + lq;
            short8 af[4];
#pragma unroll
            for (int mi = 0; mi < 4; ++mi)
                af[mi] = *(const short8*)(&Ts[(wm + mi * 16 + lr) * 128 + ((cb ^ lr) * 8)]);
#pragma unroll
            for (int mi = 0; mi < 4; ++mi)
#pragma unroll
                for (int ni = 0; ni < 4; ++ni)
                    acc[mi][ni] = __builtin_amdgcn_mfma_f32_16x16x32_bf16(af[mi], wf[ni][ks], acc[mi][ni], 0, 0, 0);
        }
#pragma unroll
        for (int mi = 0; mi < 4; ++mi)
#pragma unroll
            for (int reg = 0; reg < 4; ++reg) {
                int row = bm + wm + mi * 16 + lq * 4 + reg;
                if (row >= M) continue;
#pragma unroll
                for (int ni = 0; ni < 4; ++ni) {
                    int col = wn + ni * 16 + lr;
                    bf16 bv = __float2bfloat16(acc[mi][ni][reg] + b2[col]);
                    C[(size_t)row * 128 + col] = *(ushort*)&bv;
                }
            }
    }
}

// ===== fused GRU: 512 thr, 32 rows/block, 16 cols/wave, dbuf weight prefetch =====
__global__ __launch_bounds__(512, 4) void gru_fused(
    const ushort* __restrict__ mfeat, const ushort* __restrict__ wih,
    const ushort* __restrict__ whh, const float* __restrict__ bih,
    const float* __restrict__ bhh, ushort* __restrict__ node, int Nn)
{
    __shared__ ushort Ms[32 * 128];
    __shared__ ushort Hs[32 * 128];
    const int tid = threadIdx.x;
    const int bm = blockIdx.x * 32;
#pragma unroll
    for (int p = 0; p < 2; ++p) {
        int ch = p * 512 + tid;
        bool isH = ch >= 512;
        int r = (ch >> 4) & 31, c = ch & 15;
        int row = bm + r;
        uint4 v = make_uint4(0u, 0u, 0u, 0u);
        if (row < Nn) v = *(const uint4*)((isH ? node : mfeat) + (size_t)row * 128 + c * 8);
        ushort* dst = isH ? Hs : Ms;
        *(uint4*)(&dst[r * 128 + ((c ^ (r & 15)) * 8)]) = v;
    }
    const int lane = tid & 63, w = tid >> 6;
    const int lr = lane & 15, lq = lane >> 4;
    const int col = w * 16 + lr;
    auto loadw = [&](int ks, short8* wv) {
        int koff = ks * 32 + lq * 8;
        wv[0] = *(const short8*)(wih + (size_t)col * 128 + koff);
        wv[1] = *(const short8*)(wih + (size_t)(128 + col) * 128 + koff);
        wv[2] = *(const short8*)(wih + (size_t)(256 + col) * 128 + koff);
        wv[3] = *(const short8*)(whh + (size_t)col * 128 + koff);
        wv[4] = *(const short8*)(whh + (size_t)(128 + col) * 128 + koff);
        wv[5] = *(const short8*)(whh + (size_t)(256 + col) * 128 + koff);
    };
    short8 wA[6], wB[6];
    loadw(0, wA);
    __syncthreads();
    f32x4 aR[2] = {}, aZ[2] = {}, aN[2] = {}, aH[2] = {};
#pragma unroll
    for (int ks = 0; ks < 4; ++ks) {
        short8* cur = (ks & 1) ? wB : wA;
        short8* nxt = (ks & 1) ? wA : wB;
        if (ks < 3) loadw(ks + 1, nxt);
        int cb = ks * 4 + lq;
        short8 am[2], ah[2];
#pragma unroll
        for (int rt = 0; rt < 2; ++rt) {
            int off = (rt * 16 + lr) * 128 + ((cb ^ lr) * 8);
            am[rt] = *(const short8*)(&Ms[off]);
            ah[rt] = *(const short8*)(&Hs[off]);
        }
#pragma unroll
        for (int rt = 0; rt < 2; ++rt) {
            aR[rt] = __builtin_amdgcn_mfma_f32_16x16x32_bf16(am[rt], cur[0], aR[rt], 0, 0, 0);
            aR[rt] = __builtin_amdgcn_mfma_f32_16x16x32_bf16(ah[rt], cur[3], aR[rt], 0, 0, 0);
            aZ[rt] = __builtin_amdgcn_mfma_f32_16x16x32_bf16(am[rt], cur[1], aZ[rt], 0, 0, 0);
            aZ[rt] = __builtin_amdgcn_mfma_f32_16x16x32_bf16(ah[rt], cur[4], aZ[rt], 0, 0, 0);
            aN[rt] = __builtin_amdgcn_mfma_f32_16x16x32_bf16(am[rt], cur[2], aN[rt], 0, 0, 0);
            aH[rt] = __builtin_amdgcn_mfma_f32_16x16x32_bf16(ah[rt], cur[5], aH[rt], 0, 0, 0);
        }
    }
    {
        int h = col;
        float br = bih[h] + bhh[h];
        float bz = bih[128 + h] + bhh[128 + h];
        float bin = bih[256 + h], bhn = bhh[256 + h];
#pragma unroll
        for (int rt = 0; rt < 2; ++rt)
#pragma unroll
            for (int reg = 0; reg < 4; ++reg) {
                int lrow = rt * 16 + lq * 4 + reg;
                int row = bm + lrow;
                if (row >= Nn) continue;
                float r = sigm(aR[rt][reg] + br);
                float z = sigm(aZ[rt][reg] + bz);
                float n = ftanh(aN[rt][reg] + bin + r * (aH[rt][reg] + bhn));
                int hofs = lrow * 128 + (((h >> 3) ^ (lrow & 15)) * 8) + (h & 7);
                float hold = __bfloat162float(*(const bf16*)&Hs[hofs]);
                bf16 hv = __float2bfloat16((1.f - z) * n + z * hold);
                node[(size_t)row * 128 + h] = *(ushort*)&hv;
            }
    }
}

// ================= fused LSTM step =================
__global__ __launch_bounds__(256) void lstm_fused(
    ushort* __restrict__ s, const ushort* __restrict__ Wl,
    const float* __restrict__ bih, const float* __restrict__ bhh,
    float* __restrict__ cl, int Gn)
{
    __shared__ ushort Ss[32 * 256];
    const int tid = threadIdx.x;
    const int bm = blockIdx.x * 32;
#pragma unroll
    for (int p = 0; p < 4; ++p) {
        int ch = p * 256 + tid;
        int r = ch >> 5, c = ch & 31;
        int row = bm + r;
        uint4 v = make_uint4(0u, 0u, 0u, 0u);
        if (row < Gn) v = *(const uint4*)(s + (size_t)row * 256 + c * 8);
        *(uint4*)(&Ss[r * 256 + ((c ^ (r & 15)) * 8)]) = v;
    }
    __syncthreads();
    const int lane = tid & 63, w = tid >> 6;
    const int lr = lane & 15, lq = lane >> 4;
    f32x4 acc[2][4][2] = {};
#pragma unroll
    for (int ks = 0; ks < 8; ++ks) {
        int cb = ks * 4 + lq;
        short8 am[2];
#pragma unroll
        for (int rt = 0; rt < 2; ++rt)
            am[rt] = *(const short8*)(&Ss[(rt * 16 + lr) * 256 + ((cb ^ lr) * 8)]);
        int koff = ks * 32 + lq * 8;
#pragma unroll
        for (int g = 0; g < 4; ++g)
#pragma unroll
            for (int sub = 0; sub < 2; ++sub) {
                int col = g * 128 + w * 32 + sub * 16 + lr;
                short8 bf = *(const short8*)(Wl + (size_t)col * 256 + koff);
#pragma unroll
                for (int rt = 0; rt < 2; ++rt)
                    acc[rt][g][sub] = __builtin_amdgcn_mfma_f32_16x16x32_bf16(am[rt], bf, acc[rt][g][sub], 0, 0, 0);
            }
    }
#pragma unroll
    for (int sub = 0; sub < 2; ++sub) {
        int h = w * 32 + sub * 16 + lr;
        float bi = bih[h] + bhh[h];
        float bff = bih[128 + h] + bhh[128 + h];
        float bg = bih[256 + h] + bhh[256 + h];
        float bo = bih[384 + h] + bhh[384 + h];
#pragma unroll
        for (int rt = 0; rt < 2; ++rt)
#pragma unroll
            for (int reg = 0; reg < 4; ++reg) {
                int row = bm + rt * 16 + lq * 4 + reg;
                if (row >= Gn) continue;
                float iv = sigm(acc[rt][0][sub][reg] + bi);
                float fv = sigm(acc[rt][1][sub][reg] + bff);
                float gv = ftanh(acc[rt][2][sub][reg] + bg);
                float ov = sigm(acc[rt][3][sub][reg] + bo);
                float c = fv * cl[(size_t)row * 128 + h] + iv * gv;
                cl[(size_t)row * 128 + h] = c;
                bf16 hv = __float2bfloat16(ov * ftanh(c));
                s[(size_t)row * 256 + h] = *(ushort*)&hv;
            }
    }
}

// ================= fused per-graph attention (fully vectorized) ==============
__global__ __launch_bounds__(256) void att_fused(
    const ushort* __restrict__ node, ushort* __restrict__ s,
    const int* __restrict__ gptr)
{
    __shared__ float q[128];
    __shared__ float es[512];
    __shared__ float red[8];
    __shared__ float part[16][128];
    int g = blockIdx.x;
    int tid = threadIdx.x, lane = tid & 63, wid = tid >> 6;
    int n0 = gptr[g], n1 = gptr[g + 1];
    int cnt = n1 - n0; if (cnt > 512) cnt = 512;
    if (tid < 128) q[tid] = __bfloat162float(((const bf16*)s)[(size_t)g * 256 + tid]);
    __syncthreads();
    int gr = tid >> 4, c8 = (tid & 15) * 8;
    // vectorized dot: 16 threads/node, 16-lane segment reduce
    for (int i0 = 0; i0 < cnt; i0 += 16) {
        int i = i0 + gr;
        float p = 0.f;
        if (i < cnt) {
            uint4 v = *(const uint4*)(node + (size_t)(n0 + i) * TH + c8);
            float f[8]; unpack8(v, f);
#pragma unroll
            for (int j = 0; j < 8; ++j) p = fmaf(f[j], q[c8 + j], p);
        }
        p += __shfl_down(p, 8, 16);
        p += __shfl_down(p, 4, 16);
        p += __shfl_down(p, 2, 16);
        p += __shfl_down(p, 1, 16);
        if ((tid & 15) == 0 && i < cnt) es[i] = p;
    }
    __syncthreads();
    float m = -1e30f;
    for (int i = tid; i < cnt; i += 256) m = fmaxf(m, es[i]);
    for (int off = 32; off; off >>= 1) m = fmaxf(m, __shfl_down(m, off));
    if (lane == 0) red[wid] = m;
    __syncthreads();
    m = fmaxf(fmaxf(red[0], red[1]), fmaxf(red[2], red[3]));
    float sm = 0.f;
    for (int i = tid; i < cnt; i += 256) { float ex = __expf(es[i] - m); es[i] = ex; sm += ex; }
    for (int off = 32; off; off >>= 1) sm += __shfl_down(sm, off);
    if (lane == 0) red[4 + wid] = sm;
    __syncthreads();
    sm = red[4] + red[5] + red[6] + red[7];
    float inv = 1.f / fmaxf(sm, 1e-9f);
    float racc[8] = {};
    for (int i = gr; i < cnt; i += 16) {
        uint4 v = *(const uint4*)(node + (size_t)(n0 + i) * TH + c8);
        float f[8]; unpack8(v, f);
        float a = es[i];
#pragma unroll
        for (int j = 0; j < 8; ++j) racc[j] = fmaf(a, f[j], racc[j]);
    }
#pragma unroll
    for (int j = 0; j < 8; ++j) part[gr][c8 + j] = racc[j];
    __syncthreads();
    if (tid < 128) {
        float r = 0.f;
#pragma unroll
        for (int k = 0; k < 16; ++k) r += part[k][tid];
        bf16 rv = __float2bfloat16(r * inv);
        s[(size_t)g * 256 + 128 + tid] = *(ushort*)&rv;
    }
}

// ================= final FC =================
__global__ __launch_bounds__(128) void final_fc(const ushort* __restrict__ s,
                                                const float* __restrict__ w1,
                                                const float* __restrict__ b1,
                                                const float* __restrict__ w2,
                                                const float* __restrict__ b2,
                                                float* __restrict__ out) {
    __shared__ float q[256];
    __shared__ float red[2];
    int g = blockIdx.x, t = threadIdx.x;
    q[t] = __bfloat162float(((const bf16*)s)[(size_t)g * 256 + t]);
    q[t + 128] = __bfloat162float(((const bf16*)s)[(size_t)g * 256 + 128 + t]);
    __syncthreads();
    float acc = b1[t];
    for (int k = 0; k < 256; ++k) acc = fmaf(q[k], w1[k * TH + t], acc);
    acc = fmaxf(acc, 0.f);
    float p = acc * w2[t];
    for (int off = 32; off; off >>= 1) p += __shfl_down(p, off);
    if ((t & 63) == 0) red[t >> 6] = p;
    __syncthreads();
    if (t == 0) out[g] = red[0] + red[1] + b2[0];
}

// ---------------------------------------------------------------------------
static void launch_mlp2(const void* A, const bf16* W1t, const float* b1,
                        const bf16* W2t, const float* b2, void* C, int M, hipStream_t s) {
    hipLaunchKernelGGL(mlp2_fused, dim3((M + 127) / 128), dim3(256), 0, s,
                       (const ushort*)A, (const ushort*)W1t, b1, (const ushort*)W2t, b2,
                       (ushort*)C, M);
}

extern "C" void kernel_launch(void* const* d_in, const int* in_sizes, int n_in,
                              void* d_out, int out_size, void* d_ws, size_t ws_size,
                              hipStream_t stream) {
    const float* x         = (const float*)d_in[0];
    const float* edge_attr = (const float*)d_in[1];
    const int*   edge_index= (const int*)d_in[2];
    const int*   batch     = (const int*)d_in[3];
    const float* node_w    = (const float*)d_in[4];
    const float* node_b    = (const float*)d_in[5];
    const float* edge_w    = (const float*)d_in[6];
    const float* edge_b    = (const float*)d_in[7];
    const float* eps       = (const float*)d_in[8];
    const float* gin_w1    = (const float*)d_in[9];
    const float* gin_b1    = (const float*)d_in[10];
    const float* gin_w2    = (const float*)d_in[11];
    const float* gin_b2    = (const float*)d_in[12];
    const float* em_w1     = (const float*)d_in[13];
    const float* em_b1     = (const float*)d_in[14];
    const float* em_w2     = (const float*)d_in[15];
    const float* em_b2     = (const float*)d_in[16];
    const float* gru_wih   = (const float*)d_in[17];
    const float* gru_whh   = (const float*)d_in[18];
    const float* gru_bih   = (const float*)d_in[19];
    const float* gru_bhh   = (const float*)d_in[20];
    const float* lstm_wih  = (const float*)d_in[21];
    const float* lstm_whh  = (const float*)d_in[22];
    const float* lstm_bih  = (const float*)d_in[23];
    const float* lstm_bhh  = (const float*)d_in[24];
    const float* fc_w1     = (const float*)d_in[25];
    const float* fc_b1     = (const float*)d_in[26];
    const float* fc_w2     = (const float*)d_in[27];
    const float* fc_b2     = (const float*)d_in[28];
    float* out = (float*)d_out;
    const int* ei_src = edge_index;
    const int* ei_dst = edge_index + TE;

    // ---- workspace layout ----
    char* base = (char*)d_ws;
    size_t off = 0;
    auto alloc = [&](size_t bytes) { void* p = base + off; off += (bytes + 15) & ~size_t(15); return p; };
    bf16*  nodeb = (bf16*)alloc((size_t)TN * TH * 2);   // 25.6 MB
    bf16*  zb    = (bf16*)alloc((size_t)TN * TH * 2);   // 25.6 MB
    bf16*  e1b   = (bf16*)alloc((size_t)TE * TH * 2);   // 51.2 MB (set2set overlay later)
    int*   deg   = (int*)alloc((size_t)TN * 4);
    int*   rowptr= (int*)alloc((size_t)(TN + 1) * 4);
    int*   cur   = (int*)alloc((size_t)TN * 4);
    int*   srcp  = (int*)alloc((size_t)TE * 4);
    int*   epos  = (int*)alloc((size_t)TE * 4);
    int*   bsum  = (int*)alloc(512 * 4);
    int*   bsumx = (int*)alloc(512 * 4);
    int*   gptr  = (int*)alloc((size_t)(TG + 1) * 4);
    bf16*  w6    = (bf16*)alloc(6 * TH * TH * 2);
    bf16*  wgru  = (bf16*)alloc(2 * 384 * TH * 2);
    bf16*  wl    = (bf16*)alloc(512 * 256 * 2);
    if (ws_size < off) return;

    bf16* w_gin1_0 = w6;
    bf16* w_gin1_1 = w6 + 1 * TH * TH;
    bf16* w_gin2_0 = w6 + 2 * TH * TH;
    bf16* w_gin2_1 = w6 + 3 * TH * TH;
    bf16* w_em1    = w6 + 4 * TH * TH;
    bf16* w_em2    = w6 + 5 * TH * TH;
    bf16* w_wih    = wgru;
    bf16* w_whh    = wgru + 384 * TH;

    ushort* sbuf = (ushort*)e1b;                      // [G][256] bf16
    float*  cl   = (float*)(sbuf + (size_t)TG * 256); // [G][128] fp32

    // ---- CSR + gptr ----
    hipMemsetAsync(deg, 0, (size_t)TN * 4, stream);
    hipMemsetAsync(cur, 0, (size_t)TN * 4, stream);
    count_deg<<<(TE + 255) / 256, 256, 0, stream>>>(ei_dst, deg, TE);
    int nb = (TN + 255) / 256;
    scan_block<<<nb, 256, 0, stream>>>(deg, rowptr, bsum, TN);
    scan_bsum<<<1, 512, 0, stream>>>(bsum, bsumx, nb);
    add_off<<<nb, 256, 0, stream>>>(rowptr, bsumx, TN, TE);
    fill_csr<<<(TE + 255) / 256, 256, 0, stream>>>(ei_src, ei_dst, rowptr, cur, srcp, epos, TE);
    build_gptr<<<(TN + 255) / 256, 256, 0, stream>>>(batch, gptr, TN, TG);

    // ---- weights ----
    conv6<<<(6 * TH * TH + 255) / 256, 256, 0, stream>>>(
        gin_w1, gin_w1 + TH * TH, gin_w2, gin_w2 + TH * TH, em_w1, em_w2, w6);
    conv2<<<(2 * 384 * TH + 255) / 256, 256, 0, stream>>>(gru_wih, gru_whh, wgru);
    convL<<<(512 * 256 + 255) / 256, 256, 0, stream>>>(lstm_wih, lstm_whh, wl);

    // ---- projections (edges scattered into CSR slot order) ----
    proj64<14><<<(TN + 63) / 64, 256, 0, stream>>>(x, node_w, node_b, (ushort*)nodeb, TN);
    proj_scatter<<<(TE + 63) / 64, 256, 0, stream>>>(edge_attr, edge_w, edge_b,
                                                     epos, (ushort*)e1b, TE);

    // ---- layer 0 ----
    aggregate_v8<<<(TN * 16 + 255) / 256, 256, 0, stream>>>(
        (const ushort*)nodeb, (const ushort*)e1b, srcp, rowptr, eps, 0, (ushort*)zb, TN);
    launch_mlp2(zb, w_gin1_0, gin_b1, w_gin2_0, gin_b2, zb, TN, stream);
    gru_fused<<<(TN + 31) / 32, 512, 0, stream>>>(
        (const ushort*)zb, (const ushort*)w_wih, (const ushort*)w_whh,
        gru_bih, gru_bhh, (ushort*)nodeb, TN);

    // ---- edge MLP in-place (slot order preserved), layer 1 ----
    launch_mlp2(e1b, w_em1, em_b1, w_em2, em_b2, e1b, TE, stream);
    aggregate_v8<<<(TN * 16 + 255) / 256, 256, 0, stream>>>(
        (const ushort*)nodeb, (const ushort*)e1b, srcp, rowptr, eps, 1, (ushort*)zb, TN);
    launch_mlp2(zb, w_gin1_1, gin_b1 + TH, w_gin2_1, gin_b2 + TH, zb, TN, stream);
    gru_fused<<<(TN + 31) / 32, 512, 0, stream>>>(
        (const ushort*)zb, (const ushort*)w_wih, (const ushort*)w_whh,
        gru_bih, gru_bhh, (ushort*)nodeb, TN);

    // ---- Set2Set (3 steps) ----
    hipMemsetAsync(sbuf, 0, (size_t)TG * 256 * 2 + (size_t)TG * 128 * 4, stream);
    for (int st = 0; st < 3; ++st) {
        lstm_fused<<<(TG + 31) / 32, 256, 0, stream>>>(
            sbuf, (const ushort*)wl, lstm_bih, lstm_bhh, cl, TG);
        att_fused<<<TG, 256, 0, stream>>>((const ushort*)nodeb, sbuf, gptr);
    }

    // ---- final FC ----
    final_fc<<<TG, 128, 0, stream>>>(sbuf, fc_w1, fc_b1, fc_w2, fc_b2, out);
}

// Round 11
// 557.804 us; speedup vs baseline: 6.3526x; 1.1137x over previous
//
#include <hip/hip_runtime.h>
#include <hip/hip_bf16.h>

constexpr int TN = 100000;   // nodes
constexpr int TE = 200000;   // edges
constexpr int TG = 4000;     // graphs
constexpr int TH = 128;      // hidden

using short8 = __attribute__((ext_vector_type(8))) short;
using f32x4  = __attribute__((ext_vector_type(4))) float;
typedef __hip_bfloat16 bf16;

#define DEVINL __device__ __forceinline__
DEVINL float sigm(float x)  { return 1.f / (1.f + __expf(-x)); }
DEVINL float ftanh(float x) { return 1.f - 2.f / (__expf(2.f * x) + 1.f); }
DEVINL void unpack8(uint4 v, float* f) {
    const ushort* u = (const ushort*)&v;
#pragma unroll
    for (int j = 0; j < 8; ++j) f[j] = __bfloat162float(*(const bf16*)&u[j]);
}

// ================= merged weight conversion =================
// region 0: 6 transposed 128x128 -> w6 ; region 1: gru wih/whh copy ; region 2: lstm fused
__global__ void convAll(const float* __restrict__ g1, const float* __restrict__ g2,
                        const float* __restrict__ e1, const float* __restrict__ e2,
                        const float* __restrict__ gwih, const float* __restrict__ gwhh,
                        const float* __restrict__ lwih, const float* __restrict__ lwhh,
                        bf16* __restrict__ w6, bf16* __restrict__ wgru,
                        bf16* __restrict__ wl) {
    int i = blockIdx.x * 256 + threadIdx.x;
    if (i < 6 * TH * TH) {
        int m = i >> 14, r = i & 16383;
        int n = r >> 7, k = r & 127;
        const float* s = (m == 0) ? g1 : (m == 1) ? g1 + TH * TH
                       : (m == 2) ? g2 : (m == 3) ? g2 + TH * TH
                       : (m == 4) ? e1 : e2;
        w6[i] = __float2bfloat16(s[k * TH + n]);
        return;
    }
    i -= 6 * TH * TH;
    if (i < 2 * 384 * TH) {
        const float* s = (i < 384 * TH) ? gwih : gwhh;
        int r = (i < 384 * TH) ? i : i - 384 * TH;
        wgru[i] = __float2bfloat16(s[r]);
        return;
    }
    i -= 2 * 384 * TH;
    if (i < 512 * 256) {
        int c = i >> 8, k = i & 255;
        float v = (k < 128) ? lwih[c * 256 + k] + lwhh[c * 128 + k] : lwih[c * 256 + k];
        wl[i] = __float2bfloat16(v);
    }
}

// ================= node projection: 64 rows/block ============
template<int K>
__global__ __launch_bounds__(256) void proj64(const float* __restrict__ X,
                                              const float* __restrict__ W,
                                              const float* __restrict__ b,
                                              ushort* __restrict__ out, int M) {
    __shared__ float xs[64][K];
    int tid = threadIdx.x;
    int bm = blockIdx.x * 64;
    for (int i = tid; i < 64 * K; i += 256) {
        int r = i / K, k = i % K;
        xs[r][k] = (bm + r < M) ? X[(size_t)(bm + r) * K + k] : 0.f;
    }
    __syncthreads();
    int rb = tid >> 4, h0 = (tid & 15) * 8;
    float acc[4][8];
#pragma unroll
    for (int j = 0; j < 4; ++j)
#pragma unroll
        for (int c = 0; c < 8; ++c) acc[j][c] = b[h0 + c];
#pragma unroll
    for (int k = 0; k < K; ++k) {
        float4 w0 = *(const float4*)(W + k * TH + h0);
        float4 w1 = *(const float4*)(W + k * TH + h0 + 4);
#pragma unroll
        for (int j = 0; j < 4; ++j) {
            float xv = xs[rb + 16 * j][k];
            acc[j][0] = fmaf(xv, w0.x, acc[j][0]); acc[j][1] = fmaf(xv, w0.y, acc[j][1]);
            acc[j][2] = fmaf(xv, w0.z, acc[j][2]); acc[j][3] = fmaf(xv, w0.w, acc[j][3]);
            acc[j][4] = fmaf(xv, w1.x, acc[j][4]); acc[j][5] = fmaf(xv, w1.y, acc[j][5]);
            acc[j][6] = fmaf(xv, w1.z, acc[j][6]); acc[j][7] = fmaf(xv, w1.w, acc[j][7]);
        }
    }
#pragma unroll
    for (int j = 0; j < 4; ++j) {
        int row = bm + rb + 16 * j;
        if (row >= M) continue;
        ushort o[8];
#pragma unroll
        for (int c = 0; c < 8; ++c) {
            bf16 v = __float2bfloat16(acc[j][c]);
            o[c] = *(ushort*)&v;
        }
        *(uint4*)(out + (size_t)row * TH + h0) = *(uint4*)o;
    }
}

// ===== proj_scatter: K=4 projection with CSR-slot scatter (layer-0 e0) =====
__global__ __launch_bounds__(256) void proj_scatter(
    const float* __restrict__ X, const float* __restrict__ W,
    const float* __restrict__ b, const int* __restrict__ perm,
    ushort* __restrict__ out, int M) {
    __shared__ float xs[64][4];
    int tid = threadIdx.x;
    int bm = blockIdx.x * 64;
    if (tid < 64) {
        float4 a = make_float4(0.f, 0.f, 0.f, 0.f);
        if (bm + tid < M) a = *(const float4*)(X + (size_t)(bm + tid) * 4);
        xs[tid][0] = a.x; xs[tid][1] = a.y; xs[tid][2] = a.z; xs[tid][3] = a.w;
    }
    __syncthreads();
    int rb = tid >> 4, h0 = (tid & 15) * 8;
    float acc[4][8];
#pragma unroll
    for (int j = 0; j < 4; ++j)
#pragma unroll
        for (int c = 0; c < 8; ++c) acc[j][c] = b[h0 + c];
#pragma unroll
    for (int k = 0; k < 4; ++k) {
        float4 w0 = *(const float4*)(W + k * TH + h0);
        float4 w1 = *(const float4*)(W + k * TH + h0 + 4);
#pragma unroll
        for (int j = 0; j < 4; ++j) {
            float xv = xs[rb + 16 * j][k];
            acc[j][0] = fmaf(xv, w0.x, acc[j][0]); acc[j][1] = fmaf(xv, w0.y, acc[j][1]);
            acc[j][2] = fmaf(xv, w0.z, acc[j][2]); acc[j][3] = fmaf(xv, w0.w, acc[j][3]);
            acc[j][4] = fmaf(xv, w1.x, acc[j][4]); acc[j][5] = fmaf(xv, w1.y, acc[j][5]);
            acc[j][6] = fmaf(xv, w1.z, acc[j][6]); acc[j][7] = fmaf(xv, w1.w, acc[j][7]);
        }
    }
#pragma unroll
    for (int j = 0; j < 4; ++j) {
        int row = bm + rb + 16 * j;
        if (row >= M) continue;
        ushort o[8];
#pragma unroll
        for (int c = 0; c < 8; ++c) {
            bf16 v = __float2bfloat16(acc[j][c]);
            o[c] = *(ushort*)&v;
        }
        *(uint4*)(out + (size_t)perm[row] * TH + h0) = *(uint4*)o;
    }
}

// ================= CSR build =================
__global__ void count_deg(const int* __restrict__ ei_dst, int* __restrict__ deg, int En) {
    int e = blockIdx.x * 256 + threadIdx.x;
    if (e < En) atomicAdd(&deg[ei_dst[e]], 1);
}
__global__ void scan_block(const int* __restrict__ deg, int* __restrict__ rowptr,
                           int* __restrict__ bsum, int Nn) {
    __shared__ int sm[256];
    int tid = threadIdx.x;
    int gid = blockIdx.x * 256 + tid;
    int v = (gid < Nn) ? deg[gid] : 0;
    int x = v;
    sm[tid] = x; __syncthreads();
    for (int off = 1; off < 256; off <<= 1) {
        int t = (tid >= off) ? sm[tid - off] : 0;
        __syncthreads();
        x += t; sm[tid] = x;
        __syncthreads();
    }
    if (gid < Nn) rowptr[gid] = x - v;
    if (tid == 255) bsum[blockIdx.x] = x;
}
__global__ void scan_bsum(const int* __restrict__ bsum, int* __restrict__ bsumx, int nb) {
    __shared__ int sm[512];
    int tid = threadIdx.x;
    int v = (tid < nb) ? bsum[tid] : 0;
    int x = v;
    sm[tid] = x; __syncthreads();
    for (int off = 1; off < 512; off <<= 1) {
        int t = (tid >= off) ? sm[tid - off] : 0;
        __syncthreads();
        x += t; sm[tid] = x;
        __syncthreads();
    }
    if (tid < nb) bsumx[tid] = x - v;
}
__global__ void add_off(int* __restrict__ rowptr, const int* __restrict__ bsumx,
                        int Nn, int Etot) {
    int gid = blockIdx.x * 256 + threadIdx.x;
    if (gid < Nn) rowptr[gid] += bsumx[gid >> 8];
    if (gid == 0) rowptr[Nn] = Etot;
}
__global__ void fill_csr(const int* __restrict__ ei_src, const int* __restrict__ ei_dst,
                         const int* __restrict__ rowptr, int* __restrict__ cur,
                         int* __restrict__ srcp, int* __restrict__ epos, int En) {
    int e = blockIdx.x * 256 + threadIdx.x;
    if (e >= En) return;
    int d = ei_dst[e];
    int p = atomicAdd(&cur[d], 1);
    int slot = rowptr[d] + p;
    srcp[slot] = ei_src[e];
    epos[e] = slot;
}
__global__ void build_gptr(const int* __restrict__ batch, int* __restrict__ gptr,
                           int Nn, int Gn) {
    int n = blockIdx.x * 256 + threadIdx.x;
    if (n >= Nn) return;
    int bc = batch[n];
    int bp = (n == 0) ? -1 : batch[n - 1];
    for (int g = bp + 1; g <= bc; ++g) gptr[g] = n;
    if (n == Nn - 1) for (int g = bc + 1; g <= Gn; ++g) gptr[g] = Nn;
}

// ========== aggregation, 8 ch/thread, 2-way unrolled gather ==========
__global__ __launch_bounds__(256) void aggregate_v8(
    const ushort* __restrict__ node, const ushort* __restrict__ ef,
    const int* __restrict__ srcp, const int* __restrict__ rowptr,
    const float* __restrict__ eps, int l, ushort* __restrict__ zb, int Nn) {
    int t = blockIdx.x * 256 + threadIdx.x;
    int n = t >> 4;
    if (n >= Nn) return;
    int c8 = (t & 15) * 8;
    float se = 1.f + eps[l];
    float acc[8];
    uint4 nv = *(const uint4*)(node + (size_t)n * TH + c8);
    unpack8(nv, acc);
#pragma unroll
    for (int j = 0; j < 8; ++j) acc[j] *= se;
    int s0 = rowptr[n], s1 = rowptr[n + 1];
    int i = s0;
    for (; i + 1 < s1; i += 2) {
        int sa = srcp[i], sb = srcp[i + 1];
        uint4 av0 = *(const uint4*)(node + (size_t)sa * TH + c8);
        uint4 bv0 = *(const uint4*)(ef + (size_t)i * TH + c8);
        uint4 av1 = *(const uint4*)(node + (size_t)sb * TH + c8);
        uint4 bv1 = *(const uint4*)(ef + (size_t)(i + 1) * TH + c8);
        float a0[8], b0[8], a1[8], b1[8];
        unpack8(av0, a0); unpack8(bv0, b0);
        unpack8(av1, a1); unpack8(bv1, b1);
#pragma unroll
        for (int j = 0; j < 8; ++j)
            acc[j] += fmaxf(a0[j] + b0[j], 0.f) + fmaxf(a1[j] + b1[j], 0.f);
    }
    if (i < s1) {
        int sa = srcp[i];
        uint4 av = *(const uint4*)(node + (size_t)sa * TH + c8);
        uint4 bv = *(const uint4*)(ef + (size_t)i * TH + c8);
        float af[8], bf[8];
        unpack8(av, af); unpack8(bv, bf);
#pragma unroll
        for (int j = 0; j < 8; ++j) acc[j] += fmaxf(af[j] + bf[j], 0.f);
    }
    ushort o[8];
#pragma unroll
    for (int j = 0; j < 8; ++j) {
        bf16 v = __float2bfloat16(acc[j]);
        o[j] = *(ushort*)&v;
    }
    *(uint4*)(zb + (size_t)n * TH + c8) = *(uint4*)o;
}

// ================= fused 2-layer MLP (weights preloaded to registers) =================
__global__ __launch_bounds__(256) void mlp2_fused(
    const ushort* __restrict__ A, const ushort* __restrict__ W1t,
    const float* __restrict__ b1, const ushort* __restrict__ W2t,
    const float* __restrict__ b2, ushort* __restrict__ C, int M)
{
    __shared__ ushort As[128 * 128];
    __shared__ ushort Ts[128 * 128];
    const int tid = threadIdx.x;
    const int bm = blockIdx.x * 128;
    const int lane = tid & 63, w = tid >> 6;
    const int lr = lane & 15, lq = lane >> 4;
    const int wm = (w & 1) * 64, wn = (w >> 1) * 64;
    short8 wf[4][4];
#pragma unroll
    for (int ni = 0; ni < 4; ++ni)
#pragma unroll
        for (int ks = 0; ks < 4; ++ks)
            wf[ni][ks] = *(const short8*)(W1t + (size_t)(wn + ni * 16 + lr) * 128 + ks * 32 + lq * 8);
#pragma unroll
    for (int p = 0; p < 8; ++p) {
        int ch = p * 256 + tid;
        int r = ch >> 4, c = ch & 15;
        int row = bm + r;
        uint4 v = make_uint4(0u, 0u, 0u, 0u);
        if (row < M) v = *(const uint4*)(A + (size_t)row * 128 + c * 8);
        *(uint4*)(&As[r * 128 + ((c ^ (r & 15)) * 8)]) = v;
    }
    __syncthreads();
    {
        f32x4 acc[4][4] = {};
#pragma unroll
        for (int ks = 0; ks < 4; ++ks) {
            int cb = ks * 4 + lq;
            short8 af[4];
#pragma unroll
            for (int mi = 0; mi < 4; ++mi)
                af[mi] = *(const short8*)(&As[(wm + mi * 16 + lr) * 128 + ((cb ^ lr) * 8)]);
#pragma unroll
            for (int mi = 0; mi < 4; ++mi)
#pragma unroll
                for (int ni = 0; ni < 4; ++ni)
                    acc[mi][ni] = __builtin_amdgcn_mfma_f32_16x16x32_bf16(af[mi], wf[ni][ks], acc[mi][ni], 0, 0, 0);
        }
#pragma unroll
        for (int mi = 0; mi < 4; ++mi)
#pragma unroll
            for (int reg = 0; reg < 4; ++reg) {
                int row = wm + mi * 16 + lq * 4 + reg;
#pragma unroll
                for (int ni = 0; ni < 4; ++ni) {
                    int col = wn + ni * 16 + lr;
                    float v = fmaxf(acc[mi][ni][reg] + b1[col], 0.f);
                    bf16 bv = __float2bfloat16(v);
                    Ts[row * 128 + (((col >> 3) ^ (row & 15)) * 8) + (col & 7)] = *(ushort*)&bv;
                }
            }
    }
#pragma unroll
    for (int ni = 0; ni < 4; ++ni)
#pragma unroll
        for (int ks = 0; ks < 4; ++ks)
            wf[ni][ks] = *(const short8*)(W2t + (size_t)(wn + ni * 16 + lr) * 128 + ks * 32 + lq * 8);
    __syncthreads();
    {
        f32x4 acc[4][4] = {};
#pragma unroll
        for (int ks = 0; ks < 4; ++ks) {
            int cb = ks * 4 + lq;
            short8 af[4];
#pragma unroll
            for (int mi = 0; mi < 4; ++mi)
                af[mi] = *(const short8*)(&Ts[(wm + mi * 16 + lr) * 128 + ((cb ^ lr) * 8)]);
#pragma unroll
            for (int mi = 0; mi < 4; ++mi)
#pragma unroll
                for (int ni = 0; ni < 4; ++ni)
                    acc[mi][ni] = __builtin_amdgcn_mfma_f32_16x16x32_bf16(af[mi], wf[ni][ks], acc[mi][ni], 0, 0, 0);
        }
#pragma unroll
        for (int mi = 0; mi < 4; ++mi)
#pragma unroll
            for (int reg = 0; reg < 4; ++reg) {
                int row = bm + wm + mi * 16 + lq * 4 + reg;
                if (row >= M) continue;
#pragma unroll
                for (int ni = 0; ni < 4; ++ni) {
                    int col = wn + ni * 16 + lr;
                    bf16 bv = __float2bfloat16(acc[mi][ni][reg] + b2[col]);
                    C[(size_t)row * 128 + col] = *(ushort*)&bv;
                }
            }
    }
}

// ===== fused GRU: 512 thr, 64 rows/block, 16 cols/wave, 96 MFMA/wave =====
__global__ __launch_bounds__(512, 4) void gru_fused(
    const ushort* __restrict__ mfeat, const ushort* __restrict__ wih,
    const ushort* __restrict__ whh, const float* __restrict__ bih,
    const float* __restrict__ bhh, ushort* __restrict__ node, int Nn)
{
    __shared__ ushort Ms[64 * 128];
    __shared__ ushort Hs[64 * 128];
    const int tid = threadIdx.x;
    const int bm = blockIdx.x * 64;
#pragma unroll
    for (int p = 0; p < 4; ++p) {
        int ch = p * 512 + tid;          // 2048 = 2 bufs x 64 rows x 16 chunks
        bool isH = ch >= 1024;
        int r = (ch >> 4) & 63, c = ch & 15;
        int row = bm + r;
        uint4 v = make_uint4(0u, 0u, 0u, 0u);
        if (row < Nn) v = *(const uint4*)((isH ? node : mfeat) + (size_t)row * 128 + c * 8);
        ushort* dst = isH ? Hs : Ms;
        *(uint4*)(&dst[r * 128 + ((c ^ (r & 15)) * 8)]) = v;
    }
    __syncthreads();
    const int lane = tid & 63, w = tid >> 6;
    const int lr = lane & 15, lq = lane >> 4;
    const int col = w * 16 + lr;
    f32x4 aR[4] = {}, aZ[4] = {}, aN[4] = {}, aH[4] = {};
#pragma unroll
    for (int ks = 0; ks < 4; ++ks) {
        int koff = ks * 32 + lq * 8;
        short8 wv0 = *(const short8*)(wih + (size_t)col * 128 + koff);
        short8 wv1 = *(const short8*)(wih + (size_t)(128 + col) * 128 + koff);
        short8 wv2 = *(const short8*)(wih + (size_t)(256 + col) * 128 + koff);
        short8 wv3 = *(const short8*)(whh + (size_t)col * 128 + koff);
        short8 wv4 = *(const short8*)(whh + (size_t)(128 + col) * 128 + koff);
        short8 wv5 = *(const short8*)(whh + (size_t)(256 + col) * 128 + koff);
        int cb = ks * 4 + lq;
#pragma unroll
        for (int rt = 0; rt < 4; ++rt) {
            int off = (rt * 16 + lr) * 128 + ((cb ^ lr) * 8);
            short8 am = *(const short8*)(&Ms[off]);
            short8 ah = *(const short8*)(&Hs[off]);
            aR[rt] = __builtin_amdgcn_mfma_f32_16x16x32_bf16(am, wv0, aR[rt], 0, 0, 0);
            aR[rt] = __builtin_amdgcn_mfma_f32_16x16x32_bf16(ah, wv3, aR[rt], 0, 0, 0);
            aZ[rt] = __builtin_amdgcn_mfma_f32_16x16x32_bf16(am, wv1, aZ[rt], 0, 0, 0);
            aZ[rt] = __builtin_amdgcn_mfma_f32_16x16x32_bf16(ah, wv4, aZ[rt], 0, 0, 0);
            aN[rt] = __builtin_amdgcn_mfma_f32_16x16x32_bf16(am, wv2, aN[rt], 0, 0, 0);
            aH[rt] = __builtin_amdgcn_mfma_f32_16x16x32_bf16(ah, wv5, aH[rt], 0, 0, 0);
        }
    }
    {
        int h = col;
        float br = bih[h] + bhh[h];
        float bz = bih[128 + h] + bhh[128 + h];
        float bin = bih[256 + h], bhn = bhh[256 + h];
#pragma unroll
        for (int rt = 0; rt < 4; ++rt)
#pragma unroll
            for (int reg = 0; reg < 4; ++reg) {
                int lrow = rt * 16 + lq * 4 + reg;
                int row = bm + lrow;
                if (row >= Nn) continue;
                float r = sigm(aR[rt][reg] + br);
                float z = sigm(aZ[rt][reg] + bz);
                float n = ftanh(aN[rt][reg] + bin + r * (aH[rt][reg] + bhn));
                int hofs = lrow * 128 + (((h >> 3) ^ (lrow & 15)) * 8) + (h & 7);
                float hold = __bfloat162float(*(const bf16*)&Hs[hofs]);
                bf16 hv = __float2bfloat16((1.f - z) * n + z * hold);
                node[(size_t)row * 128 + h] = *(ushort*)&hv;
            }
    }
}

// ================= fused LSTM step (16 graphs/block, 250 blocks) =================
__global__ __launch_bounds__(256) void lstm_fused(
    ushort* __restrict__ s, const ushort* __restrict__ Wl,
    const float* __restrict__ bih, const float* __restrict__ bhh,
    float* __restrict__ cl, int Gn)
{
    __shared__ ushort Ss[16 * 256];
    const int tid = threadIdx.x;
    const int bm = blockIdx.x * 16;
#pragma unroll
    for (int p = 0; p < 2; ++p) {
        int ch = p * 256 + tid;          // 512 = 16 rows x 32 chunks
        int r = ch >> 5, c = ch & 31;
        int row = bm + r;
        uint4 v = make_uint4(0u, 0u, 0u, 0u);
        if (row < Gn) v = *(const uint4*)(s + (size_t)row * 256 + c * 8);
        *(uint4*)(&Ss[r * 256 + ((c ^ (r & 15)) * 8)]) = v;
    }
    __syncthreads();
    const int lane = tid & 63, w = tid >> 6;
    const int lr = lane & 15, lq = lane >> 4;
    f32x4 acc[4][2] = {};   // [gate][sub]
#pragma unroll
    for (int ks = 0; ks < 8; ++ks) {
        int cb = ks * 4 + lq;
        short8 am = *(const short8*)(&Ss[lr * 256 + ((cb ^ lr) * 8)]);
        int koff = ks * 32 + lq * 8;
#pragma unroll
        for (int g = 0; g < 4; ++g)
#pragma unroll
            for (int sub = 0; sub < 2; ++sub) {
                int col = g * 128 + w * 32 + sub * 16 + lr;
                short8 bf = *(const short8*)(Wl + (size_t)col * 256 + koff);
                acc[g][sub] = __builtin_amdgcn_mfma_f32_16x16x32_bf16(am, bf, acc[g][sub], 0, 0, 0);
            }
    }
#pragma unroll
    for (int sub = 0; sub < 2; ++sub) {
        int h = w * 32 + sub * 16 + lr;
        float bi = bih[h] + bhh[h];
        float bff = bih[128 + h] + bhh[128 + h];
        float bg = bih[256 + h] + bhh[256 + h];
        float bo = bih[384 + h] + bhh[384 + h];
#pragma unroll
        for (int reg = 0; reg < 4; ++reg) {
            int row = bm + lq * 4 + reg;
            if (row >= Gn) continue;
            float iv = sigm(acc[0][sub][reg] + bi);
            float fv = sigm(acc[1][sub][reg] + bff);
            float gv = ftanh(acc[2][sub][reg] + bg);
            float ov = sigm(acc[3][sub][reg] + bo);
            float c = fv * cl[(size_t)row * 128 + h] + iv * gv;
            cl[(size_t)row * 128 + h] = c;
            bf16 hv = __float2bfloat16(ov * ftanh(c));
            s[(size_t)row * 256 + h] = *(ushort*)&hv;
        }
    }
}

// ================= fused per-graph attention (fully vectorized) ==============
__global__ __launch_bounds__(256) void att_fused(
    const ushort* __restrict__ node, ushort* __restrict__ s,
    const int* __restrict__ gptr)
{
    __shared__ float q[128];
    __shared__ float es[512];
    __shared__ float red[8];
    __shared__ float part[16][128];
    int g = blockIdx.x;
    int tid = threadIdx.x, lane = tid & 63, wid = tid >> 6;
    int n0 = gptr[g], n1 = gptr[g + 1];
    int cnt = n1 - n0; if (cnt > 512) cnt = 512;
    if (tid < 128) q[tid] = __bfloat162float(((const bf16*)s)[(size_t)g * 256 + tid]);
    __syncthreads();
    int gr = tid >> 4, c8 = (tid & 15) * 8;
    for (int i0 = 0; i0 < cnt; i0 += 16) {
        int i = i0 + gr;
        float p = 0.f;
        if (i < cnt) {
            uint4 v = *(const uint4*)(node + (size_t)(n0 + i) * TH + c8);
            float f[8]; unpack8(v, f);
#pragma unroll
            for (int j = 0; j < 8; ++j) p = fmaf(f[j], q[c8 + j], p);
        }
        p += __shfl_down(p, 8, 16);
        p += __shfl_down(p, 4, 16);
        p += __shfl_down(p, 2, 16);
        p += __shfl_down(p, 1, 16);
        if ((tid & 15) == 0 && i < cnt) es[i] = p;
    }
    __syncthreads();
    float m = -1e30f;
    for (int i = tid; i < cnt; i += 256) m = fmaxf(m, es[i]);
    for (int off = 32; off; off >>= 1) m = fmaxf(m, __shfl_down(m, off));
    if (lane == 0) red[wid] = m;
    __syncthreads();
    m = fmaxf(fmaxf(red[0], red[1]), fmaxf(red[2], red[3]));
    float sm = 0.f;
    for (int i = tid; i < cnt; i += 256) { float ex = __expf(es[i] - m); es[i] = ex; sm += ex; }
    for (int off = 32; off; off >>= 1) sm += __shfl_down(sm, off);
    if (lane == 0) red[4 + wid] = sm;
    __syncthreads();
    sm = red[4] + red[5] + red[6] + red[7];
    float inv = 1.f / fmaxf(sm, 1e-9f);
    float racc[8] = {};
    for (int i = gr; i < cnt; i += 16) {
        uint4 v = *(const uint4*)(node + (size_t)(n0 + i) * TH + c8);
        float f[8]; unpack8(v, f);
        float a = es[i];
#pragma unroll
        for (int j = 0; j < 8; ++j) racc[j] = fmaf(a, f[j], racc[j]);
    }
#pragma unroll
    for (int j = 0; j < 8; ++j) part[gr][c8 + j] = racc[j];
    __syncthreads();
    if (tid < 128) {
        float r = 0.f;
#pragma unroll
        for (int k = 0; k < 16; ++k) r += part[k][tid];
        bf16 rv = __float2bfloat16(r * inv);
        s[(size_t)g * 256 + 128 + tid] = *(ushort*)&rv;
    }
}

// ================= final FC =================
__global__ __launch_bounds__(128) void final_fc(const ushort* __restrict__ s,
                                                const float* __restrict__ w1,
                                                const float* __restrict__ b1,
                                                const float* __restrict__ w2,
                                                const float* __restrict__ b2,
                                                float* __restrict__ out) {
    __shared__ float q[256];
    __shared__ float red[2];
    int g = blockIdx.x, t = threadIdx.x;
    q[t] = __bfloat162float(((const bf16*)s)[(size_t)g * 256 + t]);
    q[t + 128] = __bfloat162float(((const bf16*)s)[(size_t)g * 256 + 128 + t]);
    __syncthreads();
    float acc = b1[t];
    for (int k = 0; k < 256; ++k) acc = fmaf(q[k], w1[k * TH + t], acc);
    acc = fmaxf(acc, 0.f);
    float p = acc * w2[t];
    for (int off = 32; off; off >>= 1) p += __shfl_down(p, off);
    if ((t & 63) == 0) red[t >> 6] = p;
    __syncthreads();
    if (t == 0) out[g] = red[0] + red[1] + b2[0];
}

// ---------------------------------------------------------------------------
static void launch_mlp2(const void* A, const bf16* W1t, const float* b1,
                        const bf16* W2t, const float* b2, void* C, int M, hipStream_t s) {
    hipLaunchKernelGGL(mlp2_fused, dim3((M + 127) / 128), dim3(256), 0, s,
                       (const ushort*)A, (const ushort*)W1t, b1, (const ushort*)W2t, b2,
                       (ushort*)C, M);
}

extern "C" void kernel_launch(void* const* d_in, const int* in_sizes, int n_in,
                              void* d_out, int out_size, void* d_ws, size_t ws_size,
                              hipStream_t stream) {
    const float* x         = (const float*)d_in[0];
    const float* edge_attr = (const float*)d_in[1];
    const int*   edge_index= (const int*)d_in[2];
    const int*   batch     = (const int*)d_in[3];
    const float* node_w    = (const float*)d_in[4];
    const float* node_b    = (const float*)d_in[5];
    const float* edge_w    = (const float*)d_in[6];
    const float* edge_b    = (const float*)d_in[7];
    const float* eps       = (const float*)d_in[8];
    const float* gin_w1    = (const float*)d_in[9];
    const float* gin_b1    = (const float*)d_in[10];
    const float* gin_w2    = (const float*)d_in[11];
    const float* gin_b2    = (const float*)d_in[12];
    const float* em_w1     = (const float*)d_in[13];
    const float* em_b1     = (const float*)d_in[14];
    const float* em_w2     = (const float*)d_in[15];
    const float* em_b2     = (const float*)d_in[16];
    const float* gru_wih   = (const float*)d_in[17];
    const float* gru_whh   = (const float*)d_in[18];
    const float* gru_bih   = (const float*)d_in[19];
    const float* gru_bhh   = (const float*)d_in[20];
    const float* lstm_wih  = (const float*)d_in[21];
    const float* lstm_whh  = (const float*)d_in[22];
    const float* lstm_bih  = (const float*)d_in[23];
    const float* lstm_bhh  = (const float*)d_in[24];
    const float* fc_w1     = (const float*)d_in[25];
    const float* fc_b1     = (const float*)d_in[26];
    const float* fc_w2     = (const float*)d_in[27];
    const float* fc_b2     = (const float*)d_in[28];
    float* out = (float*)d_out;
    const int* ei_src = edge_index;
    const int* ei_dst = edge_index + TE;

    // ---- workspace layout ----
    char* base = (char*)d_ws;
    size_t off = 0;
    auto alloc = [&](size_t bytes) { void* p = base + off; off += (bytes + 15) & ~size_t(15); return p; };
    bf16*  nodeb = (bf16*)alloc((size_t)TN * TH * 2);   // 25.6 MB
    bf16*  zb    = (bf16*)alloc((size_t)TN * TH * 2);   // 25.6 MB
    bf16*  e1b   = (bf16*)alloc((size_t)TE * TH * 2);   // 51.2 MB (set2set overlay later)
    int*   deg   = (int*)alloc((size_t)TN * 4);
    int*   rowptr= (int*)alloc((size_t)(TN + 1) * 4);
    int*   cur   = (int*)alloc((size_t)TN * 4);
    int*   srcp  = (int*)alloc((size_t)TE * 4);
    int*   epos  = (int*)alloc((size_t)TE * 4);
    int*   bsum  = (int*)alloc(512 * 4);
    int*   bsumx = (int*)alloc(512 * 4);
    int*   gptr  = (int*)alloc((size_t)(TG + 1) * 4);
    bf16*  w6    = (bf16*)alloc(6 * TH * TH * 2);
    bf16*  wgru  = (bf16*)alloc(2 * 384 * TH * 2);
    bf16*  wl    = (bf16*)alloc(512 * 256 * 2);
    if (ws_size < off) return;

    bf16* w_gin1_0 = w6;
    bf16* w_gin1_1 = w6 + 1 * TH * TH;
    bf16* w_gin2_0 = w6 + 2 * TH * TH;
    bf16* w_gin2_1 = w6 + 3 * TH * TH;
    bf16* w_em1    = w6 + 4 * TH * TH;
    bf16* w_em2    = w6 + 5 * TH * TH;
    bf16* w_wih    = wgru;
    bf16* w_whh    = wgru + 384 * TH;

    ushort* sbuf = (ushort*)e1b;                      // [G][256] bf16
    float*  cl   = (float*)(sbuf + (size_t)TG * 256); // [G][128] fp32

    // ---- CSR + gptr ----
    hipMemsetAsync(deg, 0, (size_t)TN * 4, stream);
    hipMemsetAsync(cur, 0, (size_t)TN * 4, stream);
    count_deg<<<(TE + 255) / 256, 256, 0, stream>>>(ei_dst, deg, TE);
    int nb = (TN + 255) / 256;
    scan_block<<<nb, 256, 0, stream>>>(deg, rowptr, bsum, TN);
    scan_bsum<<<1, 512, 0, stream>>>(bsum, bsumx, nb);
    add_off<<<nb, 256, 0, stream>>>(rowptr, bsumx, TN, TE);
    fill_csr<<<(TE + 255) / 256, 256, 0, stream>>>(ei_src, ei_dst, rowptr, cur, srcp, epos, TE);
    build_gptr<<<(TN + 255) / 256, 256, 0, stream>>>(batch, gptr, TN, TG);

    // ---- weights (one merged kernel) ----
    int convTot = 6 * TH * TH + 2 * 384 * TH + 512 * 256;
    convAll<<<(convTot + 255) / 256, 256, 0, stream>>>(
        gin_w1, gin_w2, em_w1, em_w2, gru_wih, gru_whh, lstm_wih, lstm_whh,
        w6, wgru, wl);

    // ---- projections (edges scattered into CSR slot order) ----
    proj64<14><<<(TN + 63) / 64, 256, 0, stream>>>(x, node_w, node_b, (ushort*)nodeb, TN);
    proj_scatter<<<(TE + 63) / 64, 256, 0, stream>>>(edge_attr, edge_w, edge_b,
                                                     epos, (ushort*)e1b, TE);

    // ---- layer 0 ----
    aggregate_v8<<<(TN * 16 + 255) / 256, 256, 0, stream>>>(
        (const ushort*)nodeb, (const ushort*)e1b, srcp, rowptr, eps, 0, (ushort*)zb, TN);
    launch_mlp2(zb, w_gin1_0, gin_b1, w_gin2_0, gin_b2, zb, TN, stream);
    gru_fused<<<(TN + 63) / 64, 512, 0, stream>>>(
        (const ushort*)zb, (const ushort*)w_wih, (const ushort*)w_whh,
        gru_bih, gru_bhh, (ushort*)nodeb, TN);

    // ---- edge MLP in-place (slot order preserved), layer 1 ----
    launch_mlp2(e1b, w_em1, em_b1, w_em2, em_b2, e1b, TE, stream);
    aggregate_v8<<<(TN * 16 + 255) / 256, 256, 0, stream>>>(
        (const ushort*)nodeb, (const ushort*)e1b, srcp, rowptr, eps, 1, (ushort*)zb, TN);
    launch_mlp2(zb, w_gin1_1, gin_b1 + TH, w_gin2_1, gin_b2 + TH, zb, TN, stream);
    gru_fused<<<(TN + 63) / 64, 512, 0, stream>>>(
        (const ushort*)zb, (const ushort*)w_wih, (const ushort*)w_whh,
        gru_bih, gru_bhh, (ushort*)nodeb, TN);

    // ---- Set2Set (3 steps) ----
    hipMemsetAsync(sbuf, 0, (size_t)TG * 256 * 2 + (size_t)TG * 128 * 4, stream);
    for (int st = 0; st < 3; ++st) {
        lstm_fused<<<(TG + 15) / 16, 256, 0, stream>>>(
            sbuf, (const ushort*)wl, lstm_bih, lstm_bhh, cl, TG);
        att_fused<<<TG, 256, 0, stream>>>((const ushort*)nodeb, sbuf, gptr);
    }

    // ---- final FC ----
    final_fc<<<TG, 128, 0, stream>>>(sbuf, fc_w1, fc_b1, fc_w2, fc_b2, out);
}